// Round 2
// baseline (214.571 us; speedup 1.0000x reference)
//
#include <hip/hip_runtime.h>
#include <hip/hip_bf16.h>
#include <math.h>

typedef __attribute__((ext_vector_type(8))) short short8;
typedef __attribute__((ext_vector_type(4))) float f32x4;

#define TT 4096
#define DM 1024
#define NH 16
#define HD 64
#define PSTR 168   // attn LDS row stride in halfwords (84 dwords == 20 mod 32 banks)

typedef __attribute__((address_space(3))) unsigned int lds_u32;
typedef __attribute__((address_space(1))) unsigned int glb_u32;

__device__ __forceinline__ void async_cp16(const void* g, void* l) {
    __builtin_amdgcn_global_load_lds((glb_u32*)g, (lds_u32*)l, 16, 0, 0);
}

// Fused fp32 -> bf16 cast for x + Wq/Wk/Wv/Wo, PLUS the gate GEMM as the
// FIRST 256 blocks (f32 VALU dot products straight from raw x/Wg -- no
// dependency on cast outputs, so they hide under the memory-bound cast
// blocks instead of forming a tail; round-1 lesson: fusing gate as the
// LAST grid slice of gemm128 cost ~10 us of low-parallelism tail).
__global__ __launch_bounds__(256) void cast_all(
    const float* __restrict__ x,  const float* __restrict__ wq,
    const float* __restrict__ wk, const float* __restrict__ wv,
    const float* __restrict__ wo, const float* __restrict__ wg,
    const float* __restrict__ bg,
    __hip_bfloat16* __restrict__ xb,  __hip_bfloat16* __restrict__ wqb,
    __hip_bfloat16* __restrict__ wkb, __hip_bfloat16* __restrict__ wvb,
    __hip_bfloat16* __restrict__ wob, float* __restrict__ Gf)
{
    int b = blockIdx.x;
    if (b < 256) {
        // Gate: G[t,h] = sigmoid(x[t,:] . Wg[h,:] + bg[h]), f32 throughout.
        // 16 tokens x 16 heads per block; lanes sharing a token broadcast the
        // x row, the 16 Wg rows are L2-resident after the first blocks.
        const int h  = threadIdx.x & 15;
        const int tk = threadIdx.x >> 4;
        const int t  = b * 16 + tk;
        const float* xr = x  + (size_t)t * DM;
        const float* wr = wg + (size_t)h * DM;
        float acc = 0.f;
#pragma unroll 8
        for (int k = 0; k < DM; k += 4) {
            float4 xv = *(const float4*)(xr + k);
            float4 wv = *(const float4*)(wr + k);
            acc += xv.x * wv.x + xv.y * wv.y + xv.z * wv.z + xv.w * wv.w;
        }
        float z = acc + bg[h];
        Gf[t * NH + h] = 1.f / (1.f + __expf(-z));
        return;
    }
    b -= 256;
    const float* src;
    __hip_bfloat16* dst;
    size_t base;
    if (b < 4096)      { src = x;  dst = xb;  base = (size_t)b * 1024; }
    else if (b < 5120) { src = wq; dst = wqb; base = (size_t)(b - 4096) * 1024; }
    else if (b < 6144) { src = wk; dst = wkb; base = (size_t)(b - 5120) * 1024; }
    else if (b < 7168) { src = wv; dst = wvb; base = (size_t)(b - 6144) * 1024; }
    else               { src = wo; dst = wob; base = (size_t)(b - 7168) * 1024; }
    size_t i = base + (size_t)threadIdx.x * 4;
    float4 v = *(const float4*)(src + i);
    __hip_bfloat16 h0 = (__hip_bfloat16)v.x;
    __hip_bfloat16 h1 = (__hip_bfloat16)v.y;
    __hip_bfloat16 h2 = (__hip_bfloat16)v.z;
    __hip_bfloat16 h3 = (__hip_bfloat16)v.w;
    ushort4 u;
    u.x = *(unsigned short*)&h0;
    u.y = *(unsigned short*)&h1;
    u.z = *(unsigned short*)&h2;
    u.w = *(unsigned short*)&h3;
    *(ushort4*)((unsigned short*)dst + i) = u;
}

// 128x128-tile GEMM, single-buffered (32 KB LDS keeps 4+ blocks/CU; dbuf at
// 64 KB drops to 2 blocks/CU and regresses ~15 us -- measured round 6).
// Grid (M/128, 24): group = blockIdx.y>>3 selects B/bias/O (QKV fusion).
// For grp 1/2 (K/V) the epilogue ALSO emits the 32-token chunk means into
// CK/CV: each wave's 64-row half holds exactly two whole chunks, so a per-
// thread 8-row sum + two quad __shfl_xor reductions produce each chunk mean
// with no extra memory pass (replaces the old chunk_kernel + its 16 MB re-read).
template <typename OutT>
__global__ __launch_bounds__(256) void gemm128(
    const __hip_bfloat16* __restrict__ A,
    const __hip_bfloat16* __restrict__ B0, const __hip_bfloat16* __restrict__ B1,
    const __hip_bfloat16* __restrict__ B2,
    const float* __restrict__ c0, const float* __restrict__ c1, const float* __restrict__ c2,
    OutT* __restrict__ O0, OutT* __restrict__ O1, OutT* __restrict__ O2,
    __hip_bfloat16* __restrict__ CK, __hip_bfloat16* __restrict__ CV)
{
    const int K = DM;
    __shared__ __align__(16) unsigned short sA[128 * 32];
    __shared__ __align__(16) unsigned short sB[128 * 32];

    const int grp = blockIdx.y >> 3;
    const __hip_bfloat16* B = grp == 0 ? B0 : (grp == 1 ? B1 : B2);
    const float* bias       = grp == 0 ? c0 : (grp == 1 ? c1 : c2);
    OutT* O                 = grp == 0 ? O0 : (grp == 1 ? O1 : O2);

    const int tid  = threadIdx.x;
    const int w    = tid >> 6;
    const int lane = tid & 63;
    const int l16  = lane & 15;
    const int quad = lane >> 4;
    const int rowBase = blockIdx.x * 128;
    const int colBase = (blockIdx.y & 7) * 128;

    const int srow   = lane >> 2;
    const int sswz   = (srow & 3) ^ (srow >> 2);
    const int gchunk = (lane & 3) ^ sswz;
    const __hip_bfloat16* gA = A + (size_t)(rowBase + w * 32 + srow) * K + gchunk * 8;
    const __hip_bfloat16* gB = B + (size_t)(colBase + w * 32 + srow) * K + gchunk * 8;
    unsigned short* lA = sA + w * 32 * 32;
    unsigned short* lB = sB + w * 32 * 32;

    const int fswz = (l16 & 3) ^ (l16 >> 2);
    const int mrow = (w & 1) * 64;
    const int ncol = (w >> 1) * 64;

    f32x4 acc[4][4];
#pragma unroll
    for (int i = 0; i < 4; ++i)
#pragma unroll
        for (int j = 0; j < 4; ++j) acc[i][j] = (f32x4){0.f, 0.f, 0.f, 0.f};

    for (int k0 = 0; k0 < K; k0 += 32) {
        __syncthreads();
        async_cp16(gA + k0, lA);
        async_cp16(gA + k0 + (size_t)16 * K, lA + 16 * 32);
        async_cp16(gB + k0, lB);
        async_cp16(gB + k0 + (size_t)16 * K, lB + 16 * 32);
        __syncthreads();

        short8 af[4], bf[4];
#pragma unroll
        for (int mt = 0; mt < 4; ++mt)
            af[mt] = *(const short8*)&sA[(mrow + mt * 16 + l16) * 32 + (quad ^ fswz) * 8];
#pragma unroll
        for (int nt = 0; nt < 4; ++nt)
            bf[nt] = *(const short8*)&sB[(ncol + nt * 16 + l16) * 32 + (quad ^ fswz) * 8];
#pragma unroll
        for (int mt = 0; mt < 4; ++mt)
#pragma unroll
            for (int nt = 0; nt < 4; ++nt)
                acc[mt][nt] = __builtin_amdgcn_mfma_f32_16x16x32_bf16(af[mt], bf[nt], acc[mt][nt], 0, 0, 0);
    }

    // Epilogue: store O (+bias) and, for K/V groups, fused chunk means.
    // Rows per thread within this wave's 64-row half: mt*16 + quad*4 + r.
    // mt<2 -> local chunk 0 (rows 0..31), mt>=2 -> local chunk 1 (rows 32..63).
#pragma unroll
    for (int nt = 0; nt < 4; ++nt) {
        int col = colBase + ncol + nt * 16 + l16;
        float bv = bias[col];
        float cs0 = 0.f, cs1 = 0.f;
#pragma unroll
        for (int mt = 0; mt < 4; ++mt) {
#pragma unroll
            for (int r = 0; r < 4; ++r) {
                int row = rowBase + mrow + mt * 16 + quad * 4 + r;
                float v = acc[mt][nt][r] + bv;
                O[(size_t)row * DM + col] = (OutT)v;
                if (mt < 2) cs0 += v; else cs1 += v;
            }
        }
        if (grp >= 1) {
            cs0 += __shfl_xor(cs0, 16); cs0 += __shfl_xor(cs0, 32);
            cs1 += __shfl_xor(cs1, 16); cs1 += __shfl_xor(cs1, 32);
            if (quad == 0) {
                __hip_bfloat16* C = (grp == 1) ? CK : CV;
                int cbase = blockIdx.x * 4 + (w & 1) * 2;
                C[(size_t)cbase * DM + col]       = (__hip_bfloat16)(cs0 * (1.f / 32.f));
                C[(size_t)(cbase + 1) * DM + col] = (__hip_bfloat16)(cs1 * (1.f / 32.f));
            }
        }
    }
}

// 128x64-tile GEMM for the Wo projection: 12 KB LDS, grid (32,16) = 512
// blocks = 2+/CU (the 128x128 version gave only 1 block/CU at N=1024).
template <typename OutT>
__global__ __launch_bounds__(256) void gemm_n64(
    const __hip_bfloat16* __restrict__ A,
    const __hip_bfloat16* __restrict__ B,
    const float* __restrict__ bias,
    OutT* __restrict__ O)
{
    const int K = DM;
    __shared__ __align__(16) unsigned short sA[128 * 32];
    __shared__ __align__(16) unsigned short sB[64 * 32];

    const int tid  = threadIdx.x;
    const int w    = tid >> 6;
    const int lane = tid & 63;
    const int l16  = lane & 15;
    const int quad = lane >> 4;
    const int rowBase = blockIdx.x * 128;
    const int colBase = blockIdx.y * 64;

    const int srow   = lane >> 2;
    const int sswz   = (srow & 3) ^ (srow >> 2);
    const int gchunk = (lane & 3) ^ sswz;
    const __hip_bfloat16* gA = A + (size_t)(rowBase + w * 32 + srow) * K + gchunk * 8;
    const __hip_bfloat16* gB = B + (size_t)(colBase + w * 16 + srow) * K + gchunk * 8;
    unsigned short* lA = sA + w * 32 * 32;
    unsigned short* lB = sB + w * 16 * 32;

    const int fswz = (l16 & 3) ^ (l16 >> 2);
    const int mrow = w * 32;

    f32x4 acc[2][4];
#pragma unroll
    for (int i = 0; i < 2; ++i)
#pragma unroll
        for (int j = 0; j < 4; ++j) acc[i][j] = (f32x4){0.f, 0.f, 0.f, 0.f};

    for (int k0 = 0; k0 < K; k0 += 32) {
        __syncthreads();
        async_cp16(gA + k0, lA);
        async_cp16(gA + k0 + (size_t)16 * K, lA + 16 * 32);
        async_cp16(gB + k0, lB);
        __syncthreads();

        short8 af[2], bf[4];
#pragma unroll
        for (int mt = 0; mt < 2; ++mt)
            af[mt] = *(const short8*)&sA[(mrow + mt * 16 + l16) * 32 + (quad ^ fswz) * 8];
#pragma unroll
        for (int nt = 0; nt < 4; ++nt)
            bf[nt] = *(const short8*)&sB[(nt * 16 + l16) * 32 + (quad ^ fswz) * 8];
#pragma unroll
        for (int mt = 0; mt < 2; ++mt)
#pragma unroll
            for (int nt = 0; nt < 4; ++nt)
                acc[mt][nt] = __builtin_amdgcn_mfma_f32_16x16x32_bf16(af[mt], bf[nt], acc[mt][nt], 0, 0, 0);
    }

#pragma unroll
    for (int nt = 0; nt < 4; ++nt) {
        int col = colBase + nt * 16 + l16;
        float bv = bias[col];
#pragma unroll
        for (int mt = 0; mt < 2; ++mt) {
#pragma unroll
            for (int r = 0; r < 4; ++r) {
                int row = rowBase + mrow + mt * 16 + quad * 4 + r;
                O[(size_t)row * DM + col] = (OutT)(acc[mt][nt][r] + bv);
            }
        }
    }
}

// MFMA attention: 64 queries x 1 head per block (grid 64 x 16, 256 threads).
__global__ __launch_bounds__(256) void attn_mfma(
    const __hip_bfloat16* __restrict__ Q,
    const __hip_bfloat16* __restrict__ K,
    const __hip_bfloat16* __restrict__ V,
    const __hip_bfloat16* __restrict__ CK,
    const __hip_bfloat16* __restrict__ CV,
    const float* __restrict__ G,
    __hip_bfloat16* __restrict__ Aout)
{
    __shared__ alignas(16) unsigned short Pls[64 * PSTR];
    __shared__ alignas(16) unsigned short Vts[64 * PSTR];

    const int h   = blockIdx.y;
    const int t0  = blockIdx.x * 64;
    const int tid = threadIdx.x;
    const int w    = tid >> 6;
    const int lane = tid & 63;
    const int l16  = lane & 15;
    const int quad = lane >> 4;
    const float scale = 0.125f;

    const int rc0  = (t0 >= 96) ? ((t0 - 64) >> 5) : 0;
    const int cmin = rc0 > 16 ? rc0 - 16 : 0;

    const unsigned short* Vu  = (const unsigned short*)V;
    const unsigned short* CVu = (const unsigned short*)CV;

    // ---- stage V^T (+ CV^T) into LDS via 16B row-chunk loads + packed writes.
    // Wave w owns dim-groups g = 2w, 2w+1; lane owns slot-pair (2*pair, 2*pair+1).
    // ushort2 LDS writes land on consecutive dwords across the wave (2-way, free).
    {
#pragma unroll
        for (int gg = 0; gg < 2; ++gg) {
            const int g = w * 2 + gg;
#pragma unroll
            for (int i = 0; i < 2; ++i) {
                const int pair = lane + 64 * i;
                if (pair < 80) {
                    const int j = pair * 2;
                    const unsigned short *s0, *s1;
                    if (j < 128) {
                        int tok0 = t0 - 64 + j; if (tok0 < 0) tok0 = 0;
                        int tok1 = t0 - 63 + j; if (tok1 < 0) tok1 = 0;
                        s0 = Vu + (size_t)tok0 * DM + h * 64 + g * 8;
                        s1 = Vu + (size_t)tok1 * DM + h * 64 + g * 8;
                    } else {
                        int c0 = cmin + (j - 128); if (c0 > 127) c0 = 127;
                        int c1 = c0 + 1;           if (c1 > 127) c1 = 127;
                        s0 = CVu + (size_t)c0 * DM + h * 64 + g * 8;
                        s1 = CVu + (size_t)c1 * DM + h * 64 + g * 8;
                    }
                    short8 v0 = *(const short8*)s0;
                    short8 v1 = *(const short8*)s1;
#pragma unroll
                    for (int e = 0; e < 8; ++e) {
                        ushort2 pk;
                        pk.x = (unsigned short)v0[e];
                        pk.y = (unsigned short)v1[e];
                        *(ushort2*)&Vts[(g * 8 + e) * PSTR + j] = pk;
                    }
                }
            }
        }
    }

    const __hip_bfloat16* qp = Q + (size_t)(t0 + w * 16 + l16) * DM + h * 64 + quad * 8;
    short8 qf0 = *(const short8*)(qp);
    short8 qf1 = *(const short8*)(qp + 32);

    f32x4 sc[8];
#pragma unroll
    for (int jt = 0; jt < 8; ++jt) {
        int j = jt * 16 + l16;
        int tok = t0 - 64 + j;
        tok = tok < 0 ? 0 : tok;
        const __hip_bfloat16* kp = K + (size_t)tok * DM + h * 64 + quad * 8;
        short8 b0 = *(const short8*)(kp);
        short8 b1 = *(const short8*)(kp + 32);
        f32x4 a = __builtin_amdgcn_mfma_f32_16x16x32_bf16(qf0, b0, (f32x4){0.f,0.f,0.f,0.f}, 0, 0, 0);
        sc[jt]  = __builtin_amdgcn_mfma_f32_16x16x32_bf16(qf1, b1, a, 0, 0, 0);
    }
    f32x4 sc2[2];
#pragma unroll
    for (int jt = 0; jt < 2; ++jt) {
        int c = cmin + jt * 16 + l16;
        if (c > 127) c = 127;
        const __hip_bfloat16* cp = CK + (size_t)c * DM + h * 64 + quad * 8;
        short8 b0 = *(const short8*)(cp);
        short8 b1 = *(const short8*)(cp + 32);
        f32x4 a = __builtin_amdgcn_mfma_f32_16x16x32_bf16(qf0, b0, (f32x4){0.f,0.f,0.f,0.f}, 0, 0, 0);
        sc2[jt] = __builtin_amdgcn_mfma_f32_16x16x32_bf16(qf1, b1, a, 0, 0, 0);
    }

    __syncthreads();  // all waves' Vts writes visible before PV reads

    const int rbase = w * 16 + quad * 4;
    float gl[4], g2[4];
    float mx[4], sm[4], mx2[4], sm2[4];
#pragma unroll
    for (int reg = 0; reg < 4; ++reg) {
        int rr = rbase + reg;
        int t  = t0 + rr;
        float g = G[t * NH + h];
        int rc = (t >= 96) ? ((t - 64) >> 5) : 0;
        gl[reg] = (t > 0)  ? g        : 0.f;
        g2[reg] = (rc > 0) ? (1.f - g) : 0.f;

        int jlo = rr > (64 - t0) ? rr : (64 - t0);
        int jhi = rr + 63;
        float m = -1e30f;
#pragma unroll
        for (int jt = 0; jt < 8; ++jt) {
            int j = jt * 16 + l16;
            float s = (j >= jlo && j <= jhi) ? sc[jt][reg] * scale : -1e30f;
            sc[jt][reg] = s;
            m = fmaxf(m, s);
        }
        mx[reg] = m;

        int nvis = rc < 16 ? rc : 16;
        int clo = rc - nvis, chi = rc - 1;
        float m2 = -1e30f;
#pragma unroll
        for (int jt = 0; jt < 2; ++jt) {
            int c = cmin + jt * 16 + l16;
            float s = (c >= clo && c <= chi) ? sc2[jt][reg] * scale : -1e30f;
            sc2[jt][reg] = s;
            m2 = fmaxf(m2, s);
        }
        mx2[reg] = m2;
    }
#pragma unroll
    for (int off = 1; off <= 8; off <<= 1)
#pragma unroll
        for (int reg = 0; reg < 4; ++reg) {
            mx[reg]  = fmaxf(mx[reg],  __shfl_xor(mx[reg],  off));
            mx2[reg] = fmaxf(mx2[reg], __shfl_xor(mx2[reg], off));
        }
#pragma unroll
    for (int reg = 0; reg < 4; ++reg) {
        float s = 0.f, s2 = 0.f;
#pragma unroll
        for (int jt = 0; jt < 8; ++jt) {
            float p = __expf(sc[jt][reg] - mx[reg]);
            sc[jt][reg] = p;
            s += p;
        }
#pragma unroll
        for (int jt = 0; jt < 2; ++jt) {
            float p = __expf(sc2[jt][reg] - mx2[reg]);
            sc2[jt][reg] = p;
            s2 += p;
        }
        sm[reg] = s; sm2[reg] = s2;
    }
#pragma unroll
    for (int off = 1; off <= 8; off <<= 1)
#pragma unroll
        for (int reg = 0; reg < 4; ++reg) {
            sm[reg]  += __shfl_xor(sm[reg],  off);
            sm2[reg] += __shfl_xor(sm2[reg], off);
        }

#pragma unroll
    for (int reg = 0; reg < 4; ++reg) {
        float f1 = gl[reg] / sm[reg];
        float f2 = g2[reg] / sm2[reg];
        int rowoff = (rbase + reg) * PSTR;
#pragma unroll
        for (int jt = 0; jt < 8; ++jt) {
            __hip_bfloat16 hb = (__hip_bfloat16)(sc[jt][reg] * f1);
            Pls[rowoff + jt * 16 + l16] = *(unsigned short*)&hb;
        }
#pragma unroll
        for (int jt = 0; jt < 2; ++jt) {
            __hip_bfloat16 hb = (__hip_bfloat16)(sc2[jt][reg] * f2);
            Pls[rowoff + 128 + jt * 16 + l16] = *(unsigned short*)&hb;
        }
    }
    asm volatile("s_waitcnt lgkmcnt(0)" ::: "memory");  // wave-private P round-trip

    f32x4 o[4];
#pragma unroll
    for (int nt = 0; nt < 4; ++nt) o[nt] = (f32x4){0.f, 0.f, 0.f, 0.f};
#pragma unroll
    for (int kt = 0; kt < 5; ++kt) {
        short8 a = *(const short8*)&Pls[(w * 16 + l16) * PSTR + kt * 32 + quad * 8];
#pragma unroll
        for (int nt = 0; nt < 4; ++nt) {
            int dd = nt * 16 + l16;
            short8 b = *(const short8*)&Vts[dd * PSTR + kt * 32 + quad * 8];
            o[nt] = __builtin_amdgcn_mfma_f32_16x16x32_bf16(a, b, o[nt], 0, 0, 0);
        }
    }

#pragma unroll
    for (int nt = 0; nt < 4; ++nt) {
#pragma unroll
        for (int reg = 0; reg < 4; ++reg) {
            int row = t0 + rbase + reg;
            int col = h * 64 + nt * 16 + l16;
            Aout[(size_t)row * DM + col] = (__hip_bfloat16)(o[nt][reg]);
        }
    }
}

extern "C" void kernel_launch(void* const* d_in, const int* in_sizes, int n_in,
                              void* d_out, int out_size, void* d_ws, size_t ws_size,
                              hipStream_t stream)
{
    const float* x  = (const float*)d_in[0];
    const float* Wq = (const float*)d_in[1];
    const float* bq = (const float*)d_in[2];
    const float* Wk = (const float*)d_in[3];
    const float* bk = (const float*)d_in[4];
    const float* Wv = (const float*)d_in[5];
    const float* bv = (const float*)d_in[6];
    const float* Wo = (const float*)d_in[7];
    const float* bo = (const float*)d_in[8];
    const float* Wg = (const float*)d_in[9];
    const float* bg = (const float*)d_in[10];
    float* out = (float*)d_out;

    char* ws = (char*)d_ws;
    const size_t MB = 1024 * 1024;
    __hip_bfloat16* xb  = (__hip_bfloat16*)(ws + 0 * MB);   // 8 MB
    __hip_bfloat16* Qb  = (__hip_bfloat16*)(ws + 8 * MB);   // 8 MB
    __hip_bfloat16* Kb  = (__hip_bfloat16*)(ws + 16 * MB);  // 8 MB
    __hip_bfloat16* Vb  = (__hip_bfloat16*)(ws + 24 * MB);  // 8 MB
    __hip_bfloat16* Ab  = (__hip_bfloat16*)(ws + 32 * MB);  // 8 MB
    __hip_bfloat16* Wqb = (__hip_bfloat16*)(ws + 40 * MB);  // 2 MB
    __hip_bfloat16* Wkb = (__hip_bfloat16*)(ws + 42 * MB);  // 2 MB
    __hip_bfloat16* Wvb = (__hip_bfloat16*)(ws + 44 * MB);  // 2 MB
    __hip_bfloat16* Wob = (__hip_bfloat16*)(ws + 46 * MB);  // 2 MB
    __hip_bfloat16* CKb = (__hip_bfloat16*)(ws + 48 * MB);            // 256 KB
    __hip_bfloat16* CVb = (__hip_bfloat16*)(ws + 48 * MB + 256*1024); // 256 KB
    float* Gf           = (float*)(ws + 48 * MB + 512 * 1024);        // 256 KB

    // Gate blocks FIRST (hide under memory-bound cast blocks), then casts.
    cast_all<<<dim3(8448), 256, 0, stream>>>(x, Wq, Wk, Wv, Wo, Wg, bg,
                                             xb, Wqb, Wkb, Wvb, Wob, Gf);

    // Fused QKV GEMM (+ chunk means in K/V epilogue): grid (32, 24).
    gemm128<__hip_bfloat16><<<dim3(32, 24), 256, 0, stream>>>(
        xb, Wqb, Wkb, Wvb, bq, bk, bv, Qb, Kb, Vb, CKb, CVb);
    attn_mfma<<<dim3(64, 16), 256, 0, stream>>>(Qb, Kb, Vb, CKb, CVb, Gf, Ab);
    // Output GEMM: 128x64 tiles, grid (32, 16) = 512 blocks.
    gemm_n64<float><<<dim3(32, 16), 256, 0, stream>>>(Ab, Wob, bo, out);
}

// Round 3
// 184.145 us; speedup vs baseline: 1.1652x; 1.1652x over previous
//
#include <hip/hip_runtime.h>
#include <hip/hip_bf16.h>
#include <math.h>

typedef __attribute__((ext_vector_type(8))) short short8;
typedef __attribute__((ext_vector_type(4))) float f32x4;

#define TT 4096
#define DM 1024
#define NH 16
#define HD 64
#define PSTR 168   // attn LDS row stride in halfwords (84 dwords == 20 mod 32 banks)

typedef __attribute__((address_space(3))) unsigned int lds_u32;
typedef __attribute__((address_space(1))) unsigned int glb_u32;

__device__ __forceinline__ void async_cp16(const void* g, void* l) {
    __builtin_amdgcn_global_load_lds((glb_u32*)g, (lds_u32*)l, 16, 0, 0);
}

// Fused fp32 -> bf16 cast for x + Wq/Wk/Wv/Wo + Wg.
__global__ __launch_bounds__(256) void cast_all(
    const float* __restrict__ x,  const float* __restrict__ wq,
    const float* __restrict__ wk, const float* __restrict__ wv,
    const float* __restrict__ wo, const float* __restrict__ wg,
    __hip_bfloat16* __restrict__ xb,  __hip_bfloat16* __restrict__ wqb,
    __hip_bfloat16* __restrict__ wkb, __hip_bfloat16* __restrict__ wvb,
    __hip_bfloat16* __restrict__ wob, __hip_bfloat16* __restrict__ wgb)
{
    int b = blockIdx.x;
    const float* src;
    __hip_bfloat16* dst;
    size_t base;
    if (b < 4096)      { src = x;  dst = xb;  base = (size_t)b * 1024; }
    else if (b < 5120) { src = wq; dst = wqb; base = (size_t)(b - 4096) * 1024; }
    else if (b < 6144) { src = wk; dst = wkb; base = (size_t)(b - 5120) * 1024; }
    else if (b < 7168) { src = wv; dst = wvb; base = (size_t)(b - 6144) * 1024; }
    else if (b < 8192) { src = wo; dst = wob; base = (size_t)(b - 7168) * 1024; }
    else               { src = wg; dst = wgb; base = (size_t)(b - 8192) * 1024; }
    size_t i = base + (size_t)threadIdx.x * 4;
    float4 v = *(const float4*)(src + i);
    __hip_bfloat16 h0 = (__hip_bfloat16)v.x;
    __hip_bfloat16 h1 = (__hip_bfloat16)v.y;
    __hip_bfloat16 h2 = (__hip_bfloat16)v.z;
    __hip_bfloat16 h3 = (__hip_bfloat16)v.w;
    ushort4 u;
    u.x = *(unsigned short*)&h0;
    u.y = *(unsigned short*)&h1;
    u.z = *(unsigned short*)&h2;
    u.w = *(unsigned short*)&h3;
    *(ushort4*)((unsigned short*)dst + i) = u;
}

// 128x128-tile GEMM, single-buffered, BK=64 (two 32-wide halves staged per
// barrier pair -> 16 K-iters instead of 32; halves computed in k-order so
// accumulation is bit-identical to BK=32). LDS 32 KB/block keeps ~5 blocks/CU
// (VGPR=88 is the cap); note: DOUBLE-buffering at 64 KB was measured to
// regress ~15 us (2 blocks/CU) in a previous session -- this is not that.
// Grid (M/128, 8*ngroups): group = blockIdx.y>>3 selects B/bias/O (QKV fusion).
template <typename OutT>
__global__ __launch_bounds__(256) void gemm128(
    const __hip_bfloat16* __restrict__ A,
    const __hip_bfloat16* __restrict__ B0, const __hip_bfloat16* __restrict__ B1,
    const __hip_bfloat16* __restrict__ B2,
    const float* __restrict__ c0, const float* __restrict__ c1, const float* __restrict__ c2,
    OutT* __restrict__ O0, OutT* __restrict__ O1, OutT* __restrict__ O2)
{
    const int K = DM;
    __shared__ __align__(16) unsigned short sA[128 * 64];
    __shared__ __align__(16) unsigned short sB[128 * 64];

    const int grp = blockIdx.y >> 3;
    const __hip_bfloat16* B = grp == 0 ? B0 : (grp == 1 ? B1 : B2);
    const float* bias       = grp == 0 ? c0 : (grp == 1 ? c1 : c2);
    OutT* O                 = grp == 0 ? O0 : (grp == 1 ? O1 : O2);

    const int tid  = threadIdx.x;
    const int w    = tid >> 6;
    const int lane = tid & 63;
    const int l16  = lane & 15;
    const int quad = lane >> 4;
    const int rowBase = blockIdx.x * 128;
    const int colBase = (blockIdx.y & 7) * 128;

    const int srow   = lane >> 2;
    const int sswz   = (srow & 3) ^ (srow >> 2);
    const int gchunk = (lane & 3) ^ sswz;
    const __hip_bfloat16* gA = A + (size_t)(rowBase + w * 32 + srow) * K + gchunk * 8;
    const __hip_bfloat16* gB = B + (size_t)(colBase + w * 32 + srow) * K + gchunk * 8;
    unsigned short* lA = sA + w * 32 * 32;   // half-0 region; half-1 at +128*32
    unsigned short* lB = sB + w * 32 * 32;

    const int fswz = (l16 & 3) ^ (l16 >> 2);
    const int mrow = (w & 1) * 64;
    const int ncol = (w >> 1) * 64;

    f32x4 acc[4][4];
#pragma unroll
    for (int i = 0; i < 4; ++i)
#pragma unroll
        for (int j = 0; j < 4; ++j) acc[i][j] = (f32x4){0.f, 0.f, 0.f, 0.f};

    for (int k0 = 0; k0 < K; k0 += 64) {
        __syncthreads();
        async_cp16(gA + k0,                     lA);
        async_cp16(gA + k0 + (size_t)16 * K,    lA + 16 * 32);
        async_cp16(gA + k0 + 32,                lA + 128 * 32);
        async_cp16(gA + k0 + 32 + (size_t)16*K, lA + 128 * 32 + 16 * 32);
        async_cp16(gB + k0,                     lB);
        async_cp16(gB + k0 + (size_t)16 * K,    lB + 16 * 32);
        async_cp16(gB + k0 + 32,                lB + 128 * 32);
        async_cp16(gB + k0 + 32 + (size_t)16*K, lB + 128 * 32 + 16 * 32);
        __syncthreads();

#pragma unroll
        for (int half = 0; half < 2; ++half) {
            const unsigned short* pA = sA + half * 128 * 32;
            const unsigned short* pB = sB + half * 128 * 32;
            short8 af[4], bf[4];
#pragma unroll
            for (int mt = 0; mt < 4; ++mt)
                af[mt] = *(const short8*)&pA[(mrow + mt * 16 + l16) * 32 + (quad ^ fswz) * 8];
#pragma unroll
            for (int nt = 0; nt < 4; ++nt)
                bf[nt] = *(const short8*)&pB[(ncol + nt * 16 + l16) * 32 + (quad ^ fswz) * 8];
#pragma unroll
            for (int mt = 0; mt < 4; ++mt)
#pragma unroll
                for (int nt = 0; nt < 4; ++nt)
                    acc[mt][nt] = __builtin_amdgcn_mfma_f32_16x16x32_bf16(af[mt], bf[nt], acc[mt][nt], 0, 0, 0);
        }
    }

#pragma unroll
    for (int nt = 0; nt < 4; ++nt) {
        int col = colBase + ncol + nt * 16 + l16;
        float bv = bias[col];
#pragma unroll
        for (int mt = 0; mt < 4; ++mt) {
#pragma unroll
            for (int r = 0; r < 4; ++r) {
                int row = rowBase + mrow + mt * 16 + quad * 4 + r;
                O[(size_t)row * DM + col] = (OutT)(acc[mt][nt][r] + bv);
            }
        }
    }
}

// 128x64-tile GEMM for the Wo projection, BK=64 (same change as gemm128).
// 24 KB LDS, grid (32,16) = 512 blocks.
template <typename OutT>
__global__ __launch_bounds__(256) void gemm_n64(
    const __hip_bfloat16* __restrict__ A,
    const __hip_bfloat16* __restrict__ B,
    const float* __restrict__ bias,
    OutT* __restrict__ O)
{
    const int K = DM;
    __shared__ __align__(16) unsigned short sA[128 * 64];
    __shared__ __align__(16) unsigned short sB[64 * 64];

    const int tid  = threadIdx.x;
    const int w    = tid >> 6;
    const int lane = tid & 63;
    const int l16  = lane & 15;
    const int quad = lane >> 4;
    const int rowBase = blockIdx.x * 128;
    const int colBase = blockIdx.y * 64;

    const int srow   = lane >> 2;
    const int sswz   = (srow & 3) ^ (srow >> 2);
    const int gchunk = (lane & 3) ^ sswz;
    const __hip_bfloat16* gA = A + (size_t)(rowBase + w * 32 + srow) * K + gchunk * 8;
    const __hip_bfloat16* gB = B + (size_t)(colBase + w * 16 + srow) * K + gchunk * 8;
    unsigned short* lA = sA + w * 32 * 32;   // half-0; half-1 at +128*32
    unsigned short* lB = sB + w * 16 * 32;   // half-0; half-1 at +64*32

    const int fswz = (l16 & 3) ^ (l16 >> 2);
    const int mrow = w * 32;

    f32x4 acc[2][4];
#pragma unroll
    for (int i = 0; i < 2; ++i)
#pragma unroll
        for (int j = 0; j < 4; ++j) acc[i][j] = (f32x4){0.f, 0.f, 0.f, 0.f};

    for (int k0 = 0; k0 < K; k0 += 64) {
        __syncthreads();
        async_cp16(gA + k0,                     lA);
        async_cp16(gA + k0 + (size_t)16 * K,    lA + 16 * 32);
        async_cp16(gA + k0 + 32,                lA + 128 * 32);
        async_cp16(gA + k0 + 32 + (size_t)16*K, lA + 128 * 32 + 16 * 32);
        async_cp16(gB + k0,                     lB);
        async_cp16(gB + k0 + 32,                lB + 64 * 32);
        __syncthreads();

#pragma unroll
        for (int half = 0; half < 2; ++half) {
            const unsigned short* pA = sA + half * 128 * 32;
            const unsigned short* pB = sB + half * 64 * 32;
            short8 af[2], bf[4];
#pragma unroll
            for (int mt = 0; mt < 2; ++mt)
                af[mt] = *(const short8*)&pA[(mrow + mt * 16 + l16) * 32 + (quad ^ fswz) * 8];
#pragma unroll
            for (int nt = 0; nt < 4; ++nt)
                bf[nt] = *(const short8*)&pB[(nt * 16 + l16) * 32 + (quad ^ fswz) * 8];
#pragma unroll
            for (int mt = 0; mt < 2; ++mt)
#pragma unroll
                for (int nt = 0; nt < 4; ++nt)
                    acc[mt][nt] = __builtin_amdgcn_mfma_f32_16x16x32_bf16(af[mt], bf[nt], acc[mt][nt], 0, 0, 0);
        }
    }

#pragma unroll
    for (int nt = 0; nt < 4; ++nt) {
        int col = colBase + nt * 16 + l16;
        float bv = bias[col];
#pragma unroll
        for (int mt = 0; mt < 2; ++mt) {
#pragma unroll
            for (int r = 0; r < 4; ++r) {
                int row = rowBase + mrow + mt * 16 + quad * 4 + r;
                O[(size_t)row * DM + col] = (OutT)(acc[mt][nt][r] + bv);
            }
        }
    }
}

// Gate GEMM via MFMA: G[t,h] = sigmoid(xb[t,:] . Wgb[h,:] + bg[h]).
__global__ __launch_bounds__(64) void g_mfma(
    const __hip_bfloat16* __restrict__ xb,
    const __hip_bfloat16* __restrict__ Wgb,
    const float* __restrict__ bg,
    float* __restrict__ G)
{
    const int lane = threadIdx.x;
    const int l16  = lane & 15;
    const int quad = lane >> 4;
    const int t0   = blockIdx.x * 16;
    const __hip_bfloat16* ap = xb + (size_t)(t0 + l16) * DM + quad * 8;
    const __hip_bfloat16* bp = Wgb + (size_t)l16 * DM + quad * 8;
    f32x4 acc = (f32x4){0.f, 0.f, 0.f, 0.f};
#pragma unroll 4
    for (int k0 = 0; k0 < DM; k0 += 32) {
        short8 a = *(const short8*)(ap + k0);
        short8 b = *(const short8*)(bp + k0);
        acc = __builtin_amdgcn_mfma_f32_16x16x32_bf16(a, b, acc, 0, 0, 0);
    }
    float bgv = bg[l16];
#pragma unroll
    for (int r = 0; r < 4; ++r) {
        int t = t0 + quad * 4 + r;
        float z = acc[r] + bgv;
        G[t * NH + l16] = 1.f / (1.f + __expf(-z));
    }
}

// Chunk means over 32 consecutive tokens: CK[c,:], CV[c,:], c = 0..127.
__global__ __launch_bounds__(256) void chunk_kernel(
    const __hip_bfloat16* __restrict__ K,
    const __hip_bfloat16* __restrict__ V,
    __hip_bfloat16* __restrict__ CK,
    __hip_bfloat16* __restrict__ CV)
{
    const int c = blockIdx.x;
    const int d = blockIdx.y * 256 + threadIdx.x;
    float ak = 0.f, av = 0.f;
    for (int i = 0; i < 32; ++i) {
        ak += (float)K[(size_t)(c * 32 + i) * DM + d];
        av += (float)V[(size_t)(c * 32 + i) * DM + d];
    }
    CK[(size_t)c * DM + d] = (__hip_bfloat16)(ak * (1.f / 32.f));
    CV[(size_t)c * DM + d] = (__hip_bfloat16)(av * (1.f / 32.f));
}

// MFMA attention: 64 queries x 1 head per block (grid 64 x 16, 256 threads).
__global__ __launch_bounds__(256) void attn_mfma(
    const __hip_bfloat16* __restrict__ Q,
    const __hip_bfloat16* __restrict__ K,
    const __hip_bfloat16* __restrict__ V,
    const __hip_bfloat16* __restrict__ CK,
    const __hip_bfloat16* __restrict__ CV,
    const float* __restrict__ G,
    __hip_bfloat16* __restrict__ Aout)
{
    __shared__ alignas(16) unsigned short Pls[64 * PSTR];
    __shared__ alignas(16) unsigned short Vts[64 * PSTR];

    const int h   = blockIdx.y;
    const int t0  = blockIdx.x * 64;
    const int tid = threadIdx.x;
    const int w    = tid >> 6;
    const int lane = tid & 63;
    const int l16  = lane & 15;
    const int quad = lane >> 4;
    const float scale = 0.125f;

    const int rc0  = (t0 >= 96) ? ((t0 - 64) >> 5) : 0;
    const int cmin = rc0 > 16 ? rc0 - 16 : 0;

    const unsigned short* Vu  = (const unsigned short*)V;
    const unsigned short* CVu = (const unsigned short*)CV;

    // ---- stage V^T (+ CV^T) into LDS via 16B row-chunk loads + packed writes.
    // Wave w owns dim-groups g = 2w, 2w+1; lane owns slot-pair (2*pair, 2*pair+1).
    // ushort2 LDS writes land on consecutive dwords across the wave (2-way, free).
    {
#pragma unroll
        for (int gg = 0; gg < 2; ++gg) {
            const int g = w * 2 + gg;
#pragma unroll
            for (int i = 0; i < 2; ++i) {
                const int pair = lane + 64 * i;
                if (pair < 80) {
                    const int j = pair * 2;
                    const unsigned short *s0, *s1;
                    if (j < 128) {
                        int tok0 = t0 - 64 + j; if (tok0 < 0) tok0 = 0;
                        int tok1 = t0 - 63 + j; if (tok1 < 0) tok1 = 0;
                        s0 = Vu + (size_t)tok0 * DM + h * 64 + g * 8;
                        s1 = Vu + (size_t)tok1 * DM + h * 64 + g * 8;
                    } else {
                        int c0 = cmin + (j - 128); if (c0 > 127) c0 = 127;
                        int c1 = c0 + 1;           if (c1 > 127) c1 = 127;
                        s0 = CVu + (size_t)c0 * DM + h * 64 + g * 8;
                        s1 = CVu + (size_t)c1 * DM + h * 64 + g * 8;
                    }
                    short8 v0 = *(const short8*)s0;
                    short8 v1 = *(const short8*)s1;
#pragma unroll
                    for (int e = 0; e < 8; ++e) {
                        ushort2 pk;
                        pk.x = (unsigned short)v0[e];
                        pk.y = (unsigned short)v1[e];
                        *(ushort2*)&Vts[(g * 8 + e) * PSTR + j] = pk;
                    }
                }
            }
        }
    }

    const __hip_bfloat16* qp = Q + (size_t)(t0 + w * 16 + l16) * DM + h * 64 + quad * 8;
    short8 qf0 = *(const short8*)(qp);
    short8 qf1 = *(const short8*)(qp + 32);

    f32x4 sc[8];
#pragma unroll
    for (int jt = 0; jt < 8; ++jt) {
        int j = jt * 16 + l16;
        int tok = t0 - 64 + j;
        tok = tok < 0 ? 0 : tok;
        const __hip_bfloat16* kp = K + (size_t)tok * DM + h * 64 + quad * 8;
        short8 b0 = *(const short8*)(kp);
        short8 b1 = *(const short8*)(kp + 32);
        f32x4 a = __builtin_amdgcn_mfma_f32_16x16x32_bf16(qf0, b0, (f32x4){0.f,0.f,0.f,0.f}, 0, 0, 0);
        sc[jt]  = __builtin_amdgcn_mfma_f32_16x16x32_bf16(qf1, b1, a, 0, 0, 0);
    }
    f32x4 sc2[2];
#pragma unroll
    for (int jt = 0; jt < 2; ++jt) {
        int c = cmin + jt * 16 + l16;
        if (c > 127) c = 127;
        const __hip_bfloat16* cp = CK + (size_t)c * DM + h * 64 + quad * 8;
        short8 b0 = *(const short8*)(cp);
        short8 b1 = *(const short8*)(cp + 32);
        f32x4 a = __builtin_amdgcn_mfma_f32_16x16x32_bf16(qf0, b0, (f32x4){0.f,0.f,0.f,0.f}, 0, 0, 0);
        sc2[jt] = __builtin_amdgcn_mfma_f32_16x16x32_bf16(qf1, b1, a, 0, 0, 0);
    }

    __syncthreads();  // all waves' Vts writes visible before PV reads

    const int rbase = w * 16 + quad * 4;
    float gl[4], g2[4];
    float mx[4], sm[4], mx2[4], sm2[4];
#pragma unroll
    for (int reg = 0; reg < 4; ++reg) {
        int rr = rbase + reg;
        int t  = t0 + rr;
        float g = G[t * NH + h];
        int rc = (t >= 96) ? ((t - 64) >> 5) : 0;
        gl[reg] = (t > 0)  ? g        : 0.f;
        g2[reg] = (rc > 0) ? (1.f - g) : 0.f;

        int jlo = rr > (64 - t0) ? rr : (64 - t0);
        int jhi = rr + 63;
        float m = -1e30f;
#pragma unroll
        for (int jt = 0; jt < 8; ++jt) {
            int j = jt * 16 + l16;
            float s = (j >= jlo && j <= jhi) ? sc[jt][reg] * scale : -1e30f;
            sc[jt][reg] = s;
            m = fmaxf(m, s);
        }
        mx[reg] = m;

        int nvis = rc < 16 ? rc : 16;
        int clo = rc - nvis, chi = rc - 1;
        float m2 = -1e30f;
#pragma unroll
        for (int jt = 0; jt < 2; ++jt) {
            int c = cmin + jt * 16 + l16;
            float s = (c >= clo && c <= chi) ? sc2[jt][reg] * scale : -1e30f;
            sc2[jt][reg] = s;
            m2 = fmaxf(m2, s);
        }
        mx2[reg] = m2;
    }
#pragma unroll
    for (int off = 1; off <= 8; off <<= 1)
#pragma unroll
        for (int reg = 0; reg < 4; ++reg) {
            mx[reg]  = fmaxf(mx[reg],  __shfl_xor(mx[reg],  off));
            mx2[reg] = fmaxf(mx2[reg], __shfl_xor(mx2[reg], off));
        }
#pragma unroll
    for (int reg = 0; reg < 4; ++reg) {
        float s = 0.f, s2 = 0.f;
#pragma unroll
        for (int jt = 0; jt < 8; ++jt) {
            float p = __expf(sc[jt][reg] - mx[reg]);
            sc[jt][reg] = p;
            s += p;
        }
#pragma unroll
        for (int jt = 0; jt < 2; ++jt) {
            float p = __expf(sc2[jt][reg] - mx2[reg]);
            sc2[jt][reg] = p;
            s2 += p;
        }
        sm[reg] = s; sm2[reg] = s2;
    }
#pragma unroll
    for (int off = 1; off <= 8; off <<= 1)
#pragma unroll
        for (int reg = 0; reg < 4; ++reg) {
            sm[reg]  += __shfl_xor(sm[reg],  off);
            sm2[reg] += __shfl_xor(sm2[reg], off);
        }

#pragma unroll
    for (int reg = 0; reg < 4; ++reg) {
        float f1 = gl[reg] / sm[reg];
        float f2 = g2[reg] / sm2[reg];
        int rowoff = (rbase + reg) * PSTR;
#pragma unroll
        for (int jt = 0; jt < 8; ++jt) {
            __hip_bfloat16 hb = (__hip_bfloat16)(sc[jt][reg] * f1);
            Pls[rowoff + jt * 16 + l16] = *(unsigned short*)&hb;
        }
#pragma unroll
        for (int jt = 0; jt < 2; ++jt) {
            __hip_bfloat16 hb = (__hip_bfloat16)(sc2[jt][reg] * f2);
            Pls[rowoff + 128 + jt * 16 + l16] = *(unsigned short*)&hb;
        }
    }
    asm volatile("s_waitcnt lgkmcnt(0)" ::: "memory");  // wave-private P round-trip

    f32x4 o[4];
#pragma unroll
    for (int nt = 0; nt < 4; ++nt) o[nt] = (f32x4){0.f, 0.f, 0.f, 0.f};
#pragma unroll
    for (int kt = 0; kt < 5; ++kt) {
        short8 a = *(const short8*)&Pls[(w * 16 + l16) * PSTR + kt * 32 + quad * 8];
#pragma unroll
        for (int nt = 0; nt < 4; ++nt) {
            int dd = nt * 16 + l16;
            short8 b = *(const short8*)&Vts[dd * PSTR + kt * 32 + quad * 8];
            o[nt] = __builtin_amdgcn_mfma_f32_16x16x32_bf16(a, b, o[nt], 0, 0, 0);
        }
    }

#pragma unroll
    for (int nt = 0; nt < 4; ++nt) {
#pragma unroll
        for (int reg = 0; reg < 4; ++reg) {
            int row = t0 + rbase + reg;
            int col = h * 64 + nt * 16 + l16;
            Aout[(size_t)row * DM + col] = (__hip_bfloat16)(o[nt][reg]);
        }
    }
}

extern "C" void kernel_launch(void* const* d_in, const int* in_sizes, int n_in,
                              void* d_out, int out_size, void* d_ws, size_t ws_size,
                              hipStream_t stream)
{
    const float* x  = (const float*)d_in[0];
    const float* Wq = (const float*)d_in[1];
    const float* bq = (const float*)d_in[2];
    const float* Wk = (const float*)d_in[3];
    const float* bk = (const float*)d_in[4];
    const float* Wv = (const float*)d_in[5];
    const float* bv = (const float*)d_in[6];
    const float* Wo = (const float*)d_in[7];
    const float* bo = (const float*)d_in[8];
    const float* Wg = (const float*)d_in[9];
    const float* bg = (const float*)d_in[10];
    float* out = (float*)d_out;

    char* ws = (char*)d_ws;
    const size_t MB = 1024 * 1024;
    __hip_bfloat16* xb  = (__hip_bfloat16*)(ws + 0 * MB);   // 8 MB
    __hip_bfloat16* Qb  = (__hip_bfloat16*)(ws + 8 * MB);   // 8 MB
    __hip_bfloat16* Kb  = (__hip_bfloat16*)(ws + 16 * MB);  // 8 MB
    __hip_bfloat16* Vb  = (__hip_bfloat16*)(ws + 24 * MB);  // 8 MB
    __hip_bfloat16* Ab  = (__hip_bfloat16*)(ws + 32 * MB);  // 8 MB
    __hip_bfloat16* Wqb = (__hip_bfloat16*)(ws + 40 * MB);  // 2 MB
    __hip_bfloat16* Wkb = (__hip_bfloat16*)(ws + 42 * MB);  // 2 MB
    __hip_bfloat16* Wvb = (__hip_bfloat16*)(ws + 44 * MB);  // 2 MB
    __hip_bfloat16* Wob = (__hip_bfloat16*)(ws + 46 * MB);  // 2 MB
    __hip_bfloat16* CKb = (__hip_bfloat16*)(ws + 48 * MB);            // 256 KB
    __hip_bfloat16* CVb = (__hip_bfloat16*)(ws + 48 * MB + 256*1024); // 256 KB
    float* Gf           = (float*)(ws + 48 * MB + 512 * 1024);        // 256 KB
    __hip_bfloat16* Wgb = (__hip_bfloat16*)(ws + 48 * MB + 768*1024); // 32 KB

    cast_all<<<dim3(8208), 256, 0, stream>>>(x, Wq, Wk, Wv, Wo, Wg,
                                             xb, Wqb, Wkb, Wvb, Wob, Wgb);

    // Fused QKV GEMM: grid (32, 24); group = blockIdx.y>>3.
    gemm128<__hip_bfloat16><<<dim3(32, 24), 256, 0, stream>>>(
        xb, Wqb, Wkb, Wvb, bq, bk, bv, Qb, Kb, Vb);
    g_mfma<<<dim3(256), 64, 0, stream>>>(xb, Wgb, bg, Gf);
    chunk_kernel<<<dim3(128, 4), 256, 0, stream>>>(Kb, Vb, CKb, CVb);
    attn_mfma<<<dim3(64, 16), 256, 0, stream>>>(Qb, Kb, Vb, CKb, CVb, Gf, Ab);
    // Output GEMM: 128x64 tiles, grid (32, 16) = 512 blocks.
    gemm_n64<float><<<dim3(32, 16), 256, 0, stream>>>(Ab, Wob, bo, out);
}

// Round 4
// 179.951 us; speedup vs baseline: 1.1924x; 1.0233x over previous
//
#include <hip/hip_runtime.h>
#include <hip/hip_bf16.h>
#include <math.h>

typedef __attribute__((ext_vector_type(8))) short short8;
typedef __attribute__((ext_vector_type(4))) float f32x4;

#define TT 4096
#define DM 1024
#define NH 16
#define HD 64
#define PSTR 168   // attn LDS row stride in halfwords (84 dwords == 20 mod 32 banks)

typedef __attribute__((address_space(3))) unsigned int lds_u32;
typedef __attribute__((address_space(1))) unsigned int glb_u32;

__device__ __forceinline__ void async_cp16(const void* g, void* l) {
    __builtin_amdgcn_global_load_lds((glb_u32*)g, (lds_u32*)l, 16, 0, 0);
}

// Fused fp32 -> bf16 cast for x + Wq/Wk/Wv/Wo + Wg.
__global__ __launch_bounds__(256) void cast_all(
    const float* __restrict__ x,  const float* __restrict__ wq,
    const float* __restrict__ wk, const float* __restrict__ wv,
    const float* __restrict__ wo, const float* __restrict__ wg,
    __hip_bfloat16* __restrict__ xb,  __hip_bfloat16* __restrict__ wqb,
    __hip_bfloat16* __restrict__ wkb, __hip_bfloat16* __restrict__ wvb,
    __hip_bfloat16* __restrict__ wob, __hip_bfloat16* __restrict__ wgb)
{
    int b = blockIdx.x;
    const float* src;
    __hip_bfloat16* dst;
    size_t base;
    if (b < 4096)      { src = x;  dst = xb;  base = (size_t)b * 1024; }
    else if (b < 5120) { src = wq; dst = wqb; base = (size_t)(b - 4096) * 1024; }
    else if (b < 6144) { src = wk; dst = wkb; base = (size_t)(b - 5120) * 1024; }
    else if (b < 7168) { src = wv; dst = wvb; base = (size_t)(b - 6144) * 1024; }
    else if (b < 8192) { src = wo; dst = wob; base = (size_t)(b - 7168) * 1024; }
    else               { src = wg; dst = wgb; base = (size_t)(b - 8192) * 1024; }
    size_t i = base + (size_t)threadIdx.x * 4;
    float4 v = *(const float4*)(src + i);
    __hip_bfloat16 h0 = (__hip_bfloat16)v.x;
    __hip_bfloat16 h1 = (__hip_bfloat16)v.y;
    __hip_bfloat16 h2 = (__hip_bfloat16)v.z;
    __hip_bfloat16 h3 = (__hip_bfloat16)v.w;
    ushort4 u;
    u.x = *(unsigned short*)&h0;
    u.y = *(unsigned short*)&h1;
    u.z = *(unsigned short*)&h2;
    u.w = *(unsigned short*)&h3;
    *(ushort4*)((unsigned short*)dst + i) = u;
}

// 128x128-tile GEMM, BK=32, DOUBLE-BUFFERED pipeline (T3-minimum):
// stage(next) issued BEFORE compute(cur); one __syncthreads per step whose
// vmcnt(0) drain overlaps the whole MFMA phase. LDS 2x16=32 KB (prior
// session's 64 KB dbuf regression was a different config). Round-3 lesson:
// BK=64 single-buffer regressed (43->50 us) -- the cost is the
// un-overlapped drain, not the barrier count.
// Grid (M/128, 8*ngroups): group = blockIdx.y>>3 selects B/bias/O (QKV fusion).
template <typename OutT>
__global__ __launch_bounds__(256) void gemm128(
    const __hip_bfloat16* __restrict__ A,
    const __hip_bfloat16* __restrict__ B0, const __hip_bfloat16* __restrict__ B1,
    const __hip_bfloat16* __restrict__ B2,
    const float* __restrict__ c0, const float* __restrict__ c1, const float* __restrict__ c2,
    OutT* __restrict__ O0, OutT* __restrict__ O1, OutT* __restrict__ O2)
{
    const int K = DM;
    __shared__ __align__(16) unsigned short sA[2 * 128 * 32];
    __shared__ __align__(16) unsigned short sB[2 * 128 * 32];

    const int grp = blockIdx.y >> 3;
    const __hip_bfloat16* B = grp == 0 ? B0 : (grp == 1 ? B1 : B2);
    const float* bias       = grp == 0 ? c0 : (grp == 1 ? c1 : c2);
    OutT* O                 = grp == 0 ? O0 : (grp == 1 ? O1 : O2);

    const int tid  = threadIdx.x;
    const int w    = tid >> 6;
    const int lane = tid & 63;
    const int l16  = lane & 15;
    const int quad = lane >> 4;
    const int rowBase = blockIdx.x * 128;
    const int colBase = (blockIdx.y & 7) * 128;

    const int srow   = lane >> 2;
    const int sswz   = (srow & 3) ^ (srow >> 2);
    const int gchunk = (lane & 3) ^ sswz;
    const __hip_bfloat16* gA = A + (size_t)(rowBase + w * 32 + srow) * K + gchunk * 8;
    const __hip_bfloat16* gB = B + (size_t)(colBase + w * 32 + srow) * K + gchunk * 8;
    unsigned short* lA0 = sA + w * 32 * 32;
    unsigned short* lB0 = sB + w * 32 * 32;

    const int fswz = (l16 & 3) ^ (l16 >> 2);
    const int mrow = (w & 1) * 64;
    const int ncol = (w >> 1) * 64;

    f32x4 acc[4][4];
#pragma unroll
    for (int i = 0; i < 4; ++i)
#pragma unroll
        for (int j = 0; j < 4; ++j) acc[i][j] = (f32x4){0.f, 0.f, 0.f, 0.f};

    // Prologue: stage k0=0 into buf 0.
    {
        unsigned short* lA = lA0;
        unsigned short* lB = lB0;
        async_cp16(gA, lA);
        async_cp16(gA + (size_t)16 * K, lA + 16 * 32);
        async_cp16(gB, lB);
        async_cp16(gB + (size_t)16 * K, lB + 16 * 32);
    }
    __syncthreads();   // vmcnt(0) drain + barrier: buf0 ready

    int cur = 0;
    for (int k0 = 0; k0 < K; k0 += 32) {
        // Issue next tile's loads into the other buffer (no wait).
        if (k0 + 32 < K) {
            unsigned short* lA = lA0 + (cur ^ 1) * 128 * 32;
            unsigned short* lB = lB0 + (cur ^ 1) * 128 * 32;
            async_cp16(gA + k0 + 32,                  lA);
            async_cp16(gA + k0 + 32 + (size_t)16 * K, lA + 16 * 32);
            async_cp16(gB + k0 + 32,                  lB);
            async_cp16(gB + k0 + 32 + (size_t)16 * K, lB + 16 * 32);
        }

        const unsigned short* pA = sA + cur * 128 * 32;
        const unsigned short* pB = sB + cur * 128 * 32;
        short8 af[4], bf[4];
#pragma unroll
        for (int mt = 0; mt < 4; ++mt)
            af[mt] = *(const short8*)&pA[(mrow + mt * 16 + l16) * 32 + (quad ^ fswz) * 8];
#pragma unroll
        for (int nt = 0; nt < 4; ++nt)
            bf[nt] = *(const short8*)&pB[(ncol + nt * 16 + l16) * 32 + (quad ^ fswz) * 8];
#pragma unroll
        for (int mt = 0; mt < 4; ++mt)
#pragma unroll
            for (int nt = 0; nt < 4; ++nt)
                acc[mt][nt] = __builtin_amdgcn_mfma_f32_16x16x32_bf16(af[mt], bf[nt], acc[mt][nt], 0, 0, 0);

        __syncthreads();   // drains this step's prefetch; protects buf reuse
        cur ^= 1;
    }

#pragma unroll
    for (int nt = 0; nt < 4; ++nt) {
        int col = colBase + ncol + nt * 16 + l16;
        float bv = bias[col];
#pragma unroll
        for (int mt = 0; mt < 4; ++mt) {
#pragma unroll
            for (int r = 0; r < 4; ++r) {
                int row = rowBase + mrow + mt * 16 + quad * 4 + r;
                O[(size_t)row * DM + col] = (OutT)(acc[mt][nt][r] + bv);
            }
        }
    }
}

// 128x64-tile GEMM for the Wo projection, BK=32, same double-buffered
// pipeline as gemm128. LDS 2x12=24 KB, grid (32,16) = 512 blocks.
template <typename OutT>
__global__ __launch_bounds__(256) void gemm_n64(
    const __hip_bfloat16* __restrict__ A,
    const __hip_bfloat16* __restrict__ B,
    const float* __restrict__ bias,
    OutT* __restrict__ O)
{
    const int K = DM;
    __shared__ __align__(16) unsigned short sA[2 * 128 * 32];
    __shared__ __align__(16) unsigned short sB[2 * 64 * 32];

    const int tid  = threadIdx.x;
    const int w    = tid >> 6;
    const int lane = tid & 63;
    const int l16  = lane & 15;
    const int quad = lane >> 4;
    const int rowBase = blockIdx.x * 128;
    const int colBase = blockIdx.y * 64;

    const int srow   = lane >> 2;
    const int sswz   = (srow & 3) ^ (srow >> 2);
    const int gchunk = (lane & 3) ^ sswz;
    const __hip_bfloat16* gA = A + (size_t)(rowBase + w * 32 + srow) * K + gchunk * 8;
    const __hip_bfloat16* gB = B + (size_t)(colBase + w * 16 + srow) * K + gchunk * 8;
    unsigned short* lA0 = sA + w * 32 * 32;
    unsigned short* lB0 = sB + w * 16 * 32;

    const int fswz = (l16 & 3) ^ (l16 >> 2);
    const int mrow = w * 32;

    f32x4 acc[2][4];
#pragma unroll
    for (int i = 0; i < 2; ++i)
#pragma unroll
        for (int j = 0; j < 4; ++j) acc[i][j] = (f32x4){0.f, 0.f, 0.f, 0.f};

    // Prologue: stage k0=0 into buf 0.
    {
        async_cp16(gA, lA0);
        async_cp16(gA + (size_t)16 * K, lA0 + 16 * 32);
        async_cp16(gB, lB0);
    }
    __syncthreads();

    int cur = 0;
    for (int k0 = 0; k0 < K; k0 += 32) {
        if (k0 + 32 < K) {
            unsigned short* lA = lA0 + (cur ^ 1) * 128 * 32;
            unsigned short* lB = lB0 + (cur ^ 1) * 64 * 32;
            async_cp16(gA + k0 + 32,                  lA);
            async_cp16(gA + k0 + 32 + (size_t)16 * K, lA + 16 * 32);
            async_cp16(gB + k0 + 32,                  lB);
        }

        const unsigned short* pA = sA + cur * 128 * 32;
        const unsigned short* pB = sB + cur * 64 * 32;
        short8 af[2], bf[4];
#pragma unroll
        for (int mt = 0; mt < 2; ++mt)
            af[mt] = *(const short8*)&pA[(mrow + mt * 16 + l16) * 32 + (quad ^ fswz) * 8];
#pragma unroll
        for (int nt = 0; nt < 4; ++nt)
            bf[nt] = *(const short8*)&pB[(nt * 16 + l16) * 32 + (quad ^ fswz) * 8];
#pragma unroll
        for (int mt = 0; mt < 2; ++mt)
#pragma unroll
            for (int nt = 0; nt < 4; ++nt)
                acc[mt][nt] = __builtin_amdgcn_mfma_f32_16x16x32_bf16(af[mt], bf[nt], acc[mt][nt], 0, 0, 0);

        __syncthreads();
        cur ^= 1;
    }

#pragma unroll
    for (int nt = 0; nt < 4; ++nt) {
        int col = colBase + nt * 16 + l16;
        float bv = bias[col];
#pragma unroll
        for (int mt = 0; mt < 2; ++mt) {
#pragma unroll
            for (int r = 0; r < 4; ++r) {
                int row = rowBase + mrow + mt * 16 + quad * 4 + r;
                O[(size_t)row * DM + col] = (OutT)(acc[mt][nt][r] + bv);
            }
        }
    }
}

// Gate GEMM via MFMA: G[t,h] = sigmoid(xb[t,:] . Wgb[h,:] + bg[h]).
__global__ __launch_bounds__(64) void g_mfma(
    const __hip_bfloat16* __restrict__ xb,
    const __hip_bfloat16* __restrict__ Wgb,
    const float* __restrict__ bg,
    float* __restrict__ G)
{
    const int lane = threadIdx.x;
    const int l16  = lane & 15;
    const int quad = lane >> 4;
    const int t0   = blockIdx.x * 16;
    const __hip_bfloat16* ap = xb + (size_t)(t0 + l16) * DM + quad * 8;
    const __hip_bfloat16* bp = Wgb + (size_t)l16 * DM + quad * 8;
    f32x4 acc = (f32x4){0.f, 0.f, 0.f, 0.f};
#pragma unroll 4
    for (int k0 = 0; k0 < DM; k0 += 32) {
        short8 a = *(const short8*)(ap + k0);
        short8 b = *(const short8*)(bp + k0);
        acc = __builtin_amdgcn_mfma_f32_16x16x32_bf16(a, b, acc, 0, 0, 0);
    }
    float bgv = bg[l16];
#pragma unroll
    for (int r = 0; r < 4; ++r) {
        int t = t0 + quad * 4 + r;
        float z = acc[r] + bgv;
        G[t * NH + l16] = 1.f / (1.f + __expf(-z));
    }
}

// Chunk means over 32 consecutive tokens: CK[c,:], CV[c,:], c = 0..127.
__global__ __launch_bounds__(256) void chunk_kernel(
    const __hip_bfloat16* __restrict__ K,
    const __hip_bfloat16* __restrict__ V,
    __hip_bfloat16* __restrict__ CK,
    __hip_bfloat16* __restrict__ CV)
{
    const int c = blockIdx.x;
    const int d = blockIdx.y * 256 + threadIdx.x;
    float ak = 0.f, av = 0.f;
    for (int i = 0; i < 32; ++i) {
        ak += (float)K[(size_t)(c * 32 + i) * DM + d];
        av += (float)V[(size_t)(c * 32 + i) * DM + d];
    }
    CK[(size_t)c * DM + d] = (__hip_bfloat16)(ak * (1.f / 32.f));
    CV[(size_t)c * DM + d] = (__hip_bfloat16)(av * (1.f / 32.f));
}

// MFMA attention: 64 queries x 1 head per block (grid 64 x 16, 256 threads).
__global__ __launch_bounds__(256) void attn_mfma(
    const __hip_bfloat16* __restrict__ Q,
    const __hip_bfloat16* __restrict__ K,
    const __hip_bfloat16* __restrict__ V,
    const __hip_bfloat16* __restrict__ CK,
    const __hip_bfloat16* __restrict__ CV,
    const float* __restrict__ G,
    __hip_bfloat16* __restrict__ Aout)
{
    __shared__ alignas(16) unsigned short Pls[64 * PSTR];
    __shared__ alignas(16) unsigned short Vts[64 * PSTR];

    const int h   = blockIdx.y;
    const int t0  = blockIdx.x * 64;
    const int tid = threadIdx.x;
    const int w    = tid >> 6;
    const int lane = tid & 63;
    const int l16  = lane & 15;
    const int quad = lane >> 4;
    const float scale = 0.125f;

    const int rc0  = (t0 >= 96) ? ((t0 - 64) >> 5) : 0;
    const int cmin = rc0 > 16 ? rc0 - 16 : 0;

    const unsigned short* Vu  = (const unsigned short*)V;
    const unsigned short* CVu = (const unsigned short*)CV;

    // ---- stage V^T (+ CV^T) into LDS via 16B row-chunk loads + packed writes.
    // Wave w owns dim-groups g = 2w, 2w+1; lane owns slot-pair (2*pair, 2*pair+1).
    // ushort2 LDS writes land on consecutive dwords across the wave (2-way, free).
    {
#pragma unroll
        for (int gg = 0; gg < 2; ++gg) {
            const int g = w * 2 + gg;
#pragma unroll
            for (int i = 0; i < 2; ++i) {
                const int pair = lane + 64 * i;
                if (pair < 80) {
                    const int j = pair * 2;
                    const unsigned short *s0, *s1;
                    if (j < 128) {
                        int tok0 = t0 - 64 + j; if (tok0 < 0) tok0 = 0;
                        int tok1 = t0 - 63 + j; if (tok1 < 0) tok1 = 0;
                        s0 = Vu + (size_t)tok0 * DM + h * 64 + g * 8;
                        s1 = Vu + (size_t)tok1 * DM + h * 64 + g * 8;
                    } else {
                        int c0 = cmin + (j - 128); if (c0 > 127) c0 = 127;
                        int c1 = c0 + 1;           if (c1 > 127) c1 = 127;
                        s0 = CVu + (size_t)c0 * DM + h * 64 + g * 8;
                        s1 = CVu + (size_t)c1 * DM + h * 64 + g * 8;
                    }
                    short8 v0 = *(const short8*)s0;
                    short8 v1 = *(const short8*)s1;
#pragma unroll
                    for (int e = 0; e < 8; ++e) {
                        ushort2 pk;
                        pk.x = (unsigned short)v0[e];
                        pk.y = (unsigned short)v1[e];
                        *(ushort2*)&Vts[(g * 8 + e) * PSTR + j] = pk;
                    }
                }
            }
        }
    }

    const __hip_bfloat16* qp = Q + (size_t)(t0 + w * 16 + l16) * DM + h * 64 + quad * 8;
    short8 qf0 = *(const short8*)(qp);
    short8 qf1 = *(const short8*)(qp + 32);

    f32x4 sc[8];
#pragma unroll
    for (int jt = 0; jt < 8; ++jt) {
        int j = jt * 16 + l16;
        int tok = t0 - 64 + j;
        tok = tok < 0 ? 0 : tok;
        const __hip_bfloat16* kp = K + (size_t)tok * DM + h * 64 + quad * 8;
        short8 b0 = *(const short8*)(kp);
        short8 b1 = *(const short8*)(kp + 32);
        f32x4 a = __builtin_amdgcn_mfma_f32_16x16x32_bf16(qf0, b0, (f32x4){0.f,0.f,0.f,0.f}, 0, 0, 0);
        sc[jt]  = __builtin_amdgcn_mfma_f32_16x16x32_bf16(qf1, b1, a, 0, 0, 0);
    }
    f32x4 sc2[2];
#pragma unroll
    for (int jt = 0; jt < 2; ++jt) {
        int c = cmin + jt * 16 + l16;
        if (c > 127) c = 127;
        const __hip_bfloat16* cp = CK + (size_t)c * DM + h * 64 + quad * 8;
        short8 b0 = *(const short8*)(cp);
        short8 b1 = *(const short8*)(cp + 32);
        f32x4 a = __builtin_amdgcn_mfma_f32_16x16x32_bf16(qf0, b0, (f32x4){0.f,0.f,0.f,0.f}, 0, 0, 0);
        sc2[jt] = __builtin_amdgcn_mfma_f32_16x16x32_bf16(qf1, b1, a, 0, 0, 0);
    }

    __syncthreads();  // all waves' Vts writes visible before PV reads

    const int rbase = w * 16 + quad * 4;
    float gl[4], g2[4];
    float mx[4], sm[4], mx2[4], sm2[4];
#pragma unroll
    for (int reg = 0; reg < 4; ++reg) {
        int rr = rbase + reg;
        int t  = t0 + rr;
        float g = G[t * NH + h];
        int rc = (t >= 96) ? ((t - 64) >> 5) : 0;
        gl[reg] = (t > 0)  ? g        : 0.f;
        g2[reg] = (rc > 0) ? (1.f - g) : 0.f;

        int jlo = rr > (64 - t0) ? rr : (64 - t0);
        int jhi = rr + 63;
        float m = -1e30f;
#pragma unroll
        for (int jt = 0; jt < 8; ++jt) {
            int j = jt * 16 + l16;
            float s = (j >= jlo && j <= jhi) ? sc[jt][reg] * scale : -1e30f;
            sc[jt][reg] = s;
            m = fmaxf(m, s);
        }
        mx[reg] = m;

        int nvis = rc < 16 ? rc : 16;
        int clo = rc - nvis, chi = rc - 1;
        float m2 = -1e30f;
#pragma unroll
        for (int jt = 0; jt < 2; ++jt) {
            int c = cmin + jt * 16 + l16;
            float s = (c >= clo && c <= chi) ? sc2[jt][reg] * scale : -1e30f;
            sc2[jt][reg] = s;
            m2 = fmaxf(m2, s);
        }
        mx2[reg] = m2;
    }
#pragma unroll
    for (int off = 1; off <= 8; off <<= 1)
#pragma unroll
        for (int reg = 0; reg < 4; ++reg) {
            mx[reg]  = fmaxf(mx[reg],  __shfl_xor(mx[reg],  off));
            mx2[reg] = fmaxf(mx2[reg], __shfl_xor(mx2[reg], off));
        }
#pragma unroll
    for (int reg = 0; reg < 4; ++reg) {
        float s = 0.f, s2 = 0.f;
#pragma unroll
        for (int jt = 0; jt < 8; ++jt) {
            float p = __expf(sc[jt][reg] - mx[reg]);
            sc[jt][reg] = p;
            s += p;
        }
#pragma unroll
        for (int jt = 0; jt < 2; ++jt) {
            float p = __expf(sc2[jt][reg] - mx2[reg]);
            sc2[jt][reg] = p;
            s2 += p;
        }
        sm[reg] = s; sm2[reg] = s2;
    }
#pragma unroll
    for (int off = 1; off <= 8; off <<= 1)
#pragma unroll
        for (int reg = 0; reg < 4; ++reg) {
            sm[reg]  += __shfl_xor(sm[reg],  off);
            sm2[reg] += __shfl_xor(sm2[reg], off);
        }

#pragma unroll
    for (int reg = 0; reg < 4; ++reg) {
        float f1 = gl[reg] / sm[reg];
        float f2 = g2[reg] / sm2[reg];
        int rowoff = (rbase + reg) * PSTR;
#pragma unroll
        for (int jt = 0; jt < 8; ++jt) {
            __hip_bfloat16 hb = (__hip_bfloat16)(sc[jt][reg] * f1);
            Pls[rowoff + jt * 16 + l16] = *(unsigned short*)&hb;
        }
#pragma unroll
        for (int jt = 0; jt < 2; ++jt) {
            __hip_bfloat16 hb = (__hip_bfloat16)(sc2[jt][reg] * f2);
            Pls[rowoff + 128 + jt * 16 + l16] = *(unsigned short*)&hb;
        }
    }
    asm volatile("s_waitcnt lgkmcnt(0)" ::: "memory");  // wave-private P round-trip

    f32x4 o[4];
#pragma unroll
    for (int nt = 0; nt < 4; ++nt) o[nt] = (f32x4){0.f, 0.f, 0.f, 0.f};
#pragma unroll
    for (int kt = 0; kt < 5; ++kt) {
        short8 a = *(const short8*)&Pls[(w * 16 + l16) * PSTR + kt * 32 + quad * 8];
#pragma unroll
        for (int nt = 0; nt < 4; ++nt) {
            int dd = nt * 16 + l16;
            short8 b = *(const short8*)&Vts[dd * PSTR + kt * 32 + quad * 8];
            o[nt] = __builtin_amdgcn_mfma_f32_16x16x32_bf16(a, b, o[nt], 0, 0, 0);
        }
    }

#pragma unroll
    for (int nt = 0; nt < 4; ++nt) {
#pragma unroll
        for (int reg = 0; reg < 4; ++reg) {
            int row = t0 + rbase + reg;
            int col = h * 64 + nt * 16 + l16;
            Aout[(size_t)row * DM + col] = (__hip_bfloat16)(o[nt][reg]);
        }
    }
}

extern "C" void kernel_launch(void* const* d_in, const int* in_sizes, int n_in,
                              void* d_out, int out_size, void* d_ws, size_t ws_size,
                              hipStream_t stream)
{
    const float* x  = (const float*)d_in[0];
    const float* Wq = (const float*)d_in[1];
    const float* bq = (const float*)d_in[2];
    const float* Wk = (const float*)d_in[3];
    const float* bk = (const float*)d_in[4];
    const float* Wv = (const float*)d_in[5];
    const float* bv = (const float*)d_in[6];
    const float* Wo = (const float*)d_in[7];
    const float* bo = (const float*)d_in[8];
    const float* Wg = (const float*)d_in[9];
    const float* bg = (const float*)d_in[10];
    float* out = (float*)d_out;

    char* ws = (char*)d_ws;
    const size_t MB = 1024 * 1024;
    __hip_bfloat16* xb  = (__hip_bfloat16*)(ws + 0 * MB);   // 8 MB
    __hip_bfloat16* Qb  = (__hip_bfloat16*)(ws + 8 * MB);   // 8 MB
    __hip_bfloat16* Kb  = (__hip_bfloat16*)(ws + 16 * MB);  // 8 MB
    __hip_bfloat16* Vb  = (__hip_bfloat16*)(ws + 24 * MB);  // 8 MB
    __hip_bfloat16* Ab  = (__hip_bfloat16*)(ws + 32 * MB);  // 8 MB
    __hip_bfloat16* Wqb = (__hip_bfloat16*)(ws + 40 * MB);  // 2 MB
    __hip_bfloat16* Wkb = (__hip_bfloat16*)(ws + 42 * MB);  // 2 MB
    __hip_bfloat16* Wvb = (__hip_bfloat16*)(ws + 44 * MB);  // 2 MB
    __hip_bfloat16* Wob = (__hip_bfloat16*)(ws + 46 * MB);  // 2 MB
    __hip_bfloat16* CKb = (__hip_bfloat16*)(ws + 48 * MB);            // 256 KB
    __hip_bfloat16* CVb = (__hip_bfloat16*)(ws + 48 * MB + 256*1024); // 256 KB
    float* Gf           = (float*)(ws + 48 * MB + 512 * 1024);        // 256 KB
    __hip_bfloat16* Wgb = (__hip_bfloat16*)(ws + 48 * MB + 768*1024); // 32 KB

    cast_all<<<dim3(8208), 256, 0, stream>>>(x, Wq, Wk, Wv, Wo, Wg,
                                             xb, Wqb, Wkb, Wvb, Wob, Wgb);

    // Fused QKV GEMM: grid (32, 24); group = blockIdx.y>>3.
    gemm128<__hip_bfloat16><<<dim3(32, 24), 256, 0, stream>>>(
        xb, Wqb, Wkb, Wvb, bq, bk, bv, Qb, Kb, Vb);
    g_mfma<<<dim3(256), 64, 0, stream>>>(xb, Wgb, bg, Gf);
    chunk_kernel<<<dim3(128, 4), 256, 0, stream>>>(Kb, Vb, CKb, CVb);
    attn_mfma<<<dim3(64, 16), 256, 0, stream>>>(Qb, Kb, Vb, CKb, CVb, Gf, Ab);
    // Output GEMM: 128x64 tiles, grid (32, 16) = 512 blocks.
    gemm_n64<float><<<dim3(32, 16), 256, 0, stream>>>(Ab, Wob, bo, out);
}

// Round 5
// 178.310 us; speedup vs baseline: 1.2034x; 1.0092x over previous
//
#include <hip/hip_runtime.h>
#include <hip/hip_bf16.h>
#include <math.h>

typedef __attribute__((ext_vector_type(8))) short short8;
typedef __attribute__((ext_vector_type(4))) float f32x4;

#define TT 4096
#define DM 1024
#define NH 16
#define HD 64
#define PSTR 168   // attn LDS row stride in halfwords (84 dwords == 20 mod 32 banks)

typedef __attribute__((address_space(3))) unsigned int lds_u32;
typedef __attribute__((address_space(1))) unsigned int glb_u32;

__device__ __forceinline__ void async_cp16(const void* g, void* l) {
    __builtin_amdgcn_global_load_lds((glb_u32*)g, (lds_u32*)l, 16, 0, 0);
}

__device__ __forceinline__ float bf2f(unsigned short u) {
    union { unsigned int i; float f; } v;
    v.i = (unsigned int)u << 16;
    return v.f;
}

// Fused fp32 -> bf16 cast for x + Wq/Wk/Wv/Wo + Wg.
__global__ __launch_bounds__(256) void cast_all(
    const float* __restrict__ x,  const float* __restrict__ wq,
    const float* __restrict__ wk, const float* __restrict__ wv,
    const float* __restrict__ wo, const float* __restrict__ wg,
    __hip_bfloat16* __restrict__ xb,  __hip_bfloat16* __restrict__ wqb,
    __hip_bfloat16* __restrict__ wkb, __hip_bfloat16* __restrict__ wvb,
    __hip_bfloat16* __restrict__ wob, __hip_bfloat16* __restrict__ wgb)
{
    int b = blockIdx.x;
    const float* src;
    __hip_bfloat16* dst;
    size_t base;
    if (b < 4096)      { src = x;  dst = xb;  base = (size_t)b * 1024; }
    else if (b < 5120) { src = wq; dst = wqb; base = (size_t)(b - 4096) * 1024; }
    else if (b < 6144) { src = wk; dst = wkb; base = (size_t)(b - 5120) * 1024; }
    else if (b < 7168) { src = wv; dst = wvb; base = (size_t)(b - 6144) * 1024; }
    else if (b < 8192) { src = wo; dst = wob; base = (size_t)(b - 7168) * 1024; }
    else               { src = wg; dst = wgb; base = (size_t)(b - 8192) * 1024; }
    size_t i = base + (size_t)threadIdx.x * 4;
    float4 v = *(const float4*)(src + i);
    __hip_bfloat16 h0 = (__hip_bfloat16)v.x;
    __hip_bfloat16 h1 = (__hip_bfloat16)v.y;
    __hip_bfloat16 h2 = (__hip_bfloat16)v.z;
    __hip_bfloat16 h3 = (__hip_bfloat16)v.w;
    ushort4 u;
    u.x = *(unsigned short*)&h0;
    u.y = *(unsigned short*)&h1;
    u.z = *(unsigned short*)&h2;
    u.w = *(unsigned short*)&h3;
    *(ushort4*)((unsigned short*)dst + i) = u;
}

// 128x128-tile GEMM, single-buffered (32 KB LDS). Round-0 anchor version:
// measured <43 us. Session ledger: BK=64 single-buf regressed (50.4 us, r3);
// explicit 2-deep dbuf neutral-to-negative (r4); chunk-mean epilogue fusion
// cost ~6 us (r2); gate fused as grid tail cost ~10 us (r1). Escape from the
// ~600 TF ceiling requires the full 8-phase 256^2 schedule, not single levers.
// Grid (M/128, 8*ngroups): group = blockIdx.y>>3 selects B/bias/O (QKV fusion).
template <typename OutT>
__global__ __launch_bounds__(256) void gemm128(
    const __hip_bfloat16* __restrict__ A,
    const __hip_bfloat16* __restrict__ B0, const __hip_bfloat16* __restrict__ B1,
    const __hip_bfloat16* __restrict__ B2,
    const float* __restrict__ c0, const float* __restrict__ c1, const float* __restrict__ c2,
    OutT* __restrict__ O0, OutT* __restrict__ O1, OutT* __restrict__ O2)
{
    const int K = DM;
    __shared__ __align__(16) unsigned short sA[128 * 32];
    __shared__ __align__(16) unsigned short sB[128 * 32];

    const int grp = blockIdx.y >> 3;
    const __hip_bfloat16* B = grp == 0 ? B0 : (grp == 1 ? B1 : B2);
    const float* bias       = grp == 0 ? c0 : (grp == 1 ? c1 : c2);
    OutT* O                 = grp == 0 ? O0 : (grp == 1 ? O1 : O2);

    const int tid  = threadIdx.x;
    const int w    = tid >> 6;
    const int lane = tid & 63;
    const int l16  = lane & 15;
    const int quad = lane >> 4;
    const int rowBase = blockIdx.x * 128;
    const int colBase = (blockIdx.y & 7) * 128;

    const int srow   = lane >> 2;
    const int sswz   = (srow & 3) ^ (srow >> 2);
    const int gchunk = (lane & 3) ^ sswz;
    const __hip_bfloat16* gA = A + (size_t)(rowBase + w * 32 + srow) * K + gchunk * 8;
    const __hip_bfloat16* gB = B + (size_t)(colBase + w * 32 + srow) * K + gchunk * 8;
    unsigned short* lA = sA + w * 32 * 32;
    unsigned short* lB = sB + w * 32 * 32;

    const int fswz = (l16 & 3) ^ (l16 >> 2);
    const int mrow = (w & 1) * 64;
    const int ncol = (w >> 1) * 64;

    f32x4 acc[4][4];
#pragma unroll
    for (int i = 0; i < 4; ++i)
#pragma unroll
        for (int j = 0; j < 4; ++j) acc[i][j] = (f32x4){0.f, 0.f, 0.f, 0.f};

    for (int k0 = 0; k0 < K; k0 += 32) {
        __syncthreads();
        async_cp16(gA + k0, lA);
        async_cp16(gA + k0 + (size_t)16 * K, lA + 16 * 32);
        async_cp16(gB + k0, lB);
        async_cp16(gB + k0 + (size_t)16 * K, lB + 16 * 32);
        __syncthreads();

        short8 af[4], bf[4];
#pragma unroll
        for (int mt = 0; mt < 4; ++mt)
            af[mt] = *(const short8*)&sA[(mrow + mt * 16 + l16) * 32 + (quad ^ fswz) * 8];
#pragma unroll
        for (int nt = 0; nt < 4; ++nt)
            bf[nt] = *(const short8*)&sB[(ncol + nt * 16 + l16) * 32 + (quad ^ fswz) * 8];
#pragma unroll
        for (int mt = 0; mt < 4; ++mt)
#pragma unroll
            for (int nt = 0; nt < 4; ++nt)
                acc[mt][nt] = __builtin_amdgcn_mfma_f32_16x16x32_bf16(af[mt], bf[nt], acc[mt][nt], 0, 0, 0);
    }

#pragma unroll
    for (int nt = 0; nt < 4; ++nt) {
        int col = colBase + ncol + nt * 16 + l16;
        float bv = bias[col];
#pragma unroll
        for (int mt = 0; mt < 4; ++mt) {
#pragma unroll
            for (int r = 0; r < 4; ++r) {
                int row = rowBase + mrow + mt * 16 + quad * 4 + r;
                O[(size_t)row * DM + col] = (OutT)(acc[mt][nt][r] + bv);
            }
        }
    }
}

// 128x64-tile GEMM for the Wo projection: 12 KB LDS, grid (32,16) = 512
// blocks (round-0 anchor version).
template <typename OutT>
__global__ __launch_bounds__(256) void gemm_n64(
    const __hip_bfloat16* __restrict__ A,
    const __hip_bfloat16* __restrict__ B,
    const float* __restrict__ bias,
    OutT* __restrict__ O)
{
    const int K = DM;
    __shared__ __align__(16) unsigned short sA[128 * 32];
    __shared__ __align__(16) unsigned short sB[64 * 32];

    const int tid  = threadIdx.x;
    const int w    = tid >> 6;
    const int lane = tid & 63;
    const int l16  = lane & 15;
    const int quad = lane >> 4;
    const int rowBase = blockIdx.x * 128;
    const int colBase = blockIdx.y * 64;

    const int srow   = lane >> 2;
    const int sswz   = (srow & 3) ^ (srow >> 2);
    const int gchunk = (lane & 3) ^ sswz;
    const __hip_bfloat16* gA = A + (size_t)(rowBase + w * 32 + srow) * K + gchunk * 8;
    const __hip_bfloat16* gB = B + (size_t)(colBase + w * 16 + srow) * K + gchunk * 8;
    unsigned short* lA = sA + w * 32 * 32;
    unsigned short* lB = sB + w * 16 * 32;

    const int fswz = (l16 & 3) ^ (l16 >> 2);
    const int mrow = w * 32;

    f32x4 acc[2][4];
#pragma unroll
    for (int i = 0; i < 2; ++i)
#pragma unroll
        for (int j = 0; j < 4; ++j) acc[i][j] = (f32x4){0.f, 0.f, 0.f, 0.f};

    for (int k0 = 0; k0 < K; k0 += 32) {
        __syncthreads();
        async_cp16(gA + k0, lA);
        async_cp16(gA + k0 + (size_t)16 * K, lA + 16 * 32);
        async_cp16(gB + k0, lB);
        __syncthreads();

        short8 af[2], bf[4];
#pragma unroll
        for (int mt = 0; mt < 2; ++mt)
            af[mt] = *(const short8*)&sA[(mrow + mt * 16 + l16) * 32 + (quad ^ fswz) * 8];
#pragma unroll
        for (int nt = 0; nt < 4; ++nt)
            bf[nt] = *(const short8*)&sB[(nt * 16 + l16) * 32 + (quad ^ fswz) * 8];
#pragma unroll
        for (int mt = 0; mt < 2; ++mt)
#pragma unroll
            for (int nt = 0; nt < 4; ++nt)
                acc[mt][nt] = __builtin_amdgcn_mfma_f32_16x16x32_bf16(af[mt], bf[nt], acc[mt][nt], 0, 0, 0);
    }

#pragma unroll
    for (int nt = 0; nt < 4; ++nt) {
        int col = colBase + nt * 16 + l16;
        float bv = bias[col];
#pragma unroll
        for (int mt = 0; mt < 2; ++mt) {
#pragma unroll
            for (int r = 0; r < 4; ++r) {
                int row = rowBase + mrow + mt * 16 + quad * 4 + r;
                O[(size_t)row * DM + col] = (OutT)(acc[mt][nt][r] + bv);
            }
        }
    }
}

// Merged auxiliary kernel (one dispatch instead of g_mfma + chunk_kernel):
//   blocks 0..255   : chunk means, ushort2-vectorized (G13; old version was
//                     scalar 2B/lane). block b: c = b>>1, d-halfspace = b&1;
//                     thread handles 2 consecutive d. Same i=0..31 summation
//                     order per element -> numerics identical.
//   blocks 256..319 : gate GEMM via MFMA, 4 x 16-token units per 256-thread
//                     block (same math as the old 64-thread g_mfma).
// Both halves are independent (gate reads xb; chunk reads Kb/Vb) and short;
// co-dispatch overlaps the gate's latency-bound blocks under the chunk's
// memory-bound blocks. (Round-1's bad fusion extended the QKV GEMM's tail;
// this merges two SMALL kernels only.)
__global__ __launch_bounds__(256) void aux_kernel(
    const __hip_bfloat16* __restrict__ K,
    const __hip_bfloat16* __restrict__ V,
    const __hip_bfloat16* __restrict__ xb,
    const __hip_bfloat16* __restrict__ Wgb,
    const float* __restrict__ bg,
    __hip_bfloat16* __restrict__ CK,
    __hip_bfloat16* __restrict__ CV,
    float* __restrict__ G)
{
    const int b = blockIdx.x;
    if (b < 256) {
        const int c  = b >> 1;
        const int d0 = (b & 1) * 512 + threadIdx.x * 2;
        const unsigned short* Ku = (const unsigned short*)K;
        const unsigned short* Vu = (const unsigned short*)V;
        float ak0 = 0.f, ak1 = 0.f, av0 = 0.f, av1 = 0.f;
#pragma unroll 8
        for (int i = 0; i < 32; ++i) {
            size_t off = (size_t)(c * 32 + i) * DM + d0;
            ushort2 kv = *(const ushort2*)(Ku + off);
            ushort2 vv = *(const ushort2*)(Vu + off);
            ak0 += bf2f(kv.x); ak1 += bf2f(kv.y);
            av0 += bf2f(vv.x); av1 += bf2f(vv.y);
        }
        __hip_bfloat16 k0 = (__hip_bfloat16)(ak0 * (1.f / 32.f));
        __hip_bfloat16 k1 = (__hip_bfloat16)(ak1 * (1.f / 32.f));
        __hip_bfloat16 v0 = (__hip_bfloat16)(av0 * (1.f / 32.f));
        __hip_bfloat16 v1 = (__hip_bfloat16)(av1 * (1.f / 32.f));
        ushort2 ko, vo;
        ko.x = *(unsigned short*)&k0; ko.y = *(unsigned short*)&k1;
        vo.x = *(unsigned short*)&v0; vo.y = *(unsigned short*)&v1;
        *(ushort2*)((unsigned short*)CK + (size_t)c * DM + d0) = ko;
        *(ushort2*)((unsigned short*)CV + (size_t)c * DM + d0) = vo;
        return;
    }
    // Gate: G[t,h] = sigmoid(xb[t,:] . Wgb[h,:] + bg[h]).
    const int unit = threadIdx.x >> 6;
    const int lane = threadIdx.x & 63;
    const int l16  = lane & 15;
    const int quad = lane >> 4;
    const int t0   = (b - 256) * 64 + unit * 16;
    const __hip_bfloat16* ap = xb  + (size_t)(t0 + l16) * DM + quad * 8;
    const __hip_bfloat16* bp = Wgb + (size_t)l16 * DM + quad * 8;
    f32x4 acc = (f32x4){0.f, 0.f, 0.f, 0.f};
#pragma unroll 4
    for (int k0 = 0; k0 < DM; k0 += 32) {
        short8 a = *(const short8*)(ap + k0);
        short8 bb = *(const short8*)(bp + k0);
        acc = __builtin_amdgcn_mfma_f32_16x16x32_bf16(a, bb, acc, 0, 0, 0);
    }
    float bgv = bg[l16];
#pragma unroll
    for (int r = 0; r < 4; ++r) {
        int t = t0 + quad * 4 + r;
        float z = acc[r] + bgv;
        G[t * NH + l16] = 1.f / (1.f + __expf(-z));
    }
}

// MFMA attention: 64 queries x 1 head per block (grid 64 x 16, 256 threads).
__global__ __launch_bounds__(256) void attn_mfma(
    const __hip_bfloat16* __restrict__ Q,
    const __hip_bfloat16* __restrict__ K,
    const __hip_bfloat16* __restrict__ V,
    const __hip_bfloat16* __restrict__ CK,
    const __hip_bfloat16* __restrict__ CV,
    const float* __restrict__ G,
    __hip_bfloat16* __restrict__ Aout)
{
    __shared__ alignas(16) unsigned short Pls[64 * PSTR];
    __shared__ alignas(16) unsigned short Vts[64 * PSTR];

    const int h   = blockIdx.y;
    const int t0  = blockIdx.x * 64;
    const int tid = threadIdx.x;
    const int w    = tid >> 6;
    const int lane = tid & 63;
    const int l16  = lane & 15;
    const int quad = lane >> 4;
    const float scale = 0.125f;

    const int rc0  = (t0 >= 96) ? ((t0 - 64) >> 5) : 0;
    const int cmin = rc0 > 16 ? rc0 - 16 : 0;

    const unsigned short* Vu  = (const unsigned short*)V;
    const unsigned short* CVu = (const unsigned short*)CV;

    // ---- stage V^T (+ CV^T) into LDS via 16B row-chunk loads + packed writes.
    {
#pragma unroll
        for (int gg = 0; gg < 2; ++gg) {
            const int g = w * 2 + gg;
#pragma unroll
            for (int i = 0; i < 2; ++i) {
                const int pair = lane + 64 * i;
                if (pair < 80) {
                    const int j = pair * 2;
                    const unsigned short *s0, *s1;
                    if (j < 128) {
                        int tok0 = t0 - 64 + j; if (tok0 < 0) tok0 = 0;
                        int tok1 = t0 - 63 + j; if (tok1 < 0) tok1 = 0;
                        s0 = Vu + (size_t)tok0 * DM + h * 64 + g * 8;
                        s1 = Vu + (size_t)tok1 * DM + h * 64 + g * 8;
                    } else {
                        int c0 = cmin + (j - 128); if (c0 > 127) c0 = 127;
                        int c1 = c0 + 1;           if (c1 > 127) c1 = 127;
                        s0 = CVu + (size_t)c0 * DM + h * 64 + g * 8;
                        s1 = CVu + (size_t)c1 * DM + h * 64 + g * 8;
                    }
                    short8 v0 = *(const short8*)s0;
                    short8 v1 = *(const short8*)s1;
#pragma unroll
                    for (int e = 0; e < 8; ++e) {
                        ushort2 pk;
                        pk.x = (unsigned short)v0[e];
                        pk.y = (unsigned short)v1[e];
                        *(ushort2*)&Vts[(g * 8 + e) * PSTR + j] = pk;
                    }
                }
            }
        }
    }

    const __hip_bfloat16* qp = Q + (size_t)(t0 + w * 16 + l16) * DM + h * 64 + quad * 8;
    short8 qf0 = *(const short8*)(qp);
    short8 qf1 = *(const short8*)(qp + 32);

    f32x4 sc[8];
#pragma unroll
    for (int jt = 0; jt < 8; ++jt) {
        int j = jt * 16 + l16;
        int tok = t0 - 64 + j;
        tok = tok < 0 ? 0 : tok;
        const __hip_bfloat16* kp = K + (size_t)tok * DM + h * 64 + quad * 8;
        short8 b0 = *(const short8*)(kp);
        short8 b1 = *(const short8*)(kp + 32);
        f32x4 a = __builtin_amdgcn_mfma_f32_16x16x32_bf16(qf0, b0, (f32x4){0.f,0.f,0.f,0.f}, 0, 0, 0);
        sc[jt]  = __builtin_amdgcn_mfma_f32_16x16x32_bf16(qf1, b1, a, 0, 0, 0);
    }
    f32x4 sc2[2];
#pragma unroll
    for (int jt = 0; jt < 2; ++jt) {
        int c = cmin + jt * 16 + l16;
        if (c > 127) c = 127;
        const __hip_bfloat16* cp = CK + (size_t)c * DM + h * 64 + quad * 8;
        short8 b0 = *(const short8*)(cp);
        short8 b1 = *(const short8*)(cp + 32);
        f32x4 a = __builtin_amdgcn_mfma_f32_16x16x32_bf16(qf0, b0, (f32x4){0.f,0.f,0.f,0.f}, 0, 0, 0);
        sc2[jt] = __builtin_amdgcn_mfma_f32_16x16x32_bf16(qf1, b1, a, 0, 0, 0);
    }

    __syncthreads();  // all waves' Vts writes visible before PV reads

    const int rbase = w * 16 + quad * 4;
    float gl[4], g2[4];
    float mx[4], sm[4], mx2[4], sm2[4];
#pragma unroll
    for (int reg = 0; reg < 4; ++reg) {
        int rr = rbase + reg;
        int t  = t0 + rr;
        float g = G[t * NH + h];
        int rc = (t >= 96) ? ((t - 64) >> 5) : 0;
        gl[reg] = (t > 0)  ? g        : 0.f;
        g2[reg] = (rc > 0) ? (1.f - g) : 0.f;

        int jlo = rr > (64 - t0) ? rr : (64 - t0);
        int jhi = rr + 63;
        float m = -1e30f;
#pragma unroll
        for (int jt = 0; jt < 8; ++jt) {
            int j = jt * 16 + l16;
            float s = (j >= jlo && j <= jhi) ? sc[jt][reg] * scale : -1e30f;
            sc[jt][reg] = s;
            m = fmaxf(m, s);
        }
        mx[reg] = m;

        int nvis = rc < 16 ? rc : 16;
        int clo = rc - nvis, chi = rc - 1;
        float m2 = -1e30f;
#pragma unroll
        for (int jt = 0; jt < 2; ++jt) {
            int c = cmin + jt * 16 + l16;
            float s = (c >= clo && c <= chi) ? sc2[jt][reg] * scale : -1e30f;
            sc2[jt][reg] = s;
            m2 = fmaxf(m2, s);
        }
        mx2[reg] = m2;
    }
#pragma unroll
    for (int off = 1; off <= 8; off <<= 1)
#pragma unroll
        for (int reg = 0; reg < 4; ++reg) {
            mx[reg]  = fmaxf(mx[reg],  __shfl_xor(mx[reg],  off));
            mx2[reg] = fmaxf(mx2[reg], __shfl_xor(mx2[reg], off));
        }
#pragma unroll
    for (int reg = 0; reg < 4; ++reg) {
        float s = 0.f, s2 = 0.f;
#pragma unroll
        for (int jt = 0; jt < 8; ++jt) {
            float p = __expf(sc[jt][reg] - mx[reg]);
            sc[jt][reg] = p;
            s += p;
        }
#pragma unroll
        for (int jt = 0; jt < 2; ++jt) {
            float p = __expf(sc2[jt][reg] - mx2[reg]);
            sc2[jt][reg] = p;
            s2 += p;
        }
        sm[reg] = s; sm2[reg] = s2;
    }
#pragma unroll
    for (int off = 1; off <= 8; off <<= 1)
#pragma unroll
        for (int reg = 0; reg < 4; ++reg) {
            sm[reg]  += __shfl_xor(sm[reg],  off);
            sm2[reg] += __shfl_xor(sm2[reg], off);
        }

#pragma unroll
    for (int reg = 0; reg < 4; ++reg) {
        float f1 = gl[reg] / sm[reg];
        float f2 = g2[reg] / sm2[reg];
        int rowoff = (rbase + reg) * PSTR;
#pragma unroll
        for (int jt = 0; jt < 8; ++jt) {
            __hip_bfloat16 hb = (__hip_bfloat16)(sc[jt][reg] * f1);
            Pls[rowoff + jt * 16 + l16] = *(unsigned short*)&hb;
        }
#pragma unroll
        for (int jt = 0; jt < 2; ++jt) {
            __hip_bfloat16 hb = (__hip_bfloat16)(sc2[jt][reg] * f2);
            Pls[rowoff + 128 + jt * 16 + l16] = *(unsigned short*)&hb;
        }
    }
    asm volatile("s_waitcnt lgkmcnt(0)" ::: "memory");  // wave-private P round-trip

    f32x4 o[4];
#pragma unroll
    for (int nt = 0; nt < 4; ++nt) o[nt] = (f32x4){0.f, 0.f, 0.f, 0.f};
#pragma unroll
    for (int kt = 0; kt < 5; ++kt) {
        short8 a = *(const short8*)&Pls[(w * 16 + l16) * PSTR + kt * 32 + quad * 8];
#pragma unroll
        for (int nt = 0; nt < 4; ++nt) {
            int dd = nt * 16 + l16;
            short8 b = *(const short8*)&Vts[dd * PSTR + kt * 32 + quad * 8];
            o[nt] = __builtin_amdgcn_mfma_f32_16x16x32_bf16(a, b, o[nt], 0, 0, 0);
        }
    }

#pragma unroll
    for (int nt = 0; nt < 4; ++nt) {
#pragma unroll
        for (int reg = 0; reg < 4; ++reg) {
            int row = t0 + rbase + reg;
            int col = h * 64 + nt * 16 + l16;
            Aout[(size_t)row * DM + col] = (__hip_bfloat16)(o[nt][reg]);
        }
    }
}

extern "C" void kernel_launch(void* const* d_in, const int* in_sizes, int n_in,
                              void* d_out, int out_size, void* d_ws, size_t ws_size,
                              hipStream_t stream)
{
    const float* x  = (const float*)d_in[0];
    const float* Wq = (const float*)d_in[1];
    const float* bq = (const float*)d_in[2];
    const float* Wk = (const float*)d_in[3];
    const float* bk = (const float*)d_in[4];
    const float* Wv = (const float*)d_in[5];
    const float* bv = (const float*)d_in[6];
    const float* Wo = (const float*)d_in[7];
    const float* bo = (const float*)d_in[8];
    const float* Wg = (const float*)d_in[9];
    const float* bg = (const float*)d_in[10];
    float* out = (float*)d_out;

    char* ws = (char*)d_ws;
    const size_t MB = 1024 * 1024;
    __hip_bfloat16* xb  = (__hip_bfloat16*)(ws + 0 * MB);   // 8 MB
    __hip_bfloat16* Qb  = (__hip_bfloat16*)(ws + 8 * MB);   // 8 MB
    __hip_bfloat16* Kb  = (__hip_bfloat16*)(ws + 16 * MB);  // 8 MB
    __hip_bfloat16* Vb  = (__hip_bfloat16*)(ws + 24 * MB);  // 8 MB
    __hip_bfloat16* Ab  = (__hip_bfloat16*)(ws + 32 * MB);  // 8 MB
    __hip_bfloat16* Wqb = (__hip_bfloat16*)(ws + 40 * MB);  // 2 MB
    __hip_bfloat16* Wkb = (__hip_bfloat16*)(ws + 42 * MB);  // 2 MB
    __hip_bfloat16* Wvb = (__hip_bfloat16*)(ws + 44 * MB);  // 2 MB
    __hip_bfloat16* Wob = (__hip_bfloat16*)(ws + 46 * MB);  // 2 MB
    __hip_bfloat16* CKb = (__hip_bfloat16*)(ws + 48 * MB);            // 256 KB
    __hip_bfloat16* CVb = (__hip_bfloat16*)(ws + 48 * MB + 256*1024); // 256 KB
    float* Gf           = (float*)(ws + 48 * MB + 512 * 1024);        // 256 KB
    __hip_bfloat16* Wgb = (__hip_bfloat16*)(ws + 48 * MB + 768*1024); // 32 KB

    cast_all<<<dim3(8208), 256, 0, stream>>>(x, Wq, Wk, Wv, Wo, Wg,
                                             xb, Wqb, Wkb, Wvb, Wob, Wgb);

    // Fused QKV GEMM: grid (32, 24); group = blockIdx.y>>3.
    gemm128<__hip_bfloat16><<<dim3(32, 24), 256, 0, stream>>>(
        xb, Wqb, Wkb, Wvb, bq, bk, bv, Qb, Kb, Vb);
    // Merged chunk-means + gate GEMM (one dispatch, independent halves).
    aux_kernel<<<dim3(320), 256, 0, stream>>>(Kb, Vb, xb, Wgb, bg, CKb, CVb, Gf);
    attn_mfma<<<dim3(64, 16), 256, 0, stream>>>(Qb, Kb, Vb, CKb, CVb, Gf, Ab);
    // Output GEMM: 128x64 tiles, grid (32, 16) = 512 blocks.
    gemm_n64<float><<<dim3(32, 16), 256, 0, stream>>>(Ab, Wob, bo, out);
}

// Round 6
// 177.413 us; speedup vs baseline: 1.2094x; 1.0051x over previous
//
#include <hip/hip_runtime.h>
#include <hip/hip_bf16.h>
#include <math.h>

typedef __attribute__((ext_vector_type(8))) short short8;
typedef __attribute__((ext_vector_type(4))) float f32x4;

#define TT 4096
#define DM 1024
#define NH 16
#define HD 64
#define PSTR 168   // attn LDS row stride in halfwords (84 dwords == 20 mod 32 banks)

typedef __attribute__((address_space(3))) unsigned int lds_u32;
typedef __attribute__((address_space(1))) unsigned int glb_u32;

__device__ __forceinline__ void async_cp16(const void* g, void* l) {
    __builtin_amdgcn_global_load_lds((glb_u32*)g, (lds_u32*)l, 16, 0, 0);
}

__device__ __forceinline__ float bf2f(unsigned short u) {
    union { unsigned int i; float f; } v;
    v.i = (unsigned int)u << 16;
    return v.f;
}

// Fused fp32 -> bf16 cast for x + Wq/Wk/Wv/Wo + Wg.
__global__ __launch_bounds__(256) void cast_all(
    const float* __restrict__ x,  const float* __restrict__ wq,
    const float* __restrict__ wk, const float* __restrict__ wv,
    const float* __restrict__ wo, const float* __restrict__ wg,
    __hip_bfloat16* __restrict__ xb,  __hip_bfloat16* __restrict__ wqb,
    __hip_bfloat16* __restrict__ wkb, __hip_bfloat16* __restrict__ wvb,
    __hip_bfloat16* __restrict__ wob, __hip_bfloat16* __restrict__ wgb)
{
    int b = blockIdx.x;
    const float* src;
    __hip_bfloat16* dst;
    size_t base;
    if (b < 4096)      { src = x;  dst = xb;  base = (size_t)b * 1024; }
    else if (b < 5120) { src = wq; dst = wqb; base = (size_t)(b - 4096) * 1024; }
    else if (b < 6144) { src = wk; dst = wkb; base = (size_t)(b - 5120) * 1024; }
    else if (b < 7168) { src = wv; dst = wvb; base = (size_t)(b - 6144) * 1024; }
    else if (b < 8192) { src = wo; dst = wob; base = (size_t)(b - 7168) * 1024; }
    else               { src = wg; dst = wgb; base = (size_t)(b - 8192) * 1024; }
    size_t i = base + (size_t)threadIdx.x * 4;
    float4 v = *(const float4*)(src + i);
    __hip_bfloat16 h0 = (__hip_bfloat16)v.x;
    __hip_bfloat16 h1 = (__hip_bfloat16)v.y;
    __hip_bfloat16 h2 = (__hip_bfloat16)v.z;
    __hip_bfloat16 h3 = (__hip_bfloat16)v.w;
    ushort4 u;
    u.x = *(unsigned short*)&h0;
    u.y = *(unsigned short*)&h1;
    u.z = *(unsigned short*)&h2;
    u.w = *(unsigned short*)&h3;
    *(ushort4*)((unsigned short*)dst + i) = u;
}

// 128x128-tile GEMM, 2-deep double-buffer with COUNTED vmcnt (T4):
//   iter t: vmcnt(4)+s_barrier  -> tile t landed in ALL waves (tile t+1 still
//           in flight ACROSS the barrier -- the lever r4's __syncthreads
//           killed by draining to 0);
//           ds_read buf[t&1]; lgkmcnt(0); s_barrier -> all waves done reading;
//           stage tile t+2 into buf[t&1]; 16 MFMA.
// Cross-wave visibility: each wave waits its OWN vmcnt then barriers, so the
// barrier release implies every wave's tile-t loads landed. Barrier counts are
// aligned (uniform control flow). Last iter uses vmcnt(0) (nothing issued
// after tile31's stage, so vmcnt(4) would not cover it).
// Session ledger: BK=64 regressed (r3); dbuf+drain0 null (r4); fusions into
// this kernel's grid/epilogue all negative (r1/r2).
template <typename OutT>
__global__ __launch_bounds__(256) void gemm128(
    const __hip_bfloat16* __restrict__ A,
    const __hip_bfloat16* __restrict__ B0, const __hip_bfloat16* __restrict__ B1,
    const __hip_bfloat16* __restrict__ B2,
    const float* __restrict__ c0, const float* __restrict__ c1, const float* __restrict__ c2,
    OutT* __restrict__ O0, OutT* __restrict__ O1, OutT* __restrict__ O2)
{
    const int K = DM;
    const int NT = 32;                    // K / 32 k-steps
    __shared__ __align__(16) unsigned short sA[2 * 128 * 32];
    __shared__ __align__(16) unsigned short sB[2 * 128 * 32];

    const int grp = blockIdx.y >> 3;
    const __hip_bfloat16* B = grp == 0 ? B0 : (grp == 1 ? B1 : B2);
    const float* bias       = grp == 0 ? c0 : (grp == 1 ? c1 : c2);
    OutT* O                 = grp == 0 ? O0 : (grp == 1 ? O1 : O2);

    const int tid  = threadIdx.x;
    const int w    = tid >> 6;
    const int lane = tid & 63;
    const int l16  = lane & 15;
    const int quad = lane >> 4;
    const int rowBase = blockIdx.x * 128;
    const int colBase = (blockIdx.y & 7) * 128;

    const int srow   = lane >> 2;
    const int sswz   = (srow & 3) ^ (srow >> 2);
    const int gchunk = (lane & 3) ^ sswz;
    const __hip_bfloat16* gA = A + (size_t)(rowBase + w * 32 + srow) * K + gchunk * 8;
    const __hip_bfloat16* gB = B + (size_t)(colBase + w * 32 + srow) * K + gchunk * 8;
    unsigned short* lA0 = sA + w * 32 * 32;   // wave-uniform stage base, buf0
    unsigned short* lB0 = sB + w * 32 * 32;

    const int fswz = (l16 & 3) ^ (l16 >> 2);
    const int mrow = (w & 1) * 64;
    const int ncol = (w >> 1) * 64;

    f32x4 acc[4][4];
#pragma unroll
    for (int i = 0; i < 4; ++i)
#pragma unroll
        for (int j = 0; j < 4; ++j) acc[i][j] = (f32x4){0.f, 0.f, 0.f, 0.f};

    // Prologue: stage tile0 -> buf0 (4 loads), tile1 -> buf1 (4 loads).
    async_cp16(gA,                     lA0);
    async_cp16(gA + (size_t)16 * K,    lA0 + 16 * 32);
    async_cp16(gB,                     lB0);
    async_cp16(gB + (size_t)16 * K,    lB0 + 16 * 32);
    async_cp16(gA + 32,                  lA0 + 128 * 32);
    async_cp16(gA + 32 + (size_t)16 * K, lA0 + 128 * 32 + 16 * 32);
    async_cp16(gB + 32,                  lB0 + 128 * 32);
    async_cp16(gB + 32 + (size_t)16 * K, lB0 + 128 * 32 + 16 * 32);

    for (int t = 0; t < NT; ++t) {
        // 1. own tile-t loads landed (tile t+1 may stay in flight), then sync.
        if (t == NT - 1) asm volatile("s_waitcnt vmcnt(0)" ::: "memory");
        else             asm volatile("s_waitcnt vmcnt(4)" ::: "memory");
        __builtin_amdgcn_s_barrier();

        // 2. ds_read fragments of tile t.
        const unsigned short* pA = sA + (t & 1) * (128 * 32);
        const unsigned short* pB = sB + (t & 1) * (128 * 32);
        short8 af[4], bf[4];
#pragma unroll
        for (int mt = 0; mt < 4; ++mt)
            af[mt] = *(const short8*)&pA[(mrow + mt * 16 + l16) * 32 + (quad ^ fswz) * 8];
#pragma unroll
        for (int nt = 0; nt < 4; ++nt)
            bf[nt] = *(const short8*)&pB[(ncol + nt * 16 + l16) * 32 + (quad ^ fswz) * 8];
        asm volatile("s_waitcnt lgkmcnt(0)" ::: "memory");   // reads complete...
        __builtin_amdgcn_sched_barrier(0);
        __builtin_amdgcn_s_barrier();                        // ...in ALL waves

        // 3. stage tile t+2 into buf[t&1] (write-safe now); flies under MFMA.
        if (t + 2 < NT) {
            const int k2 = (t + 2) * 32;
            unsigned short* dA = lA0 + (t & 1) * (128 * 32);
            unsigned short* dB = lB0 + (t & 1) * (128 * 32);
            async_cp16(gA + k2,                  dA);
            async_cp16(gA + k2 + (size_t)16 * K, dA + 16 * 32);
            async_cp16(gB + k2,                  dB);
            async_cp16(gB + k2 + (size_t)16 * K, dB + 16 * 32);
        }

        // 4. MFMA cluster.
#pragma unroll
        for (int mt = 0; mt < 4; ++mt)
#pragma unroll
            for (int nt = 0; nt < 4; ++nt)
                acc[mt][nt] = __builtin_amdgcn_mfma_f32_16x16x32_bf16(af[mt], bf[nt], acc[mt][nt], 0, 0, 0);
    }

#pragma unroll
    for (int nt = 0; nt < 4; ++nt) {
        int col = colBase + ncol + nt * 16 + l16;
        float bv = bias[col];
#pragma unroll
        for (int mt = 0; mt < 4; ++mt) {
#pragma unroll
            for (int r = 0; r < 4; ++r) {
                int row = rowBase + mrow + mt * 16 + quad * 4 + r;
                O[(size_t)row * DM + col] = (OutT)(acc[mt][nt][r] + bv);
            }
        }
    }
}

// 128x64-tile GEMM for the Wo projection, same counted-vmcnt pipeline.
// Stage = 3 loads -> steady-state vmcnt(3). LDS 2x12 = 24 KB.
template <typename OutT>
__global__ __launch_bounds__(256) void gemm_n64(
    const __hip_bfloat16* __restrict__ A,
    const __hip_bfloat16* __restrict__ B,
    const float* __restrict__ bias,
    OutT* __restrict__ O)
{
    const int K = DM;
    const int NT = 32;
    __shared__ __align__(16) unsigned short sA[2 * 128 * 32];
    __shared__ __align__(16) unsigned short sB[2 * 64 * 32];

    const int tid  = threadIdx.x;
    const int w    = tid >> 6;
    const int lane = tid & 63;
    const int l16  = lane & 15;
    const int quad = lane >> 4;
    const int rowBase = blockIdx.x * 128;
    const int colBase = blockIdx.y * 64;

    const int srow   = lane >> 2;
    const int sswz   = (srow & 3) ^ (srow >> 2);
    const int gchunk = (lane & 3) ^ sswz;
    const __hip_bfloat16* gA = A + (size_t)(rowBase + w * 32 + srow) * K + gchunk * 8;
    const __hip_bfloat16* gB = B + (size_t)(colBase + w * 16 + srow) * K + gchunk * 8;
    unsigned short* lA0 = sA + w * 32 * 32;
    unsigned short* lB0 = sB + w * 16 * 32;

    const int fswz = (l16 & 3) ^ (l16 >> 2);
    const int mrow = w * 32;

    f32x4 acc[2][4];
#pragma unroll
    for (int i = 0; i < 2; ++i)
#pragma unroll
        for (int j = 0; j < 4; ++j) acc[i][j] = (f32x4){0.f, 0.f, 0.f, 0.f};

    // Prologue: tile0 -> buf0, tile1 -> buf1.
    async_cp16(gA,                  lA0);
    async_cp16(gA + (size_t)16 * K, lA0 + 16 * 32);
    async_cp16(gB,                  lB0);
    async_cp16(gA + 32,                  lA0 + 128 * 32);
    async_cp16(gA + 32 + (size_t)16 * K, lA0 + 128 * 32 + 16 * 32);
    async_cp16(gB + 32,                  lB0 + 64 * 32);

    for (int t = 0; t < NT; ++t) {
        if (t == NT - 1) asm volatile("s_waitcnt vmcnt(0)" ::: "memory");
        else             asm volatile("s_waitcnt vmcnt(3)" ::: "memory");
        __builtin_amdgcn_s_barrier();

        const unsigned short* pA = sA + (t & 1) * (128 * 32);
        const unsigned short* pB = sB + (t & 1) * (64 * 32);
        short8 af[2], bf[4];
#pragma unroll
        for (int mt = 0; mt < 2; ++mt)
            af[mt] = *(const short8*)&pA[(mrow + mt * 16 + l16) * 32 + (quad ^ fswz) * 8];
#pragma unroll
        for (int nt = 0; nt < 4; ++nt)
            bf[nt] = *(const short8*)&pB[(nt * 16 + l16) * 32 + (quad ^ fswz) * 8];
        asm volatile("s_waitcnt lgkmcnt(0)" ::: "memory");
        __builtin_amdgcn_sched_barrier(0);
        __builtin_amdgcn_s_barrier();

        if (t + 2 < NT) {
            const int k2 = (t + 2) * 32;
            unsigned short* dA = lA0 + (t & 1) * (128 * 32);
            unsigned short* dB = lB0 + (t & 1) * (64 * 32);
            async_cp16(gA + k2,                  dA);
            async_cp16(gA + k2 + (size_t)16 * K, dA + 16 * 32);
            async_cp16(gB + k2,                  dB);
        }

#pragma unroll
        for (int mt = 0; mt < 2; ++mt)
#pragma unroll
            for (int nt = 0; nt < 4; ++nt)
                acc[mt][nt] = __builtin_amdgcn_mfma_f32_16x16x32_bf16(af[mt], bf[nt], acc[mt][nt], 0, 0, 0);
    }

#pragma unroll
    for (int nt = 0; nt < 4; ++nt) {
        int col = colBase + nt * 16 + l16;
        float bv = bias[col];
#pragma unroll
        for (int mt = 0; mt < 2; ++mt) {
#pragma unroll
            for (int r = 0; r < 4; ++r) {
                int row = rowBase + mrow + mt * 16 + quad * 4 + r;
                O[(size_t)row * DM + col] = (OutT)(acc[mt][nt][r] + bv);
            }
        }
    }
}

// Merged auxiliary kernel (chunk means, ushort2-vectorized + gate GEMM).
__global__ __launch_bounds__(256) void aux_kernel(
    const __hip_bfloat16* __restrict__ K,
    const __hip_bfloat16* __restrict__ V,
    const __hip_bfloat16* __restrict__ xb,
    const __hip_bfloat16* __restrict__ Wgb,
    const float* __restrict__ bg,
    __hip_bfloat16* __restrict__ CK,
    __hip_bfloat16* __restrict__ CV,
    float* __restrict__ G)
{
    const int b = blockIdx.x;
    if (b < 256) {
        const int c  = b >> 1;
        const int d0 = (b & 1) * 512 + threadIdx.x * 2;
        const unsigned short* Ku = (const unsigned short*)K;
        const unsigned short* Vu = (const unsigned short*)V;
        float ak0 = 0.f, ak1 = 0.f, av0 = 0.f, av1 = 0.f;
#pragma unroll 8
        for (int i = 0; i < 32; ++i) {
            size_t off = (size_t)(c * 32 + i) * DM + d0;
            ushort2 kv = *(const ushort2*)(Ku + off);
            ushort2 vv = *(const ushort2*)(Vu + off);
            ak0 += bf2f(kv.x); ak1 += bf2f(kv.y);
            av0 += bf2f(vv.x); av1 += bf2f(vv.y);
        }
        __hip_bfloat16 k0 = (__hip_bfloat16)(ak0 * (1.f / 32.f));
        __hip_bfloat16 k1 = (__hip_bfloat16)(ak1 * (1.f / 32.f));
        __hip_bfloat16 v0 = (__hip_bfloat16)(av0 * (1.f / 32.f));
        __hip_bfloat16 v1 = (__hip_bfloat16)(av1 * (1.f / 32.f));
        ushort2 ko, vo;
        ko.x = *(unsigned short*)&k0; ko.y = *(unsigned short*)&k1;
        vo.x = *(unsigned short*)&v0; vo.y = *(unsigned short*)&v1;
        *(ushort2*)((unsigned short*)CK + (size_t)c * DM + d0) = ko;
        *(ushort2*)((unsigned short*)CV + (size_t)c * DM + d0) = vo;
        return;
    }
    const int unit = threadIdx.x >> 6;
    const int lane = threadIdx.x & 63;
    const int l16  = lane & 15;
    const int quad = lane >> 4;
    const int t0   = (b - 256) * 64 + unit * 16;
    const __hip_bfloat16* ap = xb  + (size_t)(t0 + l16) * DM + quad * 8;
    const __hip_bfloat16* bp = Wgb + (size_t)l16 * DM + quad * 8;
    f32x4 acc = (f32x4){0.f, 0.f, 0.f, 0.f};
#pragma unroll 4
    for (int k0 = 0; k0 < DM; k0 += 32) {
        short8 a = *(const short8*)(ap + k0);
        short8 bb = *(const short8*)(bp + k0);
        acc = __builtin_amdgcn_mfma_f32_16x16x32_bf16(a, bb, acc, 0, 0, 0);
    }
    float bgv = bg[l16];
#pragma unroll
    for (int r = 0; r < 4; ++r) {
        int t = t0 + quad * 4 + r;
        float z = acc[r] + bgv;
        G[t * NH + l16] = 1.f / (1.f + __expf(-z));
    }
}

// MFMA attention: 64 queries x 1 head per block (grid 64 x 16, 256 threads).
__global__ __launch_bounds__(256) void attn_mfma(
    const __hip_bfloat16* __restrict__ Q,
    const __hip_bfloat16* __restrict__ K,
    const __hip_bfloat16* __restrict__ V,
    const __hip_bfloat16* __restrict__ CK,
    const __hip_bfloat16* __restrict__ CV,
    const float* __restrict__ G,
    __hip_bfloat16* __restrict__ Aout)
{
    __shared__ alignas(16) unsigned short Pls[64 * PSTR];
    __shared__ alignas(16) unsigned short Vts[64 * PSTR];

    const int h   = blockIdx.y;
    const int t0  = blockIdx.x * 64;
    const int tid = threadIdx.x;
    const int w    = tid >> 6;
    const int lane = tid & 63;
    const int l16  = lane & 15;
    const int quad = lane >> 4;
    const float scale = 0.125f;

    const int rc0  = (t0 >= 96) ? ((t0 - 64) >> 5) : 0;
    const int cmin = rc0 > 16 ? rc0 - 16 : 0;

    const unsigned short* Vu  = (const unsigned short*)V;
    const unsigned short* CVu = (const unsigned short*)CV;

    {
#pragma unroll
        for (int gg = 0; gg < 2; ++gg) {
            const int g = w * 2 + gg;
#pragma unroll
            for (int i = 0; i < 2; ++i) {
                const int pair = lane + 64 * i;
                if (pair < 80) {
                    const int j = pair * 2;
                    const unsigned short *s0, *s1;
                    if (j < 128) {
                        int tok0 = t0 - 64 + j; if (tok0 < 0) tok0 = 0;
                        int tok1 = t0 - 63 + j; if (tok1 < 0) tok1 = 0;
                        s0 = Vu + (size_t)tok0 * DM + h * 64 + g * 8;
                        s1 = Vu + (size_t)tok1 * DM + h * 64 + g * 8;
                    } else {
                        int c0 = cmin + (j - 128); if (c0 > 127) c0 = 127;
                        int c1 = c0 + 1;           if (c1 > 127) c1 = 127;
                        s0 = CVu + (size_t)c0 * DM + h * 64 + g * 8;
                        s1 = CVu + (size_t)c1 * DM + h * 64 + g * 8;
                    }
                    short8 v0 = *(const short8*)s0;
                    short8 v1 = *(const short8*)s1;
#pragma unroll
                    for (int e = 0; e < 8; ++e) {
                        ushort2 pk;
                        pk.x = (unsigned short)v0[e];
                        pk.y = (unsigned short)v1[e];
                        *(ushort2*)&Vts[(g * 8 + e) * PSTR + j] = pk;
                    }
                }
            }
        }
    }

    const __hip_bfloat16* qp = Q + (size_t)(t0 + w * 16 + l16) * DM + h * 64 + quad * 8;
    short8 qf0 = *(const short8*)(qp);
    short8 qf1 = *(const short8*)(qp + 32);

    f32x4 sc[8];
#pragma unroll
    for (int jt = 0; jt < 8; ++jt) {
        int j = jt * 16 + l16;
        int tok = t0 - 64 + j;
        tok = tok < 0 ? 0 : tok;
        const __hip_bfloat16* kp = K + (size_t)tok * DM + h * 64 + quad * 8;
        short8 b0 = *(const short8*)(kp);
        short8 b1 = *(const short8*)(kp + 32);
        f32x4 a = __builtin_amdgcn_mfma_f32_16x16x32_bf16(qf0, b0, (f32x4){0.f,0.f,0.f,0.f}, 0, 0, 0);
        sc[jt]  = __builtin_amdgcn_mfma_f32_16x16x32_bf16(qf1, b1, a, 0, 0, 0);
    }
    f32x4 sc2[2];
#pragma unroll
    for (int jt = 0; jt < 2; ++jt) {
        int c = cmin + jt * 16 + l16;
        if (c > 127) c = 127;
        const __hip_bfloat16* cp = CK + (size_t)c * DM + h * 64 + quad * 8;
        short8 b0 = *(const short8*)(cp);
        short8 b1 = *(const short8*)(cp + 32);
        f32x4 a = __builtin_amdgcn_mfma_f32_16x16x32_bf16(qf0, b0, (f32x4){0.f,0.f,0.f,0.f}, 0, 0, 0);
        sc2[jt] = __builtin_amdgcn_mfma_f32_16x16x32_bf16(qf1, b1, a, 0, 0, 0);
    }

    __syncthreads();  // all waves' Vts writes visible before PV reads

    const int rbase = w * 16 + quad * 4;
    float gl[4], g2[4];
    float mx[4], sm[4], mx2[4], sm2[4];
#pragma unroll
    for (int reg = 0; reg < 4; ++reg) {
        int rr = rbase + reg;
        int t  = t0 + rr;
        float g = G[t * NH + h];
        int rc = (t >= 96) ? ((t - 64) >> 5) : 0;
        gl[reg] = (t > 0)  ? g        : 0.f;
        g2[reg] = (rc > 0) ? (1.f - g) : 0.f;

        int jlo = rr > (64 - t0) ? rr : (64 - t0);
        int jhi = rr + 63;
        float m = -1e30f;
#pragma unroll
        for (int jt = 0; jt < 8; ++jt) {
            int j = jt * 16 + l16;
            float s = (j >= jlo && j <= jhi) ? sc[jt][reg] * scale : -1e30f;
            sc[jt][reg] = s;
            m = fmaxf(m, s);
        }
        mx[reg] = m;

        int nvis = rc < 16 ? rc : 16;
        int clo = rc - nvis, chi = rc - 1;
        float m2 = -1e30f;
#pragma unroll
        for (int jt = 0; jt < 2; ++jt) {
            int c = cmin + jt * 16 + l16;
            float s = (c >= clo && c <= chi) ? sc2[jt][reg] * scale : -1e30f;
            sc2[jt][reg] = s;
            m2 = fmaxf(m2, s);
        }
        mx2[reg] = m2;
    }
#pragma unroll
    for (int off = 1; off <= 8; off <<= 1)
#pragma unroll
        for (int reg = 0; reg < 4; ++reg) {
            mx[reg]  = fmaxf(mx[reg],  __shfl_xor(mx[reg],  off));
            mx2[reg] = fmaxf(mx2[reg], __shfl_xor(mx2[reg], off));
        }
#pragma unroll
    for (int reg = 0; reg < 4; ++reg) {
        float s = 0.f, s2 = 0.f;
#pragma unroll
        for (int jt = 0; jt < 8; ++jt) {
            float p = __expf(sc[jt][reg] - mx[reg]);
            sc[jt][reg] = p;
            s += p;
        }
#pragma unroll
        for (int jt = 0; jt < 2; ++jt) {
            float p = __expf(sc2[jt][reg] - mx2[reg]);
            sc2[jt][reg] = p;
            s2 += p;
        }
        sm[reg] = s; sm2[reg] = s2;
    }
#pragma unroll
    for (int off = 1; off <= 8; off <<= 1)
#pragma unroll
        for (int reg = 0; reg < 4; ++reg) {
            sm[reg]  += __shfl_xor(sm[reg],  off);
            sm2[reg] += __shfl_xor(sm2[reg], off);
        }

#pragma unroll
    for (int reg = 0; reg < 4; ++reg) {
        float f1 = gl[reg] / sm[reg];
        float f2 = g2[reg] / sm2[reg];
        int rowoff = (rbase + reg) * PSTR;
#pragma unroll
        for (int jt = 0; jt < 8; ++jt) {
            __hip_bfloat16 hb = (__hip_bfloat16)(sc[jt][reg] * f1);
            Pls[rowoff + jt * 16 + l16] = *(unsigned short*)&hb;
        }
#pragma unroll
        for (int jt = 0; jt < 2; ++jt) {
            __hip_bfloat16 hb = (__hip_bfloat16)(sc2[jt][reg] * f2);
            Pls[rowoff + 128 + jt * 16 + l16] = *(unsigned short*)&hb;
        }
    }
    asm volatile("s_waitcnt lgkmcnt(0)" ::: "memory");  // wave-private P round-trip

    f32x4 o[4];
#pragma unroll
    for (int nt = 0; nt < 4; ++nt) o[nt] = (f32x4){0.f, 0.f, 0.f, 0.f};
#pragma unroll
    for (int kt = 0; kt < 5; ++kt) {
        short8 a = *(const short8*)&Pls[(w * 16 + l16) * PSTR + kt * 32 + quad * 8];
#pragma unroll
        for (int nt = 0; nt < 4; ++nt) {
            int dd = nt * 16 + l16;
            short8 b = *(const short8*)&Vts[dd * PSTR + kt * 32 + quad * 8];
            o[nt] = __builtin_amdgcn_mfma_f32_16x16x32_bf16(a, b, o[nt], 0, 0, 0);
        }
    }

#pragma unroll
    for (int nt = 0; nt < 4; ++nt) {
#pragma unroll
        for (int reg = 0; reg < 4; ++reg) {
            int row = t0 + rbase + reg;
            int col = h * 64 + nt * 16 + l16;
            Aout[(size_t)row * DM + col] = (__hip_bfloat16)(o[nt][reg]);
        }
    }
}

extern "C" void kernel_launch(void* const* d_in, const int* in_sizes, int n_in,
                              void* d_out, int out_size, void* d_ws, size_t ws_size,
                              hipStream_t stream)
{
    const float* x  = (const float*)d_in[0];
    const float* Wq = (const float*)d_in[1];
    const float* bq = (const float*)d_in[2];
    const float* Wk = (const float*)d_in[3];
    const float* bk = (const float*)d_in[4];
    const float* Wv = (const float*)d_in[5];
    const float* bv = (const float*)d_in[6];
    const float* Wo = (const float*)d_in[7];
    const float* bo = (const float*)d_in[8];
    const float* Wg = (const float*)d_in[9];
    const float* bg = (const float*)d_in[10];
    float* out = (float*)d_out;

    char* ws = (char*)d_ws;
    const size_t MB = 1024 * 1024;
    __hip_bfloat16* xb  = (__hip_bfloat16*)(ws + 0 * MB);   // 8 MB
    __hip_bfloat16* Qb  = (__hip_bfloat16*)(ws + 8 * MB);   // 8 MB
    __hip_bfloat16* Kb  = (__hip_bfloat16*)(ws + 16 * MB);  // 8 MB
    __hip_bfloat16* Vb  = (__hip_bfloat16*)(ws + 24 * MB);  // 8 MB
    __hip_bfloat16* Ab  = (__hip_bfloat16*)(ws + 32 * MB);  // 8 MB
    __hip_bfloat16* Wqb = (__hip_bfloat16*)(ws + 40 * MB);  // 2 MB
    __hip_bfloat16* Wkb = (__hip_bfloat16*)(ws + 42 * MB);  // 2 MB
    __hip_bfloat16* Wvb = (__hip_bfloat16*)(ws + 44 * MB);  // 2 MB
    __hip_bfloat16* Wob = (__hip_bfloat16*)(ws + 46 * MB);  // 2 MB
    __hip_bfloat16* CKb = (__hip_bfloat16*)(ws + 48 * MB);            // 256 KB
    __hip_bfloat16* CVb = (__hip_bfloat16*)(ws + 48 * MB + 256*1024); // 256 KB
    float* Gf           = (float*)(ws + 48 * MB + 512 * 1024);        // 256 KB
    __hip_bfloat16* Wgb = (__hip_bfloat16*)(ws + 48 * MB + 768*1024); // 32 KB

    cast_all<<<dim3(8208), 256, 0, stream>>>(x, Wq, Wk, Wv, Wo, Wg,
                                             xb, Wqb, Wkb, Wvb, Wob, Wgb);

    // Fused QKV GEMM: grid (32, 24); group = blockIdx.y>>3.
    gemm128<__hip_bfloat16><<<dim3(32, 24), 256, 0, stream>>>(
        xb, Wqb, Wkb, Wvb, bq, bk, bv, Qb, Kb, Vb);
    // Merged chunk-means + gate GEMM (one dispatch, independent halves).
    aux_kernel<<<dim3(320), 256, 0, stream>>>(Kb, Vb, xb, Wgb, bg, CKb, CVb, Gf);
    attn_mfma<<<dim3(64, 16), 256, 0, stream>>>(Qb, Kb, Vb, CKb, CVb, Gf, Ab);
    // Output GEMM: 128x64 tiles, grid (32, 16) = 512 blocks.
    gemm_n64<float><<<dim3(32, 16), 256, 0, stream>>>(Ab, Wob, bo, out);
}

// Round 7
// 177.357 us; speedup vs baseline: 1.2098x; 1.0003x over previous
//
#include <hip/hip_runtime.h>
#include <hip/hip_bf16.h>
#include <math.h>

typedef __attribute__((ext_vector_type(8))) short short8;
typedef __attribute__((ext_vector_type(4))) float f32x4;

#define TT 4096
#define DM 1024
#define NH 16
#define HD 64
#define PSTR 168   // attn LDS row stride in halfwords (84 dwords == 20 mod 32 banks)

typedef __attribute__((address_space(3))) unsigned int lds_u32;
typedef __attribute__((address_space(1))) unsigned int glb_u32;

__device__ __forceinline__ void async_cp16(const void* g, void* l) {
    __builtin_amdgcn_global_load_lds((glb_u32*)g, (lds_u32*)l, 16, 0, 0);
}

__device__ __forceinline__ float bf2f(unsigned short u) {
    union { unsigned int i; float f; } v;
    v.i = (unsigned int)u << 16;
    return v.f;
}

// Fused fp32 -> bf16 cast for x + Wq/Wk/Wv/Wo + Wg.
__global__ __launch_bounds__(256) void cast_all(
    const float* __restrict__ x,  const float* __restrict__ wq,
    const float* __restrict__ wk, const float* __restrict__ wv,
    const float* __restrict__ wo, const float* __restrict__ wg,
    __hip_bfloat16* __restrict__ xb,  __hip_bfloat16* __restrict__ wqb,
    __hip_bfloat16* __restrict__ wkb, __hip_bfloat16* __restrict__ wvb,
    __hip_bfloat16* __restrict__ wob, __hip_bfloat16* __restrict__ wgb)
{
    int b = blockIdx.x;
    const float* src;
    __hip_bfloat16* dst;
    size_t base;
    if (b < 4096)      { src = x;  dst = xb;  base = (size_t)b * 1024; }
    else if (b < 5120) { src = wq; dst = wqb; base = (size_t)(b - 4096) * 1024; }
    else if (b < 6144) { src = wk; dst = wkb; base = (size_t)(b - 5120) * 1024; }
    else if (b < 7168) { src = wv; dst = wvb; base = (size_t)(b - 6144) * 1024; }
    else if (b < 8192) { src = wo; dst = wob; base = (size_t)(b - 7168) * 1024; }
    else               { src = wg; dst = wgb; base = (size_t)(b - 8192) * 1024; }
    size_t i = base + (size_t)threadIdx.x * 4;
    float4 v = *(const float4*)(src + i);
    __hip_bfloat16 h0 = (__hip_bfloat16)v.x;
    __hip_bfloat16 h1 = (__hip_bfloat16)v.y;
    __hip_bfloat16 h2 = (__hip_bfloat16)v.z;
    __hip_bfloat16 h3 = (__hip_bfloat16)v.w;
    ushort4 u;
    u.x = *(unsigned short*)&h0;
    u.y = *(unsigned short*)&h1;
    u.z = *(unsigned short*)&h2;
    u.w = *(unsigned short*)&h3;
    *(ushort4*)((unsigned short*)dst + i) = u;
}

// ---------------------------------------------------------------------------
// 256x256-tile QKV GEMM, 4-phase-per-K-tile schedule (8-phase/2-tile family),
// BK=64, 8 waves (2M x 4N), per-wave output 128x64, acc[8][4].
// LDS ring: 8 half-tile slots (2 bufs x {Alo,Ahi,Blo,Bhi}) = 128 KB.
// Staging (one half-tile = 2 global_load_lds of 8 KB): p0->Ahi(t+1),
// p2->Blo(t+2), p3->Bhi(t+2)+Alo(t+2). Issue stream gives exactly 3 halves
// (6 instr) after Ahi(t) -> s_waitcnt vmcnt(6) at p0 (vmcnt(0) at t=NT-1).
// Barriers: p0-pre (after vmcnt), p1-end (B(t) consumed), p2-end (A(t)
// consumed) -- each staging lands after the barrier closing its slot's reads.
// Swizzle: LDS[r][c] holds G[r][c^(r&7)] (8 chunks of 16B per 128B row);
// read chunk = (ks*4+quad)^(l16&7); staged via pre-swizzled global source
// chunk (lane&7)^(lane>>3) with linear LDS dest (both-sides rule).
// Session ledger: 128-tile levers all null/negative (r1-r6); this is the
// documented structural escape from the ~600 TF 2-phase ceiling.
// ---------------------------------------------------------------------------
template <typename OutT>
__global__ __launch_bounds__(512, 2) void gemm256(
    const __hip_bfloat16* __restrict__ A,
    const __hip_bfloat16* __restrict__ B0, const __hip_bfloat16* __restrict__ B1,
    const __hip_bfloat16* __restrict__ B2,
    const float* __restrict__ c0, const float* __restrict__ c1, const float* __restrict__ c2,
    OutT* __restrict__ O0, OutT* __restrict__ O1, OutT* __restrict__ O2)
{
    const int K  = DM;
    const int NT = 16;   // K / 64
    __shared__ __align__(16) unsigned short sL[2][4][128 * 64];  // [buf][Alo,Ahi,Blo,Bhi]

    const int grp = blockIdx.y >> 2;
    const __hip_bfloat16* B = grp == 0 ? B0 : (grp == 1 ? B1 : B2);
    const float* bias       = grp == 0 ? c0 : (grp == 1 ? c1 : c2);
    OutT* O                 = grp == 0 ? O0 : (grp == 1 ? O1 : O2);

    const int tid  = threadIdx.x;
    const int w    = tid >> 6;
    const int lane = tid & 63;
    const int l16  = lane & 15;
    const int quad = lane >> 4;
    const int wr   = w >> 2;      // wave row (0,1) -> A half
    const int wc   = w & 3;       // wave col (0..3) -> B half + 64-col slice
    const int rowBase = blockIdx.x * 256;
    const int colBase = (blockIdx.y & 3) * 256;

    // staging: lane -> (row = base + i*64 + w*8 + (lane>>3), chunk = lane&7);
    // global source chunk pre-swizzled by row&7 (= lane>>3 since offsets %8==0).
    const int srow = lane >> 3;
    const int schk = (lane & 7) ^ srow;
    const __hip_bfloat16* gA = A + (size_t)(rowBase + w * 8 + srow) * K + schk * 8;
    const __hip_bfloat16* gB = B + (size_t)(colBase + w * 8 + srow) * K + schk * 8;
    const int dstoff = w * 8 * 64;   // halfwords; wave-uniform LDS dest base

#define STG(buf, slot, gbase, half, kt) do {                                                   \
    async_cp16((gbase) + (size_t)((half) * 128)      * K + (kt) * 64, &sL[buf][slot][dstoff]); \
    async_cp16((gbase) + (size_t)((half) * 128 + 64) * K + (kt) * 64, &sL[buf][slot][64 * 64 + dstoff]); \
} while (0)

    // read-side swizzled chunk offsets (halfwords) for k-slot 0/1
    const int cs0 = ((quad)     ^ (l16 & 7)) * 8;
    const int cs1 = ((4 + quad) ^ (l16 & 7)) * 8;

    f32x4 acc[8][4];
#pragma unroll
    for (int i = 0; i < 8; ++i)
#pragma unroll
        for (int j = 0; j < 4; ++j) acc[i][j] = (f32x4){0.f, 0.f, 0.f, 0.f};

    // Prologue: tile0 {Blo,Bhi,Alo,Ahi} -> buf0; tile1 {Blo,Bhi,Alo} -> buf1.
    STG(0, 2, gB, 0, 0); STG(0, 3, gB, 1, 0); STG(0, 0, gA, 0, 0); STG(0, 1, gA, 1, 0);
    STG(1, 2, gB, 0, 1); STG(1, 3, gB, 1, 1); STG(1, 0, gA, 0, 1);

    short8 af[4][2], bf[4][2];
    for (int t = 0; t < NT; ++t) {
        const int b = t & 1;
        const unsigned short* pa = &sL[b][wr][0];
        const unsigned short* pb = &sL[b][2 + (wc >> 1)][(wc & 1) * 64 * 64];

        // ---- phase 0: A-mLo(8) + B-nLo(4); stage Ahi(t+1) ----
        if (t == NT - 1) asm volatile("s_waitcnt vmcnt(0)" ::: "memory");
        else             asm volatile("s_waitcnt vmcnt(6)" ::: "memory");
        __builtin_amdgcn_s_barrier();
#pragma unroll
        for (int m = 0; m < 4; ++m) {
            af[m][0] = *(const short8*)&pa[(m * 16 + l16) * 64 + cs0];
            af[m][1] = *(const short8*)&pa[(m * 16 + l16) * 64 + cs1];
        }
#pragma unroll
        for (int n = 0; n < 2; ++n) {
            bf[n][0] = *(const short8*)&pb[(n * 16 + l16) * 64 + cs0];
            bf[n][1] = *(const short8*)&pb[(n * 16 + l16) * 64 + cs1];
        }
        if (t + 1 < NT) STG(b ^ 1, 1, gA, 1, t + 1);
        asm volatile("s_waitcnt lgkmcnt(0)" ::: "memory");
        __builtin_amdgcn_sched_barrier(0);
        __builtin_amdgcn_s_setprio(1);
#pragma unroll
        for (int ks = 0; ks < 2; ++ks)
#pragma unroll
            for (int m = 0; m < 4; ++m)
#pragma unroll
                for (int n = 0; n < 2; ++n)
                    acc[m][n] = __builtin_amdgcn_mfma_f32_16x16x32_bf16(af[m][ks], bf[n][ks], acc[m][n], 0, 0, 0);
        __builtin_amdgcn_s_setprio(0);

        // ---- phase 1: B-nHi(4) ----
#pragma unroll
        for (int n = 2; n < 4; ++n) {
            bf[n][0] = *(const short8*)&pb[(n * 16 + l16) * 64 + cs0];
            bf[n][1] = *(const short8*)&pb[(n * 16 + l16) * 64 + cs1];
        }
        asm volatile("s_waitcnt lgkmcnt(0)" ::: "memory");
        __builtin_amdgcn_sched_barrier(0);
        __builtin_amdgcn_s_setprio(1);
#pragma unroll
        for (int ks = 0; ks < 2; ++ks)
#pragma unroll
            for (int m = 0; m < 4; ++m)
#pragma unroll
            for (int n = 2; n < 4; ++n)
                acc[m][n] = __builtin_amdgcn_mfma_f32_16x16x32_bf16(af[m][ks], bf[n][ks], acc[m][n], 0, 0, 0);
        __builtin_amdgcn_s_setprio(0);
        __builtin_amdgcn_s_barrier();   // B(t) fully consumed by all waves

        // ---- phase 2: A-mHi(8, reg reuse); stage Blo(t+2) ----
#pragma unroll
        for (int m = 0; m < 4; ++m) {
            af[m][0] = *(const short8*)&pa[((m + 4) * 16 + l16) * 64 + cs0];
            af[m][1] = *(const short8*)&pa[((m + 4) * 16 + l16) * 64 + cs1];
        }
        if (t + 2 < NT) STG(b, 2, gB, 0, t + 2);
        asm volatile("s_waitcnt lgkmcnt(0)" ::: "memory");
        __builtin_amdgcn_sched_barrier(0);
        __builtin_amdgcn_s_setprio(1);
#pragma unroll
        for (int ks = 0; ks < 2; ++ks)
#pragma unroll
            for (int m = 0; m < 4; ++m)
#pragma unroll
                for (int n = 0; n < 2; ++n)
                    acc[m + 4][n] = __builtin_amdgcn_mfma_f32_16x16x32_bf16(af[m][ks], bf[n][ks], acc[m + 4][n], 0, 0, 0);
        __builtin_amdgcn_s_setprio(0);
        __builtin_amdgcn_s_barrier();   // A(t) fully consumed by all waves

        // ---- phase 3: no reads; stage Bhi(t+2), Alo(t+2) ----
        if (t + 2 < NT) { STG(b, 3, gB, 1, t + 2); STG(b, 0, gA, 0, t + 2); }
        __builtin_amdgcn_s_setprio(1);
#pragma unroll
        for (int ks = 0; ks < 2; ++ks)
#pragma unroll
            for (int m = 0; m < 4; ++m)
#pragma unroll
            for (int n = 2; n < 4; ++n)
                acc[m + 4][n] = __builtin_amdgcn_mfma_f32_16x16x32_bf16(af[m][ks], bf[n][ks], acc[m + 4][n], 0, 0, 0);
        __builtin_amdgcn_s_setprio(0);
        // no barrier: next iter's p0 vmcnt+barrier covers the p3->p0 edge
    }
#undef STG

#pragma unroll
    for (int n = 0; n < 4; ++n) {
        int col = colBase + wc * 64 + n * 16 + l16;
        float bv = bias[col];
#pragma unroll
        for (int m = 0; m < 8; ++m) {
#pragma unroll
            for (int r = 0; r < 4; ++r) {
                int row = rowBase + wr * 128 + m * 16 + quad * 4 + r;
                O[(size_t)row * DM + col] = (OutT)(acc[m][n][r] + bv);
            }
        }
    }
}

// 128x64-tile GEMM for the Wo projection, counted-vmcnt 2-deep pipeline
// (r6 version, known-passing). LDS 2x12 = 24 KB.
template <typename OutT>
__global__ __launch_bounds__(256) void gemm_n64(
    const __hip_bfloat16* __restrict__ A,
    const __hip_bfloat16* __restrict__ B,
    const float* __restrict__ bias,
    OutT* __restrict__ O)
{
    const int K = DM;
    const int NT = 32;
    __shared__ __align__(16) unsigned short sA[2 * 128 * 32];
    __shared__ __align__(16) unsigned short sB[2 * 64 * 32];

    const int tid  = threadIdx.x;
    const int w    = tid >> 6;
    const int lane = tid & 63;
    const int l16  = lane & 15;
    const int quad = lane >> 4;
    const int rowBase = blockIdx.x * 128;
    const int colBase = blockIdx.y * 64;

    const int srow   = lane >> 2;
    const int sswz   = (srow & 3) ^ (srow >> 2);
    const int gchunk = (lane & 3) ^ sswz;
    const __hip_bfloat16* gA = A + (size_t)(rowBase + w * 32 + srow) * K + gchunk * 8;
    const __hip_bfloat16* gB = B + (size_t)(colBase + w * 16 + srow) * K + gchunk * 8;
    unsigned short* lA0 = sA + w * 32 * 32;
    unsigned short* lB0 = sB + w * 16 * 32;

    const int fswz = (l16 & 3) ^ (l16 >> 2);
    const int mrow = w * 32;

    f32x4 acc[2][4];
#pragma unroll
    for (int i = 0; i < 2; ++i)
#pragma unroll
        for (int j = 0; j < 4; ++j) acc[i][j] = (f32x4){0.f, 0.f, 0.f, 0.f};

    async_cp16(gA,                  lA0);
    async_cp16(gA + (size_t)16 * K, lA0 + 16 * 32);
    async_cp16(gB,                  lB0);
    async_cp16(gA + 32,                  lA0 + 128 * 32);
    async_cp16(gA + 32 + (size_t)16 * K, lA0 + 128 * 32 + 16 * 32);
    async_cp16(gB + 32,                  lB0 + 64 * 32);

    for (int t = 0; t < NT; ++t) {
        if (t == NT - 1) asm volatile("s_waitcnt vmcnt(0)" ::: "memory");
        else             asm volatile("s_waitcnt vmcnt(3)" ::: "memory");
        __builtin_amdgcn_s_barrier();

        const unsigned short* pA = sA + (t & 1) * (128 * 32);
        const unsigned short* pB = sB + (t & 1) * (64 * 32);
        short8 af[2], bf[4];
#pragma unroll
        for (int mt = 0; mt < 2; ++mt)
            af[mt] = *(const short8*)&pA[(mrow + mt * 16 + l16) * 32 + (quad ^ fswz) * 8];
#pragma unroll
        for (int nt = 0; nt < 4; ++nt)
            bf[nt] = *(const short8*)&pB[(nt * 16 + l16) * 32 + (quad ^ fswz) * 8];
        asm volatile("s_waitcnt lgkmcnt(0)" ::: "memory");
        __builtin_amdgcn_sched_barrier(0);
        __builtin_amdgcn_s_barrier();

        if (t + 2 < NT) {
            const int k2 = (t + 2) * 32;
            unsigned short* dA = lA0 + (t & 1) * (128 * 32);
            unsigned short* dB = lB0 + (t & 1) * (64 * 32);
            async_cp16(gA + k2,                  dA);
            async_cp16(gA + k2 + (size_t)16 * K, dA + 16 * 32);
            async_cp16(gB + k2,                  dB);
        }

#pragma unroll
        for (int mt = 0; mt < 2; ++mt)
#pragma unroll
            for (int nt = 0; nt < 4; ++nt)
                acc[mt][nt] = __builtin_amdgcn_mfma_f32_16x16x32_bf16(af[mt], bf[nt], acc[mt][nt], 0, 0, 0);
    }

#pragma unroll
    for (int nt = 0; nt < 4; ++nt) {
        int col = colBase + nt * 16 + l16;
        float bv = bias[col];
#pragma unroll
        for (int mt = 0; mt < 2; ++mt) {
#pragma unroll
            for (int r = 0; r < 4; ++r) {
                int row = rowBase + mrow + mt * 16 + quad * 4 + r;
                O[(size_t)row * DM + col] = (OutT)(acc[mt][nt][r] + bv);
            }
        }
    }
}

// Merged auxiliary kernel (chunk means, ushort2-vectorized + gate GEMM).
__global__ __launch_bounds__(256) void aux_kernel(
    const __hip_bfloat16* __restrict__ K,
    const __hip_bfloat16* __restrict__ V,
    const __hip_bfloat16* __restrict__ xb,
    const __hip_bfloat16* __restrict__ Wgb,
    const float* __restrict__ bg,
    __hip_bfloat16* __restrict__ CK,
    __hip_bfloat16* __restrict__ CV,
    float* __restrict__ G)
{
    const int b = blockIdx.x;
    if (b < 256) {
        const int c  = b >> 1;
        const int d0 = (b & 1) * 512 + threadIdx.x * 2;
        const unsigned short* Ku = (const unsigned short*)K;
        const unsigned short* Vu = (const unsigned short*)V;
        float ak0 = 0.f, ak1 = 0.f, av0 = 0.f, av1 = 0.f;
#pragma unroll 8
        for (int i = 0; i < 32; ++i) {
            size_t off = (size_t)(c * 32 + i) * DM + d0;
            ushort2 kv = *(const ushort2*)(Ku + off);
            ushort2 vv = *(const ushort2*)(Vu + off);
            ak0 += bf2f(kv.x); ak1 += bf2f(kv.y);
            av0 += bf2f(vv.x); av1 += bf2f(vv.y);
        }
        __hip_bfloat16 k0 = (__hip_bfloat16)(ak0 * (1.f / 32.f));
        __hip_bfloat16 k1 = (__hip_bfloat16)(ak1 * (1.f / 32.f));
        __hip_bfloat16 v0 = (__hip_bfloat16)(av0 * (1.f / 32.f));
        __hip_bfloat16 v1 = (__hip_bfloat16)(av1 * (1.f / 32.f));
        ushort2 ko, vo;
        ko.x = *(unsigned short*)&k0; ko.y = *(unsigned short*)&k1;
        vo.x = *(unsigned short*)&v0; vo.y = *(unsigned short*)&v1;
        *(ushort2*)((unsigned short*)CK + (size_t)c * DM + d0) = ko;
        *(ushort2*)((unsigned short*)CV + (size_t)c * DM + d0) = vo;
        return;
    }
    const int unit = threadIdx.x >> 6;
    const int lane = threadIdx.x & 63;
    const int l16  = lane & 15;
    const int quad = lane >> 4;
    const int t0   = (b - 256) * 64 + unit * 16;
    const __hip_bfloat16* ap = xb  + (size_t)(t0 + l16) * DM + quad * 8;
    const __hip_bfloat16* bp = Wgb + (size_t)l16 * DM + quad * 8;
    f32x4 acc = (f32x4){0.f, 0.f, 0.f, 0.f};
#pragma unroll 4
    for (int k0 = 0; k0 < DM; k0 += 32) {
        short8 a = *(const short8*)(ap + k0);
        short8 bb = *(const short8*)(bp + k0);
        acc = __builtin_amdgcn_mfma_f32_16x16x32_bf16(a, bb, acc, 0, 0, 0);
    }
    float bgv = bg[l16];
#pragma unroll
    for (int r = 0; r < 4; ++r) {
        int t = t0 + quad * 4 + r;
        float z = acc[r] + bgv;
        G[t * NH + l16] = 1.f / (1.f + __expf(-z));
    }
}

// MFMA attention: 64 queries x 1 head per block (grid 64 x 16, 256 threads).
__global__ __launch_bounds__(256) void attn_mfma(
    const __hip_bfloat16* __restrict__ Q,
    const __hip_bfloat16* __restrict__ K,
    const __hip_bfloat16* __restrict__ V,
    const __hip_bfloat16* __restrict__ CK,
    const __hip_bfloat16* __restrict__ CV,
    const float* __restrict__ G,
    __hip_bfloat16* __restrict__ Aout)
{
    __shared__ alignas(16) unsigned short Pls[64 * PSTR];
    __shared__ alignas(16) unsigned short Vts[64 * PSTR];

    const int h   = blockIdx.y;
    const int t0  = blockIdx.x * 64;
    const int tid = threadIdx.x;
    const int w    = tid >> 6;
    const int lane = tid & 63;
    const int l16  = lane & 15;
    const int quad = lane >> 4;
    const float scale = 0.125f;

    const int rc0  = (t0 >= 96) ? ((t0 - 64) >> 5) : 0;
    const int cmin = rc0 > 16 ? rc0 - 16 : 0;

    const unsigned short* Vu  = (const unsigned short*)V;
    const unsigned short* CVu = (const unsigned short*)CV;

    {
#pragma unroll
        for (int gg = 0; gg < 2; ++gg) {
            const int g = w * 2 + gg;
#pragma unroll
            for (int i = 0; i < 2; ++i) {
                const int pair = lane + 64 * i;
                if (pair < 80) {
                    const int j = pair * 2;
                    const unsigned short *s0, *s1;
                    if (j < 128) {
                        int tok0 = t0 - 64 + j; if (tok0 < 0) tok0 = 0;
                        int tok1 = t0 - 63 + j; if (tok1 < 0) tok1 = 0;
                        s0 = Vu + (size_t)tok0 * DM + h * 64 + g * 8;
                        s1 = Vu + (size_t)tok1 * DM + h * 64 + g * 8;
                    } else {
                        int c0 = cmin + (j - 128); if (c0 > 127) c0 = 127;
                        int c1 = c0 + 1;           if (c1 > 127) c1 = 127;
                        s0 = CVu + (size_t)c0 * DM + h * 64 + g * 8;
                        s1 = CVu + (size_t)c1 * DM + h * 64 + g * 8;
                    }
                    short8 v0 = *(const short8*)s0;
                    short8 v1 = *(const short8*)s1;
#pragma unroll
                    for (int e = 0; e < 8; ++e) {
                        ushort2 pk;
                        pk.x = (unsigned short)v0[e];
                        pk.y = (unsigned short)v1[e];
                        *(ushort2*)&Vts[(g * 8 + e) * PSTR + j] = pk;
                    }
                }
            }
        }
    }

    const __hip_bfloat16* qp = Q + (size_t)(t0 + w * 16 + l16) * DM + h * 64 + quad * 8;
    short8 qf0 = *(const short8*)(qp);
    short8 qf1 = *(const short8*)(qp + 32);

    f32x4 sc[8];
#pragma unroll
    for (int jt = 0; jt < 8; ++jt) {
        int j = jt * 16 + l16;
        int tok = t0 - 64 + j;
        tok = tok < 0 ? 0 : tok;
        const __hip_bfloat16* kp = K + (size_t)tok * DM + h * 64 + quad * 8;
        short8 b0 = *(const short8*)(kp);
        short8 b1 = *(const short8*)(kp + 32);
        f32x4 a = __builtin_amdgcn_mfma_f32_16x16x32_bf16(qf0, b0, (f32x4){0.f,0.f,0.f,0.f}, 0, 0, 0);
        sc[jt]  = __builtin_amdgcn_mfma_f32_16x16x32_bf16(qf1, b1, a, 0, 0, 0);
    }
    f32x4 sc2[2];
#pragma unroll
    for (int jt = 0; jt < 2; ++jt) {
        int c = cmin + jt * 16 + l16;
        if (c > 127) c = 127;
        const __hip_bfloat16* cp = CK + (size_t)c * DM + h * 64 + quad * 8;
        short8 b0 = *(const short8*)(cp);
        short8 b1 = *(const short8*)(cp + 32);
        f32x4 a = __builtin_amdgcn_mfma_f32_16x16x32_bf16(qf0, b0, (f32x4){0.f,0.f,0.f,0.f}, 0, 0, 0);
        sc2[jt] = __builtin_amdgcn_mfma_f32_16x16x32_bf16(qf1, b1, a, 0, 0, 0);
    }

    __syncthreads();  // all waves' Vts writes visible before PV reads

    const int rbase = w * 16 + quad * 4;
    float gl[4], g2[4];
    float mx[4], sm[4], mx2[4], sm2[4];
#pragma unroll
    for (int reg = 0; reg < 4; ++reg) {
        int rr = rbase + reg;
        int t  = t0 + rr;
        float g = G[t * NH + h];
        int rc = (t >= 96) ? ((t - 64) >> 5) : 0;
        gl[reg] = (t > 0)  ? g        : 0.f;
        g2[reg] = (rc > 0) ? (1.f - g) : 0.f;

        int jlo = rr > (64 - t0) ? rr : (64 - t0);
        int jhi = rr + 63;
        float m = -1e30f;
#pragma unroll
        for (int jt = 0; jt < 8; ++jt) {
            int j = jt * 16 + l16;
            float s = (j >= jlo && j <= jhi) ? sc[jt][reg] * scale : -1e30f;
            sc[jt][reg] = s;
            m = fmaxf(m, s);
        }
        mx[reg] = m;

        int nvis = rc < 16 ? rc : 16;
        int clo = rc - nvis, chi = rc - 1;
        float m2 = -1e30f;
#pragma unroll
        for (int jt = 0; jt < 2; ++jt) {
            int c = cmin + jt * 16 + l16;
            float s = (c >= clo && c <= chi) ? sc2[jt][reg] * scale : -1e30f;
            sc2[jt][reg] = s;
            m2 = fmaxf(m2, s);
        }
        mx2[reg] = m2;
    }
#pragma unroll
    for (int off = 1; off <= 8; off <<= 1)
#pragma unroll
        for (int reg = 0; reg < 4; ++reg) {
            mx[reg]  = fmaxf(mx[reg],  __shfl_xor(mx[reg],  off));
            mx2[reg] = fmaxf(mx2[reg], __shfl_xor(mx2[reg], off));
        }
#pragma unroll
    for (int reg = 0; reg < 4; ++reg) {
        float s = 0.f, s2 = 0.f;
#pragma unroll
        for (int jt = 0; jt < 8; ++jt) {
            float p = __expf(sc[jt][reg] - mx[reg]);
            sc[jt][reg] = p;
            s += p;
        }
#pragma unroll
        for (int jt = 0; jt < 2; ++jt) {
            float p = __expf(sc2[jt][reg] - mx2[reg]);
            sc2[jt][reg] = p;
            s2 += p;
        }
        sm[reg] = s; sm2[reg] = s2;
    }
#pragma unroll
    for (int off = 1; off <= 8; off <<= 1)
#pragma unroll
        for (int reg = 0; reg < 4; ++reg) {
            sm[reg]  += __shfl_xor(sm[reg],  off);
            sm2[reg] += __shfl_xor(sm2[reg], off);
        }

#pragma unroll
    for (int reg = 0; reg < 4; ++reg) {
        float f1 = gl[reg] / sm[reg];
        float f2 = g2[reg] / sm2[reg];
        int rowoff = (rbase + reg) * PSTR;
#pragma unroll
        for (int jt = 0; jt < 8; ++jt) {
            __hip_bfloat16 hb = (__hip_bfloat16)(sc[jt][reg] * f1);
            Pls[rowoff + jt * 16 + l16] = *(unsigned short*)&hb;
        }
#pragma unroll
        for (int jt = 0; jt < 2; ++jt) {
            __hip_bfloat16 hb = (__hip_bfloat16)(sc2[jt][reg] * f2);
            Pls[rowoff + 128 + jt * 16 + l16] = *(unsigned short*)&hb;
        }
    }
    asm volatile("s_waitcnt lgkmcnt(0)" ::: "memory");  // wave-private P round-trip

    f32x4 o[4];
#pragma unroll
    for (int nt = 0; nt < 4; ++nt) o[nt] = (f32x4){0.f, 0.f, 0.f, 0.f};
#pragma unroll
    for (int kt = 0; kt < 5; ++kt) {
        short8 a = *(const short8*)&Pls[(w * 16 + l16) * PSTR + kt * 32 + quad * 8];
#pragma unroll
        for (int nt = 0; nt < 4; ++nt) {
            int dd = nt * 16 + l16;
            short8 b = *(const short8*)&Vts[dd * PSTR + kt * 32 + quad * 8];
            o[nt] = __builtin_amdgcn_mfma_f32_16x16x32_bf16(a, b, o[nt], 0, 0, 0);
        }
    }

#pragma unroll
    for (int nt = 0; nt < 4; ++nt) {
#pragma unroll
        for (int reg = 0; reg < 4; ++reg) {
            int row = t0 + rbase + reg;
            int col = h * 64 + nt * 16 + l16;
            Aout[(size_t)row * DM + col] = (__hip_bfloat16)(o[nt][reg]);
        }
    }
}

extern "C" void kernel_launch(void* const* d_in, const int* in_sizes, int n_in,
                              void* d_out, int out_size, void* d_ws, size_t ws_size,
                              hipStream_t stream)
{
    const float* x  = (const float*)d_in[0];
    const float* Wq = (const float*)d_in[1];
    const float* bq = (const float*)d_in[2];
    const float* Wk = (const float*)d_in[3];
    const float* bk = (const float*)d_in[4];
    const float* Wv = (const float*)d_in[5];
    const float* bv = (const float*)d_in[6];
    const float* Wo = (const float*)d_in[7];
    const float* bo = (const float*)d_in[8];
    const float* Wg = (const float*)d_in[9];
    const float* bg = (const float*)d_in[10];
    float* out = (float*)d_out;

    char* ws = (char*)d_ws;
    const size_t MB = 1024 * 1024;
    __hip_bfloat16* xb  = (__hip_bfloat16*)(ws + 0 * MB);   // 8 MB
    __hip_bfloat16* Qb  = (__hip_bfloat16*)(ws + 8 * MB);   // 8 MB
    __hip_bfloat16* Kb  = (__hip_bfloat16*)(ws + 16 * MB);  // 8 MB
    __hip_bfloat16* Vb  = (__hip_bfloat16*)(ws + 24 * MB);  // 8 MB
    __hip_bfloat16* Ab  = (__hip_bfloat16*)(ws + 32 * MB);  // 8 MB
    __hip_bfloat16* Wqb = (__hip_bfloat16*)(ws + 40 * MB);  // 2 MB
    __hip_bfloat16* Wkb = (__hip_bfloat16*)(ws + 42 * MB);  // 2 MB
    __hip_bfloat16* Wvb = (__hip_bfloat16*)(ws + 44 * MB);  // 2 MB
    __hip_bfloat16* Wob = (__hip_bfloat16*)(ws + 46 * MB);  // 2 MB
    __hip_bfloat16* CKb = (__hip_bfloat16*)(ws + 48 * MB);            // 256 KB
    __hip_bfloat16* CVb = (__hip_bfloat16*)(ws + 48 * MB + 256*1024); // 256 KB
    float* Gf           = (float*)(ws + 48 * MB + 512 * 1024);        // 256 KB
    __hip_bfloat16* Wgb = (__hip_bfloat16*)(ws + 48 * MB + 768*1024); // 32 KB

    cast_all<<<dim3(8208), 256, 0, stream>>>(x, Wq, Wk, Wv, Wo, Wg,
                                             xb, Wqb, Wkb, Wvb, Wob, Wgb);

    // Fused QKV GEMM, 256^2 4-phase schedule: grid (16, 12); group = y>>2.
    gemm256<__hip_bfloat16><<<dim3(16, 12), 512, 0, stream>>>(
        xb, Wqb, Wkb, Wvb, bq, bk, bv, Qb, Kb, Vb);
    // Merged chunk-means + gate GEMM (one dispatch, independent halves).
    aux_kernel<<<dim3(320), 256, 0, stream>>>(Kb, Vb, xb, Wgb, bg, CKb, CVb, Gf);
    attn_mfma<<<dim3(64, 16), 256, 0, stream>>>(Qb, Kb, Vb, CKb, CVb, Gf, Ab);
    // Output GEMM: 128x64 tiles, grid (32, 16) = 512 blocks.
    gemm_n64<float><<<dim3(32, 16), 256, 0, stream>>>(Ab, Wob, bo, out);
}

// Round 8
// 176.311 us; speedup vs baseline: 1.2170x; 1.0059x over previous
//
#include <hip/hip_runtime.h>
#include <hip/hip_bf16.h>
#include <math.h>

typedef __attribute__((ext_vector_type(8))) short short8;
typedef __attribute__((ext_vector_type(4))) float f32x4;

#define TT 4096
#define DM 1024
#define NH 16
#define HD 64
#define PSTR 168   // attn LDS row stride in halfwords (84 dwords == 20 mod 32 banks)

typedef __attribute__((address_space(3))) unsigned int lds_u32;
typedef __attribute__((address_space(1))) unsigned int glb_u32;

__device__ __forceinline__ void async_cp16(const void* g, void* l) {
    __builtin_amdgcn_global_load_lds((glb_u32*)g, (lds_u32*)l, 16, 0, 0);
}

__device__ __forceinline__ float bf2f(unsigned short u) {
    union { unsigned int i; float f; } v;
    v.i = (unsigned int)u << 16;
    return v.f;
}

// Fused fp32 -> bf16 cast for x + Wq/Wk/Wv/Wo + Wg.
__global__ __launch_bounds__(256) void cast_all(
    const float* __restrict__ x,  const float* __restrict__ wq,
    const float* __restrict__ wk, const float* __restrict__ wv,
    const float* __restrict__ wo, const float* __restrict__ wg,
    __hip_bfloat16* __restrict__ xb,  __hip_bfloat16* __restrict__ wqb,
    __hip_bfloat16* __restrict__ wkb, __hip_bfloat16* __restrict__ wvb,
    __hip_bfloat16* __restrict__ wob, __hip_bfloat16* __restrict__ wgb)
{
    int b = blockIdx.x;
    const float* src;
    __hip_bfloat16* dst;
    size_t base;
    if (b < 4096)      { src = x;  dst = xb;  base = (size_t)b * 1024; }
    else if (b < 5120) { src = wq; dst = wqb; base = (size_t)(b - 4096) * 1024; }
    else if (b < 6144) { src = wk; dst = wkb; base = (size_t)(b - 5120) * 1024; }
    else if (b < 7168) { src = wv; dst = wvb; base = (size_t)(b - 6144) * 1024; }
    else if (b < 8192) { src = wo; dst = wob; base = (size_t)(b - 7168) * 1024; }
    else               { src = wg; dst = wgb; base = (size_t)(b - 8192) * 1024; }
    size_t i = base + (size_t)threadIdx.x * 4;
    float4 v = *(const float4*)(src + i);
    __hip_bfloat16 h0 = (__hip_bfloat16)v.x;
    __hip_bfloat16 h1 = (__hip_bfloat16)v.y;
    __hip_bfloat16 h2 = (__hip_bfloat16)v.z;
    __hip_bfloat16 h3 = (__hip_bfloat16)v.w;
    ushort4 u;
    u.x = *(unsigned short*)&h0;
    u.y = *(unsigned short*)&h1;
    u.z = *(unsigned short*)&h2;
    u.w = *(unsigned short*)&h3;
    *(ushort4*)((unsigned short*)dst + i) = u;
}

// ---------------------------------------------------------------------------
// 256x192-tile QKV GEMM over VIRTUAL concatenated B (Wqb|Wkb|Wvb contiguous
// at ws+40..46MB -> one 3072x1024 matrix) and concatenated output (Qb|Kb|Vb
// contiguous 8MB regions). Grid (16,16) = 256 blocks = FULL machine at
// 1 block/CU -- fixes r7's 192-block / 75%-utilization null (the 4-phase
// schedule delivered ~1.33x per-CU, cancelled by 64 idle CUs).
// 8 waves (2Mx4N), per-wave 128x48, acc[8][3]. Staging unit = 64 rows x
// 64 k = 8KB = exactly 1 global_load_lds per thread; 7 units/K-tile
// (A0..A3,B0..B2); LDS 2 bufs x 7 x 8KB = 112 KB.
// Slot-free schedule: {B*,A0,A2} staged after p1-mid barrier (all reads of
// those slots closed), {A1,A3} after p2-mid barrier. Issue stream = 7
// loads/tile -> steady-state s_waitcnt vmcnt(7) at p0 (vmcnt(0) at t=15).
// Swizzle: LDS[r][c] holds G[r][c^(r&7)]; read chunk (ks*4+quad)^(l16&7);
// staged via pre-swizzled global source chunk (tid&7)^((tid>>3)&7).
// ---------------------------------------------------------------------------
template <typename OutT>
__global__ __launch_bounds__(512, 2) void gemm192(
    const __hip_bfloat16* __restrict__ A,      // xb [4096][1024]
    const __hip_bfloat16* __restrict__ Bcat,   // Wqb|Wkb|Wvb [3072][1024]
    const float* __restrict__ c0, const float* __restrict__ c1, const float* __restrict__ c2,
    OutT* __restrict__ Ocat)                   // Qb|Kb|Vb [3][4096][1024]
{
    const int K  = DM;
    const int NT = 16;   // K / 64
    __shared__ __align__(16) unsigned short sL[2][7][64 * 64];  // [buf][A0..A3,B0,B1,B2]

    const int tid  = threadIdx.x;
    const int w    = tid >> 6;
    const int lane = tid & 63;
    const int l16  = lane & 15;
    const int quad = lane >> 4;
    const int wr   = w >> 2;      // 0,1: A row half (128 rows)
    const int wc   = w & 3;       // 0..3: 48-col slice
    const int rowBase = blockIdx.x * 256;
    const int colBase = blockIdx.y * 192;

    // Staging: thread t loads 16B: row = unit*64 + (t>>3), global chunk
    // (t&7)^((t>>3)&7) -> LDS linear dest (both-sides swizzle rule).
    const int srow8 = tid >> 3;                 // 0..63
    const int schk  = (tid & 7) ^ (srow8 & 7);
    const __hip_bfloat16* gA = A    + (size_t)(rowBase + srow8) * K + schk * 8;
    const __hip_bfloat16* gB = Bcat + (size_t)(colBase + srow8) * K + schk * 8;
    const int ldst = w * 512;                   // wave-uniform dest (halfwords)

#define STGA(buf, ua, kt) async_cp16(gA + (size_t)(ua) * 64 * K + (kt) * 64, &sL[buf][ua][ldst])
#define STGB(buf, ub, kt) async_cp16(gB + (size_t)(ub) * 64 * K + (kt) * 64, &sL[buf][4 + (ub)][ldst])

    // read-side swizzled chunk offsets (halfwords) for k-slot 0/1
    const int cs0 = ((quad)     ^ (l16 & 7)) * 8;
    const int cs1 = ((4 + quad) ^ (l16 & 7)) * 8;

    f32x4 acc[8][3];
#pragma unroll
    for (int i = 0; i < 8; ++i)
#pragma unroll
        for (int j = 0; j < 3; ++j) acc[i][j] = (f32x4){0.f, 0.f, 0.f, 0.f};

    // Prologue: tile0 -> buf0 (7 units), tile1 -> buf1 (7 units).
    STGB(0, 0, 0); STGB(0, 1, 0); STGB(0, 2, 0);
    STGA(0, 0, 0); STGA(0, 2, 0); STGA(0, 1, 0); STGA(0, 3, 0);
    STGB(1, 0, 1); STGB(1, 1, 1); STGB(1, 2, 1);
    STGA(1, 0, 1); STGA(1, 2, 1); STGA(1, 1, 1); STGA(1, 3, 1);

    short8 af[4][2], bf[3][2];
    for (int t = 0; t < NT; ++t) {
        const int b = t & 1;
        const unsigned short* paL = &sL[b][wr * 2][0];
        const unsigned short* paH = &sL[b][wr * 2 + 1][0];

        // ---- phase 0: af-lo(8) + bf0(2); 8 MFMA ----
        if (t == NT - 1) asm volatile("s_waitcnt vmcnt(0)" ::: "memory");
        else             asm volatile("s_waitcnt vmcnt(7)" ::: "memory");
        __builtin_amdgcn_s_barrier();
#pragma unroll
        for (int m = 0; m < 4; ++m) {
            af[m][0] = *(const short8*)&paL[(m * 16 + l16) * 64 + cs0];
            af[m][1] = *(const short8*)&paL[(m * 16 + l16) * 64 + cs1];
        }
        {
            const int bu  = (wc * 48) >> 6;
            const int bro = (wc * 48) & 63;
            const unsigned short* pb = &sL[b][4 + bu][0];
            bf[0][0] = *(const short8*)&pb[(bro + l16) * 64 + cs0];
            bf[0][1] = *(const short8*)&pb[(bro + l16) * 64 + cs1];
        }
        asm volatile("s_waitcnt lgkmcnt(0)" ::: "memory");
        __builtin_amdgcn_sched_barrier(0);
        __builtin_amdgcn_s_setprio(1);
#pragma unroll
        for (int ks = 0; ks < 2; ++ks)
#pragma unroll
            for (int m = 0; m < 4; ++m)
                acc[m][0] = __builtin_amdgcn_mfma_f32_16x16x32_bf16(af[m][ks], bf[0][ks], acc[m][0], 0, 0, 0);
        __builtin_amdgcn_s_setprio(0);

        // ---- phase 1: bf1,bf2(4); barrier closes ALL reads of B*,A0,A2;
        //      stage those 5 units for t+2; 16 MFMA ----
#pragma unroll
        for (int n = 1; n < 3; ++n) {
            const int bu  = (wc * 48 + n * 16) >> 6;
            const int bro = (wc * 48 + n * 16) & 63;
            const unsigned short* pb = &sL[b][4 + bu][0];
            bf[n][0] = *(const short8*)&pb[(bro + l16) * 64 + cs0];
            bf[n][1] = *(const short8*)&pb[(bro + l16) * 64 + cs1];
        }
        asm volatile("s_waitcnt lgkmcnt(0)" ::: "memory");
        __builtin_amdgcn_sched_barrier(0);
        __builtin_amdgcn_s_barrier();
        if (t + 2 < NT) {
            STGB(b, 0, t + 2); STGB(b, 1, t + 2); STGB(b, 2, t + 2);
            STGA(b, 0, t + 2); STGA(b, 2, t + 2);
        }
        __builtin_amdgcn_s_setprio(1);
#pragma unroll
        for (int ks = 0; ks < 2; ++ks)
#pragma unroll
            for (int m = 0; m < 4; ++m)
#pragma unroll
                for (int n = 1; n < 3; ++n)
                    acc[m][n] = __builtin_amdgcn_mfma_f32_16x16x32_bf16(af[m][ks], bf[n][ks], acc[m][n], 0, 0, 0);
        __builtin_amdgcn_s_setprio(0);

        // ---- phase 2: af-hi(8); barrier closes A1,A3 reads; stage them;
        //      8 MFMA ----
#pragma unroll
        for (int m = 0; m < 4; ++m) {
            af[m][0] = *(const short8*)&paH[(m * 16 + l16) * 64 + cs0];
            af[m][1] = *(const short8*)&paH[(m * 16 + l16) * 64 + cs1];
        }
        asm volatile("s_waitcnt lgkmcnt(0)" ::: "memory");
        __builtin_amdgcn_sched_barrier(0);
        __builtin_amdgcn_s_barrier();
        if (t + 2 < NT) { STGA(b, 1, t + 2); STGA(b, 3, t + 2); }
        __builtin_amdgcn_s_setprio(1);
#pragma unroll
        for (int ks = 0; ks < 2; ++ks)
#pragma unroll
            for (int m = 0; m < 4; ++m)
                acc[m + 4][0] = __builtin_amdgcn_mfma_f32_16x16x32_bf16(af[m][ks], bf[0][ks], acc[m + 4][0], 0, 0, 0);
        __builtin_amdgcn_s_setprio(0);

        // ---- phase 3: no reads, no barrier; 16 MFMA ----
        __builtin_amdgcn_s_setprio(1);
#pragma unroll
        for (int ks = 0; ks < 2; ++ks)
#pragma unroll
            for (int m = 0; m < 4; ++m)
#pragma unroll
                for (int n = 1; n < 3; ++n)
                    acc[m + 4][n] = __builtin_amdgcn_mfma_f32_16x16x32_bf16(af[m][ks], bf[n][ks], acc[m + 4][n], 0, 0, 0);
        __builtin_amdgcn_s_setprio(0);
    }
#undef STGA
#undef STGB

    // Epilogue: per 16-wide fragment, grp = col>>10 is uniform (1024%16==0).
#pragma unroll
    for (int n = 0; n < 3; ++n) {
        int col = colBase + wc * 48 + n * 16 + l16;
        int grp = col >> 10;
        int cl  = col & 1023;
        const float* bias = grp == 0 ? c0 : (grp == 1 ? c1 : c2);
        float bv = bias[cl];
        OutT* O = Ocat + (size_t)grp * TT * DM;
#pragma unroll
        for (int m = 0; m < 8; ++m) {
#pragma unroll
            for (int r = 0; r < 4; ++r) {
                int row = rowBase + wr * 128 + m * 16 + quad * 4 + r;
                O[(size_t)row * DM + cl] = (OutT)(acc[m][n][r] + bv);
            }
        }
    }
}

// 128x64-tile GEMM for the Wo projection, counted-vmcnt 2-deep pipeline
// (r6 version, known-passing). LDS 2x12 = 24 KB.
template <typename OutT>
__global__ __launch_bounds__(256) void gemm_n64(
    const __hip_bfloat16* __restrict__ A,
    const __hip_bfloat16* __restrict__ B,
    const float* __restrict__ bias,
    OutT* __restrict__ O)
{
    const int K = DM;
    const int NT = 32;
    __shared__ __align__(16) unsigned short sA[2 * 128 * 32];
    __shared__ __align__(16) unsigned short sB[2 * 64 * 32];

    const int tid  = threadIdx.x;
    const int w    = tid >> 6;
    const int lane = tid & 63;
    const int l16  = lane & 15;
    const int quad = lane >> 4;
    const int rowBase = blockIdx.x * 128;
    const int colBase = blockIdx.y * 64;

    const int srow   = lane >> 2;
    const int sswz   = (srow & 3) ^ (srow >> 2);
    const int gchunk = (lane & 3) ^ sswz;
    const __hip_bfloat16* gA = A + (size_t)(rowBase + w * 32 + srow) * K + gchunk * 8;
    const __hip_bfloat16* gB = B + (size_t)(colBase + w * 16 + srow) * K + gchunk * 8;
    unsigned short* lA0 = sA + w * 32 * 32;
    unsigned short* lB0 = sB + w * 16 * 32;

    const int fswz = (l16 & 3) ^ (l16 >> 2);
    const int mrow = w * 32;

    f32x4 acc[2][4];
#pragma unroll
    for (int i = 0; i < 2; ++i)
#pragma unroll
        for (int j = 0; j < 4; ++j) acc[i][j] = (f32x4){0.f, 0.f, 0.f, 0.f};

    async_cp16(gA,                  lA0);
    async_cp16(gA + (size_t)16 * K, lA0 + 16 * 32);
    async_cp16(gB,                  lB0);
    async_cp16(gA + 32,                  lA0 + 128 * 32);
    async_cp16(gA + 32 + (size_t)16 * K, lA0 + 128 * 32 + 16 * 32);
    async_cp16(gB + 32,                  lB0 + 64 * 32);

    for (int t = 0; t < NT; ++t) {
        if (t == NT - 1) asm volatile("s_waitcnt vmcnt(0)" ::: "memory");
        else             asm volatile("s_waitcnt vmcnt(3)" ::: "memory");
        __builtin_amdgcn_s_barrier();

        const unsigned short* pA = sA + (t & 1) * (128 * 32);
        const unsigned short* pB = sB + (t & 1) * (64 * 32);
        short8 af[2], bf[4];
#pragma unroll
        for (int mt = 0; mt < 2; ++mt)
            af[mt] = *(const short8*)&pA[(mrow + mt * 16 + l16) * 32 + (quad ^ fswz) * 8];
#pragma unroll
        for (int nt = 0; nt < 4; ++nt)
            bf[nt] = *(const short8*)&pB[(nt * 16 + l16) * 32 + (quad ^ fswz) * 8];
        asm volatile("s_waitcnt lgkmcnt(0)" ::: "memory");
        __builtin_amdgcn_sched_barrier(0);
        __builtin_amdgcn_s_barrier();

        if (t + 2 < NT) {
            const int k2 = (t + 2) * 32;
            unsigned short* dA = lA0 + (t & 1) * (128 * 32);
            unsigned short* dB = lB0 + (t & 1) * (64 * 32);
            async_cp16(gA + k2,                  dA);
            async_cp16(gA + k2 + (size_t)16 * K, dA + 16 * 32);
            async_cp16(gB + k2,                  dB);
        }

#pragma unroll
        for (int mt = 0; mt < 2; ++mt)
#pragma unroll
            for (int nt = 0; nt < 4; ++nt)
                acc[mt][nt] = __builtin_amdgcn_mfma_f32_16x16x32_bf16(af[mt], bf[nt], acc[mt][nt], 0, 0, 0);
    }

#pragma unroll
    for (int nt = 0; nt < 4; ++nt) {
        int col = colBase + nt * 16 + l16;
        float bv = bias[col];
#pragma unroll
        for (int mt = 0; mt < 2; ++mt) {
#pragma unroll
            for (int r = 0; r < 4; ++r) {
                int row = rowBase + mrow + mt * 16 + quad * 4 + r;
                O[(size_t)row * DM + col] = (OutT)(acc[mt][nt][r] + bv);
            }
        }
    }
}

// Merged auxiliary kernel (chunk means, ushort2-vectorized + gate GEMM).
__global__ __launch_bounds__(256) void aux_kernel(
    const __hip_bfloat16* __restrict__ K,
    const __hip_bfloat16* __restrict__ V,
    const __hip_bfloat16* __restrict__ xb,
    const __hip_bfloat16* __restrict__ Wgb,
    const float* __restrict__ bg,
    __hip_bfloat16* __restrict__ CK,
    __hip_bfloat16* __restrict__ CV,
    float* __restrict__ G)
{
    const int b = blockIdx.x;
    if (b < 256) {
        const int c  = b >> 1;
        const int d0 = (b & 1) * 512 + threadIdx.x * 2;
        const unsigned short* Ku = (const unsigned short*)K;
        const unsigned short* Vu = (const unsigned short*)V;
        float ak0 = 0.f, ak1 = 0.f, av0 = 0.f, av1 = 0.f;
#pragma unroll 8
        for (int i = 0; i < 32; ++i) {
            size_t off = (size_t)(c * 32 + i) * DM + d0;
            ushort2 kv = *(const ushort2*)(Ku + off);
            ushort2 vv = *(const ushort2*)(Vu + off);
            ak0 += bf2f(kv.x); ak1 += bf2f(kv.y);
            av0 += bf2f(vv.x); av1 += bf2f(vv.y);
        }
        __hip_bfloat16 k0 = (__hip_bfloat16)(ak0 * (1.f / 32.f));
        __hip_bfloat16 k1 = (__hip_bfloat16)(ak1 * (1.f / 32.f));
        __hip_bfloat16 v0 = (__hip_bfloat16)(av0 * (1.f / 32.f));
        __hip_bfloat16 v1 = (__hip_bfloat16)(av1 * (1.f / 32.f));
        ushort2 ko, vo;
        ko.x = *(unsigned short*)&k0; ko.y = *(unsigned short*)&k1;
        vo.x = *(unsigned short*)&v0; vo.y = *(unsigned short*)&v1;
        *(ushort2*)((unsigned short*)CK + (size_t)c * DM + d0) = ko;
        *(ushort2*)((unsigned short*)CV + (size_t)c * DM + d0) = vo;
        return;
    }
    const int unit = threadIdx.x >> 6;
    const int lane = threadIdx.x & 63;
    const int l16  = lane & 15;
    const int quad = lane >> 4;
    const int t0   = (b - 256) * 64 + unit * 16;
    const __hip_bfloat16* ap = xb  + (size_t)(t0 + l16) * DM + quad * 8;
    const __hip_bfloat16* bp = Wgb + (size_t)l16 * DM + quad * 8;
    f32x4 acc = (f32x4){0.f, 0.f, 0.f, 0.f};
#pragma unroll 4
    for (int k0 = 0; k0 < DM; k0 += 32) {
        short8 a = *(const short8*)(ap + k0);
        short8 bb = *(const short8*)(bp + k0);
        acc = __builtin_amdgcn_mfma_f32_16x16x32_bf16(a, bb, acc, 0, 0, 0);
    }
    float bgv = bg[l16];
#pragma unroll
    for (int r = 0; r < 4; ++r) {
        int t = t0 + quad * 4 + r;
        float z = acc[r] + bgv;
        G[t * NH + l16] = 1.f / (1.f + __expf(-z));
    }
}

// MFMA attention: 64 queries x 1 head per block (grid 64 x 16, 256 threads).
__global__ __launch_bounds__(256) void attn_mfma(
    const __hip_bfloat16* __restrict__ Q,
    const __hip_bfloat16* __restrict__ K,
    const __hip_bfloat16* __restrict__ V,
    const __hip_bfloat16* __restrict__ CK,
    const __hip_bfloat16* __restrict__ CV,
    const float* __restrict__ G,
    __hip_bfloat16* __restrict__ Aout)
{
    __shared__ alignas(16) unsigned short Pls[64 * PSTR];
    __shared__ alignas(16) unsigned short Vts[64 * PSTR];

    const int h   = blockIdx.y;
    const int t0  = blockIdx.x * 64;
    const int tid = threadIdx.x;
    const int w    = tid >> 6;
    const int lane = tid & 63;
    const int l16  = lane & 15;
    const int quad = lane >> 4;
    const float scale = 0.125f;

    const int rc0  = (t0 >= 96) ? ((t0 - 64) >> 5) : 0;
    const int cmin = rc0 > 16 ? rc0 - 16 : 0;

    const unsigned short* Vu  = (const unsigned short*)V;
    const unsigned short* CVu = (const unsigned short*)CV;

    {
#pragma unroll
        for (int gg = 0; gg < 2; ++gg) {
            const int g = w * 2 + gg;
#pragma unroll
            for (int i = 0; i < 2; ++i) {
                const int pair = lane + 64 * i;
                if (pair < 80) {
                    const int j = pair * 2;
                    const unsigned short *s0, *s1;
                    if (j < 128) {
                        int tok0 = t0 - 64 + j; if (tok0 < 0) tok0 = 0;
                        int tok1 = t0 - 63 + j; if (tok1 < 0) tok1 = 0;
                        s0 = Vu + (size_t)tok0 * DM + h * 64 + g * 8;
                        s1 = Vu + (size_t)tok1 * DM + h * 64 + g * 8;
                    } else {
                        int c0 = cmin + (j - 128); if (c0 > 127) c0 = 127;
                        int c1 = c0 + 1;           if (c1 > 127) c1 = 127;
                        s0 = CVu + (size_t)c0 * DM + h * 64 + g * 8;
                        s1 = CVu + (size_t)c1 * DM + h * 64 + g * 8;
                    }
                    short8 v0 = *(const short8*)s0;
                    short8 v1 = *(const short8*)s1;
#pragma unroll
                    for (int e = 0; e < 8; ++e) {
                        ushort2 pk;
                        pk.x = (unsigned short)v0[e];
                        pk.y = (unsigned short)v1[e];
                        *(ushort2*)&Vts[(g * 8 + e) * PSTR + j] = pk;
                    }
                }
            }
        }
    }

    const __hip_bfloat16* qp = Q + (size_t)(t0 + w * 16 + l16) * DM + h * 64 + quad * 8;
    short8 qf0 = *(const short8*)(qp);
    short8 qf1 = *(const short8*)(qp + 32);

    f32x4 sc[8];
#pragma unroll
    for (int jt = 0; jt < 8; ++jt) {
        int j = jt * 16 + l16;
        int tok = t0 - 64 + j;
        tok = tok < 0 ? 0 : tok;
        const __hip_bfloat16* kp = K + (size_t)tok * DM + h * 64 + quad * 8;
        short8 b0 = *(const short8*)(kp);
        short8 b1 = *(const short8*)(kp + 32);
        f32x4 a = __builtin_amdgcn_mfma_f32_16x16x32_bf16(qf0, b0, (f32x4){0.f,0.f,0.f,0.f}, 0, 0, 0);
        sc[jt]  = __builtin_amdgcn_mfma_f32_16x16x32_bf16(qf1, b1, a, 0, 0, 0);
    }
    f32x4 sc2[2];
#pragma unroll
    for (int jt = 0; jt < 2; ++jt) {
        int c = cmin + jt * 16 + l16;
        if (c > 127) c = 127;
        const __hip_bfloat16* cp = CK + (size_t)c * DM + h * 64 + quad * 8;
        short8 b0 = *(const short8*)(cp);
        short8 b1 = *(const short8*)(cp + 32);
        f32x4 a = __builtin_amdgcn_mfma_f32_16x16x32_bf16(qf0, b0, (f32x4){0.f,0.f,0.f,0.f}, 0, 0, 0);
        sc2[jt] = __builtin_amdgcn_mfma_f32_16x16x32_bf16(qf1, b1, a, 0, 0, 0);
    }

    __syncthreads();  // all waves' Vts writes visible before PV reads

    const int rbase = w * 16 + quad * 4;
    float gl[4], g2[4];
    float mx[4], sm[4], mx2[4], sm2[4];
#pragma unroll
    for (int reg = 0; reg < 4; ++reg) {
        int rr = rbase + reg;
        int t  = t0 + rr;
        float g = G[t * NH + h];
        int rc = (t >= 96) ? ((t - 64) >> 5) : 0;
        gl[reg] = (t > 0)  ? g        : 0.f;
        g2[reg] = (rc > 0) ? (1.f - g) : 0.f;

        int jlo = rr > (64 - t0) ? rr : (64 - t0);
        int jhi = rr + 63;
        float m = -1e30f;
#pragma unroll
        for (int jt = 0; jt < 8; ++jt) {
            int j = jt * 16 + l16;
            float s = (j >= jlo && j <= jhi) ? sc[jt][reg] * scale : -1e30f;
            sc[jt][reg] = s;
            m = fmaxf(m, s);
        }
        mx[reg] = m;

        int nvis = rc < 16 ? rc : 16;
        int clo = rc - nvis, chi = rc - 1;
        float m2 = -1e30f;
#pragma unroll
        for (int jt = 0; jt < 2; ++jt) {
            int c = cmin + jt * 16 + l16;
            float s = (c >= clo && c <= chi) ? sc2[jt][reg] * scale : -1e30f;
            sc2[jt][reg] = s;
            m2 = fmaxf(m2, s);
        }
        mx2[reg] = m2;
    }
#pragma unroll
    for (int off = 1; off <= 8; off <<= 1)
#pragma unroll
        for (int reg = 0; reg < 4; ++reg) {
            mx[reg]  = fmaxf(mx[reg],  __shfl_xor(mx[reg],  off));
            mx2[reg] = fmaxf(mx2[reg], __shfl_xor(mx2[reg], off));
        }
#pragma unroll
    for (int reg = 0; reg < 4; ++reg) {
        float s = 0.f, s2 = 0.f;
#pragma unroll
        for (int jt = 0; jt < 8; ++jt) {
            float p = __expf(sc[jt][reg] - mx[reg]);
            sc[jt][reg] = p;
            s += p;
        }
#pragma unroll
        for (int jt = 0; jt < 2; ++jt) {
            float p = __expf(sc2[jt][reg] - mx2[reg]);
            sc2[jt][reg] = p;
            s2 += p;
        }
        sm[reg] = s; sm2[reg] = s2;
    }
#pragma unroll
    for (int off = 1; off <= 8; off <<= 1)
#pragma unroll
        for (int reg = 0; reg < 4; ++reg) {
            sm[reg]  += __shfl_xor(sm[reg],  off);
            sm2[reg] += __shfl_xor(sm2[reg], off);
        }

#pragma unroll
    for (int reg = 0; reg < 4; ++reg) {
        float f1 = gl[reg] / sm[reg];
        float f2 = g2[reg] / sm2[reg];
        int rowoff = (rbase + reg) * PSTR;
#pragma unroll
        for (int jt = 0; jt < 8; ++jt) {
            __hip_bfloat16 hb = (__hip_bfloat16)(sc[jt][reg] * f1);
            Pls[rowoff + jt * 16 + l16] = *(unsigned short*)&hb;
        }
#pragma unroll
        for (int jt = 0; jt < 2; ++jt) {
            __hip_bfloat16 hb = (__hip_bfloat16)(sc2[jt][reg] * f2);
            Pls[rowoff + 128 + jt * 16 + l16] = *(unsigned short*)&hb;
        }
    }
    asm volatile("s_waitcnt lgkmcnt(0)" ::: "memory");  // wave-private P round-trip

    f32x4 o[4];
#pragma unroll
    for (int nt = 0; nt < 4; ++nt) o[nt] = (f32x4){0.f, 0.f, 0.f, 0.f};
#pragma unroll
    for (int kt = 0; kt < 5; ++kt) {
        short8 a = *(const short8*)&Pls[(w * 16 + l16) * PSTR + kt * 32 + quad * 8];
#pragma unroll
        for (int nt = 0; nt < 4; ++nt) {
            int dd = nt * 16 + l16;
            short8 b = *(const short8*)&Vts[dd * PSTR + kt * 32 + quad * 8];
            o[nt] = __builtin_amdgcn_mfma_f32_16x16x32_bf16(a, b, o[nt], 0, 0, 0);
        }
    }

#pragma unroll
    for (int nt = 0; nt < 4; ++nt) {
#pragma unroll
        for (int reg = 0; reg < 4; ++reg) {
            int row = t0 + rbase + reg;
            int col = h * 64 + nt * 16 + l16;
            Aout[(size_t)row * DM + col] = (__hip_bfloat16)(o[nt][reg]);
        }
    }
}

extern "C" void kernel_launch(void* const* d_in, const int* in_sizes, int n_in,
                              void* d_out, int out_size, void* d_ws, size_t ws_size,
                              hipStream_t stream)
{
    const float* x  = (const float*)d_in[0];
    const float* Wq = (const float*)d_in[1];
    const float* bq = (const float*)d_in[2];
    const float* Wk = (const float*)d_in[3];
    const float* bk = (const float*)d_in[4];
    const float* Wv = (const float*)d_in[5];
    const float* bv = (const float*)d_in[6];
    const float* Wo = (const float*)d_in[7];
    const float* bo = (const float*)d_in[8];
    const float* Wg = (const float*)d_in[9];
    const float* bg = (const float*)d_in[10];
    float* out = (float*)d_out;

    char* ws = (char*)d_ws;
    const size_t MB = 1024 * 1024;
    __hip_bfloat16* xb  = (__hip_bfloat16*)(ws + 0 * MB);   // 8 MB
    __hip_bfloat16* Qb  = (__hip_bfloat16*)(ws + 8 * MB);   // 8 MB  } contiguous
    __hip_bfloat16* Kb  = (__hip_bfloat16*)(ws + 16 * MB);  // 8 MB  } Ocat for
    __hip_bfloat16* Vb  = (__hip_bfloat16*)(ws + 24 * MB);  // 8 MB  } gemm192
    __hip_bfloat16* Ab  = (__hip_bfloat16*)(ws + 32 * MB);  // 8 MB
    __hip_bfloat16* Wqb = (__hip_bfloat16*)(ws + 40 * MB);  // 2 MB  } contiguous
    __hip_bfloat16* Wkb = (__hip_bfloat16*)(ws + 42 * MB);  // 2 MB  } Bcat for
    __hip_bfloat16* Wvb = (__hip_bfloat16*)(ws + 44 * MB);  // 2 MB  } gemm192
    __hip_bfloat16* Wob = (__hip_bfloat16*)(ws + 46 * MB);  // 2 MB
    __hip_bfloat16* CKb = (__hip_bfloat16*)(ws + 48 * MB);            // 256 KB
    __hip_bfloat16* CVb = (__hip_bfloat16*)(ws + 48 * MB + 256*1024); // 256 KB
    float* Gf           = (float*)(ws + 48 * MB + 512 * 1024);        // 256 KB
    __hip_bfloat16* Wgb = (__hip_bfloat16*)(ws + 48 * MB + 768*1024); // 32 KB

    cast_all<<<dim3(8208), 256, 0, stream>>>(x, Wq, Wk, Wv, Wo, Wg,
                                             xb, Wqb, Wkb, Wvb, Wob, Wgb);

    // Fused QKV GEMM, 256x192 tiles over concatenated B/O: grid (16,16)
    // = 256 blocks = full machine.
    gemm192<__hip_bfloat16><<<dim3(16, 16), 512, 0, stream>>>(
        xb, Wqb, bq, bk, bv, Qb);
    // Merged chunk-means + gate GEMM (one dispatch, independent halves).
    aux_kernel<<<dim3(320), 256, 0, stream>>>(Kb, Vb, xb, Wgb, bg, CKb, CVb, Gf);
    attn_mfma<<<dim3(64, 16), 256, 0, stream>>>(Qb, Kb, Vb, CKb, CVb, Gf, Ab);
    // Output GEMM: 128x64 tiles, grid (32, 16) = 512 blocks.
    gemm_n64<float><<<dim3(32, 16), 256, 0, stream>>>(Ab, Wob, bo, out);
}

// Round 9
// 173.053 us; speedup vs baseline: 1.2399x; 1.0188x over previous
//
#include <hip/hip_runtime.h>
#include <hip/hip_bf16.h>
#include <math.h>

typedef __attribute__((ext_vector_type(8))) short short8;
typedef __attribute__((ext_vector_type(4))) float f32x4;

#define TT 4096
#define DM 1024
#define NH 16
#define HD 64
#define PSTR 168   // attn LDS row stride in halfwords (84 dwords == 20 mod 32 banks)

typedef __attribute__((address_space(3))) unsigned int lds_u32;
typedef __attribute__((address_space(1))) unsigned int glb_u32;

__device__ __forceinline__ void async_cp16(const void* g, void* l) {
    __builtin_amdgcn_global_load_lds((glb_u32*)g, (lds_u32*)l, 16, 0, 0);
}

__device__ __forceinline__ float bf2f(unsigned short u) {
    union { unsigned int i; float f; } v;
    v.i = (unsigned int)u << 16;
    return v.f;
}

// Fused fp32 -> bf16 cast for x + Wq/Wk/Wv/Wo + Wg.
__global__ __launch_bounds__(256) void cast_all(
    const float* __restrict__ x,  const float* __restrict__ wq,
    const float* __restrict__ wk, const float* __restrict__ wv,
    const float* __restrict__ wo, const float* __restrict__ wg,
    __hip_bfloat16* __restrict__ xb,  __hip_bfloat16* __restrict__ wqb,
    __hip_bfloat16* __restrict__ wkb, __hip_bfloat16* __restrict__ wvb,
    __hip_bfloat16* __restrict__ wob, __hip_bfloat16* __restrict__ wgb)
{
    int b = blockIdx.x;
    const float* src;
    __hip_bfloat16* dst;
    size_t base;
    if (b < 4096)      { src = x;  dst = xb;  base = (size_t)b * 1024; }
    else if (b < 5120) { src = wq; dst = wqb; base = (size_t)(b - 4096) * 1024; }
    else if (b < 6144) { src = wk; dst = wkb; base = (size_t)(b - 5120) * 1024; }
    else if (b < 7168) { src = wv; dst = wvb; base = (size_t)(b - 6144) * 1024; }
    else if (b < 8192) { src = wo; dst = wob; base = (size_t)(b - 7168) * 1024; }
    else               { src = wg; dst = wgb; base = (size_t)(b - 8192) * 1024; }
    size_t i = base + (size_t)threadIdx.x * 4;
    float4 v = *(const float4*)(src + i);
    __hip_bfloat16 h0 = (__hip_bfloat16)v.x;
    __hip_bfloat16 h1 = (__hip_bfloat16)v.y;
    __hip_bfloat16 h2 = (__hip_bfloat16)v.z;
    __hip_bfloat16 h3 = (__hip_bfloat16)v.w;
    ushort4 u;
    u.x = *(unsigned short*)&h0;
    u.y = *(unsigned short*)&h1;
    u.z = *(unsigned short*)&h2;
    u.w = *(unsigned short*)&h3;
    *(ushort4*)((unsigned short*)dst + i) = u;
}

// ---------------------------------------------------------------------------
// 256x192-tile QKV GEMM (r8 schedule, verified) + T1 XCD-aware block swizzle:
// linear id -> XCD = id&7 (HW round-robin heuristic); XCD c owns the 4x8
// tile rectangle rows 4*(c>>1).., cols 8*(c&1).. -> per-XCD working set
// A 2 MB + B 3 MB ~= L2-resident; A panels duplicated across 2 XCDs
// instead of ~8. Mechanism: r1-r8 showed the dispatch pinned at ~42 us
// schedule-invariant with MfmaUtil 19% / HBM 17% (latency-bound) and
// FETCH 33 MB vs 14 compulsory -- cross-XCD panel duplication makes the
// staging loads L2-misses; swizzle converts them to L2 hits.
// ---------------------------------------------------------------------------
template <typename OutT>
__global__ __launch_bounds__(512, 2) void gemm192(
    const __hip_bfloat16* __restrict__ A,      // xb [4096][1024]
    const __hip_bfloat16* __restrict__ Bcat,   // Wqb|Wkb|Wvb [3072][1024]
    const float* __restrict__ c0, const float* __restrict__ c1, const float* __restrict__ c2,
    OutT* __restrict__ Ocat)                   // Qb|Kb|Vb [3][4096][1024]
{
    const int K  = DM;
    const int NT = 16;   // K / 64
    __shared__ __align__(16) unsigned short sL[2][7][64 * 64];  // [buf][A0..A3,B0,B1,B2]

    // XCD-aware bijective remap of the 16x16 tile grid.
    const int id  = blockIdx.y * 16 + blockIdx.x;
    const int xcd = id & 7;
    const int q   = id >> 3;                      // 0..31 within XCD
    const int bx  = 4 * (xcd >> 1) + (q >> 3);    // row-tile 0..15
    const int by  = 8 * (xcd & 1) + (q & 7);      // col-tile 0..15

    const int tid  = threadIdx.x;
    const int w    = tid >> 6;
    const int lane = tid & 63;
    const int l16  = lane & 15;
    const int quad = lane >> 4;
    const int wr   = w >> 2;      // 0,1: A row half (128 rows)
    const int wc   = w & 3;       // 0..3: 48-col slice
    const int rowBase = bx * 256;
    const int colBase = by * 192;

    // Staging: thread t loads 16B: row = unit*64 + (t>>3), global chunk
    // (t&7)^((t>>3)&7) -> LDS linear dest (both-sides swizzle rule).
    const int srow8 = tid >> 3;                 // 0..63
    const int schk  = (tid & 7) ^ (srow8 & 7);
    const __hip_bfloat16* gA = A    + (size_t)(rowBase + srow8) * K + schk * 8;
    const __hip_bfloat16* gB = Bcat + (size_t)(colBase + srow8) * K + schk * 8;
    const int ldst = w * 512;                   // wave-uniform dest (halfwords)

#define STGA(buf, ua, kt) async_cp16(gA + (size_t)(ua) * 64 * K + (kt) * 64, &sL[buf][ua][ldst])
#define STGB(buf, ub, kt) async_cp16(gB + (size_t)(ub) * 64 * K + (kt) * 64, &sL[buf][4 + (ub)][ldst])

    // read-side swizzled chunk offsets (halfwords) for k-slot 0/1
    const int cs0 = ((quad)     ^ (l16 & 7)) * 8;
    const int cs1 = ((4 + quad) ^ (l16 & 7)) * 8;

    f32x4 acc[8][3];
#pragma unroll
    for (int i = 0; i < 8; ++i)
#pragma unroll
        for (int j = 0; j < 3; ++j) acc[i][j] = (f32x4){0.f, 0.f, 0.f, 0.f};

    // Prologue: tile0 -> buf0 (7 units), tile1 -> buf1 (7 units).
    STGB(0, 0, 0); STGB(0, 1, 0); STGB(0, 2, 0);
    STGA(0, 0, 0); STGA(0, 2, 0); STGA(0, 1, 0); STGA(0, 3, 0);
    STGB(1, 0, 1); STGB(1, 1, 1); STGB(1, 2, 1);
    STGA(1, 0, 1); STGA(1, 2, 1); STGA(1, 1, 1); STGA(1, 3, 1);

    short8 af[4][2], bf[3][2];
    for (int t = 0; t < NT; ++t) {
        const int b = t & 1;
        const unsigned short* paL = &sL[b][wr * 2][0];
        const unsigned short* paH = &sL[b][wr * 2 + 1][0];

        // ---- phase 0: af-lo(8) + bf0(2); 8 MFMA ----
        if (t == NT - 1) asm volatile("s_waitcnt vmcnt(0)" ::: "memory");
        else             asm volatile("s_waitcnt vmcnt(7)" ::: "memory");
        __builtin_amdgcn_s_barrier();
#pragma unroll
        for (int m = 0; m < 4; ++m) {
            af[m][0] = *(const short8*)&paL[(m * 16 + l16) * 64 + cs0];
            af[m][1] = *(const short8*)&paL[(m * 16 + l16) * 64 + cs1];
        }
        {
            const int bu  = (wc * 48) >> 6;
            const int bro = (wc * 48) & 63;
            const unsigned short* pb = &sL[b][4 + bu][0];
            bf[0][0] = *(const short8*)&pb[(bro + l16) * 64 + cs0];
            bf[0][1] = *(const short8*)&pb[(bro + l16) * 64 + cs1];
        }
        asm volatile("s_waitcnt lgkmcnt(0)" ::: "memory");
        __builtin_amdgcn_sched_barrier(0);
        __builtin_amdgcn_s_setprio(1);
#pragma unroll
        for (int ks = 0; ks < 2; ++ks)
#pragma unroll
            for (int m = 0; m < 4; ++m)
                acc[m][0] = __builtin_amdgcn_mfma_f32_16x16x32_bf16(af[m][ks], bf[0][ks], acc[m][0], 0, 0, 0);
        __builtin_amdgcn_s_setprio(0);

        // ---- phase 1: bf1,bf2(4); barrier closes ALL reads of B*,A0,A2;
        //      stage those 5 units for t+2; 16 MFMA ----
#pragma unroll
        for (int n = 1; n < 3; ++n) {
            const int bu  = (wc * 48 + n * 16) >> 6;
            const int bro = (wc * 48 + n * 16) & 63;
            const unsigned short* pb = &sL[b][4 + bu][0];
            bf[n][0] = *(const short8*)&pb[(bro + l16) * 64 + cs0];
            bf[n][1] = *(const short8*)&pb[(bro + l16) * 64 + cs1];
        }
        asm volatile("s_waitcnt lgkmcnt(0)" ::: "memory");
        __builtin_amdgcn_sched_barrier(0);
        __builtin_amdgcn_s_barrier();
        if (t + 2 < NT) {
            STGB(b, 0, t + 2); STGB(b, 1, t + 2); STGB(b, 2, t + 2);
            STGA(b, 0, t + 2); STGA(b, 2, t + 2);
        }
        __builtin_amdgcn_s_setprio(1);
#pragma unroll
        for (int ks = 0; ks < 2; ++ks)
#pragma unroll
            for (int m = 0; m < 4; ++m)
#pragma unroll
                for (int n = 1; n < 3; ++n)
                    acc[m][n] = __builtin_amdgcn_mfma_f32_16x16x32_bf16(af[m][ks], bf[n][ks], acc[m][n], 0, 0, 0);
        __builtin_amdgcn_s_setprio(0);

        // ---- phase 2: af-hi(8); barrier closes A1,A3 reads; stage them;
        //      8 MFMA ----
#pragma unroll
        for (int m = 0; m < 4; ++m) {
            af[m][0] = *(const short8*)&paH[(m * 16 + l16) * 64 + cs0];
            af[m][1] = *(const short8*)&paH[(m * 16 + l16) * 64 + cs1];
        }
        asm volatile("s_waitcnt lgkmcnt(0)" ::: "memory");
        __builtin_amdgcn_sched_barrier(0);
        __builtin_amdgcn_s_barrier();
        if (t + 2 < NT) { STGA(b, 1, t + 2); STGA(b, 3, t + 2); }
        __builtin_amdgcn_s_setprio(1);
#pragma unroll
        for (int ks = 0; ks < 2; ++ks)
#pragma unroll
            for (int m = 0; m < 4; ++m)
                acc[m + 4][0] = __builtin_amdgcn_mfma_f32_16x16x32_bf16(af[m][ks], bf[0][ks], acc[m + 4][0], 0, 0, 0);
        __builtin_amdgcn_s_setprio(0);

        // ---- phase 3: no reads, no barrier; 16 MFMA ----
        __builtin_amdgcn_s_setprio(1);
#pragma unroll
        for (int ks = 0; ks < 2; ++ks)
#pragma unroll
            for (int m = 0; m < 4; ++m)
#pragma unroll
                for (int n = 1; n < 3; ++n)
                    acc[m + 4][n] = __builtin_amdgcn_mfma_f32_16x16x32_bf16(af[m][ks], bf[n][ks], acc[m + 4][n], 0, 0, 0);
        __builtin_amdgcn_s_setprio(0);
    }
#undef STGA
#undef STGB

    // Epilogue: per 16-wide fragment, grp = col>>10 is uniform (1024%16==0).
#pragma unroll
    for (int n = 0; n < 3; ++n) {
        int col = colBase + wc * 48 + n * 16 + l16;
        int grp = col >> 10;
        int cl  = col & 1023;
        const float* bias = grp == 0 ? c0 : (grp == 1 ? c1 : c2);
        float bv = bias[cl];
        OutT* O = Ocat + (size_t)grp * TT * DM;
#pragma unroll
        for (int m = 0; m < 8; ++m) {
#pragma unroll
            for (int r = 0; r < 4; ++r) {
                int row = rowBase + wr * 128 + m * 16 + quad * 4 + r;
                O[(size_t)row * DM + cl] = (OutT)(acc[m][n][r] + bv);
            }
        }
    }
}

// 128x64-tile GEMM for the Wo projection, counted-vmcnt 2-deep pipeline
// (r6 version, known-passing) + XCD swizzle (8x8 tile rectangle per XCD).
template <typename OutT>
__global__ __launch_bounds__(256) void gemm_n64(
    const __hip_bfloat16* __restrict__ A,
    const __hip_bfloat16* __restrict__ B,
    const float* __restrict__ bias,
    OutT* __restrict__ O)
{
    const int K = DM;
    const int NT = 32;
    __shared__ __align__(16) unsigned short sA[2 * 128 * 32];
    __shared__ __align__(16) unsigned short sB[2 * 64 * 32];

    // XCD-aware bijective remap of the 32x16 tile grid (64 blocks/XCD).
    const int id  = blockIdx.y * 32 + blockIdx.x;
    const int xcd = id & 7;
    const int q   = id >> 3;                      // 0..63
    const int bx  = 8 * (xcd >> 1) + (q >> 3);    // row-tile 0..31
    const int by  = 8 * (xcd & 1) + (q & 7);      // col-tile 0..15

    const int tid  = threadIdx.x;
    const int w    = tid >> 6;
    const int lane = tid & 63;
    const int l16  = lane & 15;
    const int quad = lane >> 4;
    const int rowBase = bx * 128;
    const int colBase = by * 64;

    const int srow   = lane >> 2;
    const int sswz   = (srow & 3) ^ (srow >> 2);
    const int gchunk = (lane & 3) ^ sswz;
    const __hip_bfloat16* gA = A + (size_t)(rowBase + w * 32 + srow) * K + gchunk * 8;
    const __hip_bfloat16* gB = B + (size_t)(colBase + w * 16 + srow) * K + gchunk * 8;
    unsigned short* lA0 = sA + w * 32 * 32;
    unsigned short* lB0 = sB + w * 16 * 32;

    const int fswz = (l16 & 3) ^ (l16 >> 2);
    const int mrow = w * 32;

    f32x4 acc[2][4];
#pragma unroll
    for (int i = 0; i < 2; ++i)
#pragma unroll
        for (int j = 0; j < 4; ++j) acc[i][j] = (f32x4){0.f, 0.f, 0.f, 0.f};

    async_cp16(gA,                  lA0);
    async_cp16(gA + (size_t)16 * K, lA0 + 16 * 32);
    async_cp16(gB,                  lB0);
    async_cp16(gA + 32,                  lA0 + 128 * 32);
    async_cp16(gA + 32 + (size_t)16 * K, lA0 + 128 * 32 + 16 * 32);
    async_cp16(gB + 32,                  lB0 + 64 * 32);

    for (int t = 0; t < NT; ++t) {
        if (t == NT - 1) asm volatile("s_waitcnt vmcnt(0)" ::: "memory");
        else             asm volatile("s_waitcnt vmcnt(3)" ::: "memory");
        __builtin_amdgcn_s_barrier();

        const unsigned short* pA = sA + (t & 1) * (128 * 32);
        const unsigned short* pB = sB + (t & 1) * (64 * 32);
        short8 af[2], bf[4];
#pragma unroll
        for (int mt = 0; mt < 2; ++mt)
            af[mt] = *(const short8*)&pA[(mrow + mt * 16 + l16) * 32 + (quad ^ fswz) * 8];
#pragma unroll
        for (int nt = 0; nt < 4; ++nt)
            bf[nt] = *(const short8*)&pB[(nt * 16 + l16) * 32 + (quad ^ fswz) * 8];
        asm volatile("s_waitcnt lgkmcnt(0)" ::: "memory");
        __builtin_amdgcn_sched_barrier(0);
        __builtin_amdgcn_s_barrier();

        if (t + 2 < NT) {
            const int k2 = (t + 2) * 32;
            unsigned short* dA = lA0 + (t & 1) * (128 * 32);
            unsigned short* dB = lB0 + (t & 1) * (64 * 32);
            async_cp16(gA + k2,                  dA);
            async_cp16(gA + k2 + (size_t)16 * K, dA + 16 * 32);
            async_cp16(gB + k2,                  dB);
        }

#pragma unroll
        for (int mt = 0; mt < 2; ++mt)
#pragma unroll
            for (int nt = 0; nt < 4; ++nt)
                acc[mt][nt] = __builtin_amdgcn_mfma_f32_16x16x32_bf16(af[mt], bf[nt], acc[mt][nt], 0, 0, 0);
    }

#pragma unroll
    for (int nt = 0; nt < 4; ++nt) {
        int col = colBase + nt * 16 + l16;
        float bv = bias[col];
#pragma unroll
        for (int mt = 0; mt < 2; ++mt) {
#pragma unroll
            for (int r = 0; r < 4; ++r) {
                int row = rowBase + mrow + mt * 16 + quad * 4 + r;
                O[(size_t)row * DM + col] = (OutT)(acc[mt][nt][r] + bv);
            }
        }
    }
}

// Merged auxiliary kernel (chunk means, ushort2-vectorized + gate GEMM).
__global__ __launch_bounds__(256) void aux_kernel(
    const __hip_bfloat16* __restrict__ K,
    const __hip_bfloat16* __restrict__ V,
    const __hip_bfloat16* __restrict__ xb,
    const __hip_bfloat16* __restrict__ Wgb,
    const float* __restrict__ bg,
    __hip_bfloat16* __restrict__ CK,
    __hip_bfloat16* __restrict__ CV,
    float* __restrict__ G)
{
    const int b = blockIdx.x;
    if (b < 256) {
        const int c  = b >> 1;
        const int d0 = (b & 1) * 512 + threadIdx.x * 2;
        const unsigned short* Ku = (const unsigned short*)K;
        const unsigned short* Vu = (const unsigned short*)V;
        float ak0 = 0.f, ak1 = 0.f, av0 = 0.f, av1 = 0.f;
#pragma unroll 8
        for (int i = 0; i < 32; ++i) {
            size_t off = (size_t)(c * 32 + i) * DM + d0;
            ushort2 kv = *(const ushort2*)(Ku + off);
            ushort2 vv = *(const ushort2*)(Vu + off);
            ak0 += bf2f(kv.x); ak1 += bf2f(kv.y);
            av0 += bf2f(vv.x); av1 += bf2f(vv.y);
        }
        __hip_bfloat16 k0 = (__hip_bfloat16)(ak0 * (1.f / 32.f));
        __hip_bfloat16 k1 = (__hip_bfloat16)(ak1 * (1.f / 32.f));
        __hip_bfloat16 v0 = (__hip_bfloat16)(av0 * (1.f / 32.f));
        __hip_bfloat16 v1 = (__hip_bfloat16)(av1 * (1.f / 32.f));
        ushort2 ko, vo;
        ko.x = *(unsigned short*)&k0; ko.y = *(unsigned short*)&k1;
        vo.x = *(unsigned short*)&v0; vo.y = *(unsigned short*)&v1;
        *(ushort2*)((unsigned short*)CK + (size_t)c * DM + d0) = ko;
        *(ushort2*)((unsigned short*)CV + (size_t)c * DM + d0) = vo;
        return;
    }
    const int unit = threadIdx.x >> 6;
    const int lane = threadIdx.x & 63;
    const int l16  = lane & 15;
    const int quad = lane >> 4;
    const int t0   = (b - 256) * 64 + unit * 16;
    const __hip_bfloat16* ap = xb  + (size_t)(t0 + l16) * DM + quad * 8;
    const __hip_bfloat16* bp = Wgb + (size_t)l16 * DM + quad * 8;
    f32x4 acc = (f32x4){0.f, 0.f, 0.f, 0.f};
#pragma unroll 4
    for (int k0 = 0; k0 < DM; k0 += 32) {
        short8 a = *(const short8*)(ap + k0);
        short8 bb = *(const short8*)(bp + k0);
        acc = __builtin_amdgcn_mfma_f32_16x16x32_bf16(a, bb, acc, 0, 0, 0);
    }
    float bgv = bg[l16];
#pragma unroll
    for (int r = 0; r < 4; ++r) {
        int t = t0 + quad * 4 + r;
        float z = acc[r] + bgv;
        G[t * NH + l16] = 1.f / (1.f + __expf(-z));
    }
}

// MFMA attention: 64 queries x 1 head per block (grid 64 x 16, 256 threads)
// + XCD swizzle: XCD c owns heads {2c, 2c+1} x all 64 t-tiles, so each
// XCD's K/V head-slices (~2 MB) stay L2-resident instead of every XCD
// touching all 16 heads.
__global__ __launch_bounds__(256) void attn_mfma(
    const __hip_bfloat16* __restrict__ Q,
    const __hip_bfloat16* __restrict__ K,
    const __hip_bfloat16* __restrict__ V,
    const __hip_bfloat16* __restrict__ CK,
    const __hip_bfloat16* __restrict__ CV,
    const float* __restrict__ G,
    __hip_bfloat16* __restrict__ Aout)
{
    __shared__ alignas(16) unsigned short Pls[64 * PSTR];
    __shared__ alignas(16) unsigned short Vts[64 * PSTR];

    // XCD-aware bijective remap of the 64x16 (t-tile, head) grid.
    const int id  = blockIdx.y * 64 + blockIdx.x;
    const int xcd = id & 7;
    const int q   = id >> 3;                 // 0..127
    const int h   = 2 * xcd + (q >> 6);      // head 0..15
    const int t0  = (q & 63) * 64;           // t-tile base

    const int tid = threadIdx.x;
    const int w    = tid >> 6;
    const int lane = tid & 63;
    const int l16  = lane & 15;
    const int quad = lane >> 4;
    const float scale = 0.125f;

    const int rc0  = (t0 >= 96) ? ((t0 - 64) >> 5) : 0;
    const int cmin = rc0 > 16 ? rc0 - 16 : 0;

    const unsigned short* Vu  = (const unsigned short*)V;
    const unsigned short* CVu = (const unsigned short*)CV;

    {
#pragma unroll
        for (int gg = 0; gg < 2; ++gg) {
            const int g = w * 2 + gg;
#pragma unroll
            for (int i = 0; i < 2; ++i) {
                const int pair = lane + 64 * i;
                if (pair < 80) {
                    const int j = pair * 2;
                    const unsigned short *s0, *s1;
                    if (j < 128) {
                        int tok0 = t0 - 64 + j; if (tok0 < 0) tok0 = 0;
                        int tok1 = t0 - 63 + j; if (tok1 < 0) tok1 = 0;
                        s0 = Vu + (size_t)tok0 * DM + h * 64 + g * 8;
                        s1 = Vu + (size_t)tok1 * DM + h * 64 + g * 8;
                    } else {
                        int c0 = cmin + (j - 128); if (c0 > 127) c0 = 127;
                        int c1 = c0 + 1;           if (c1 > 127) c1 = 127;
                        s0 = CVu + (size_t)c0 * DM + h * 64 + g * 8;
                        s1 = CVu + (size_t)c1 * DM + h * 64 + g * 8;
                    }
                    short8 v0 = *(const short8*)s0;
                    short8 v1 = *(const short8*)s1;
#pragma unroll
                    for (int e = 0; e < 8; ++e) {
                        ushort2 pk;
                        pk.x = (unsigned short)v0[e];
                        pk.y = (unsigned short)v1[e];
                        *(ushort2*)&Vts[(g * 8 + e) * PSTR + j] = pk;
                    }
                }
            }
        }
    }

    const __hip_bfloat16* qp = Q + (size_t)(t0 + w * 16 + l16) * DM + h * 64 + quad * 8;
    short8 qf0 = *(const short8*)(qp);
    short8 qf1 = *(const short8*)(qp + 32);

    f32x4 sc[8];
#pragma unroll
    for (int jt = 0; jt < 8; ++jt) {
        int j = jt * 16 + l16;
        int tok = t0 - 64 + j;
        tok = tok < 0 ? 0 : tok;
        const __hip_bfloat16* kp = K + (size_t)tok * DM + h * 64 + quad * 8;
        short8 b0 = *(const short8*)(kp);
        short8 b1 = *(const short8*)(kp + 32);
        f32x4 a = __builtin_amdgcn_mfma_f32_16x16x32_bf16(qf0, b0, (f32x4){0.f,0.f,0.f,0.f}, 0, 0, 0);
        sc[jt]  = __builtin_amdgcn_mfma_f32_16x16x32_bf16(qf1, b1, a, 0, 0, 0);
    }
    f32x4 sc2[2];
#pragma unroll
    for (int jt = 0; jt < 2; ++jt) {
        int c = cmin + jt * 16 + l16;
        if (c > 127) c = 127;
        const __hip_bfloat16* cp = CK + (size_t)c * DM + h * 64 + quad * 8;
        short8 b0 = *(const short8*)(cp);
        short8 b1 = *(const short8*)(cp + 32);
        f32x4 a = __builtin_amdgcn_mfma_f32_16x16x32_bf16(qf0, b0, (f32x4){0.f,0.f,0.f,0.f}, 0, 0, 0);
        sc2[jt] = __builtin_amdgcn_mfma_f32_16x16x32_bf16(qf1, b1, a, 0, 0, 0);
    }

    __syncthreads();  // all waves' Vts writes visible before PV reads

    const int rbase = w * 16 + quad * 4;
    float gl[4], g2[4];
    float mx[4], sm[4], mx2[4], sm2[4];
#pragma unroll
    for (int reg = 0; reg < 4; ++reg) {
        int rr = rbase + reg;
        int t  = t0 + rr;
        float g = G[t * NH + h];
        int rc = (t >= 96) ? ((t - 64) >> 5) : 0;
        gl[reg] = (t > 0)  ? g        : 0.f;
        g2[reg] = (rc > 0) ? (1.f - g) : 0.f;

        int jlo = rr > (64 - t0) ? rr : (64 - t0);
        int jhi = rr + 63;
        float m = -1e30f;
#pragma unroll
        for (int jt = 0; jt < 8; ++jt) {
            int j = jt * 16 + l16;
            float s = (j >= jlo && j <= jhi) ? sc[jt][reg] * scale : -1e30f;
            sc[jt][reg] = s;
            m = fmaxf(m, s);
        }
        mx[reg] = m;

        int nvis = rc < 16 ? rc : 16;
        int clo = rc - nvis, chi = rc - 1;
        float m2 = -1e30f;
#pragma unroll
        for (int jt = 0; jt < 2; ++jt) {
            int c = cmin + jt * 16 + l16;
            float s = (c >= clo && c <= chi) ? sc2[jt][reg] * scale : -1e30f;
            sc2[jt][reg] = s;
            m2 = fmaxf(m2, s);
        }
        mx2[reg] = m2;
    }
#pragma unroll
    for (int off = 1; off <= 8; off <<= 1)
#pragma unroll
        for (int reg = 0; reg < 4; ++reg) {
            mx[reg]  = fmaxf(mx[reg],  __shfl_xor(mx[reg],  off));
            mx2[reg] = fmaxf(mx2[reg], __shfl_xor(mx2[reg], off));
        }
#pragma unroll
    for (int reg = 0; reg < 4; ++reg) {
        float s = 0.f, s2 = 0.f;
#pragma unroll
        for (int jt = 0; jt < 8; ++jt) {
            float p = __expf(sc[jt][reg] - mx[reg]);
            sc[jt][reg] = p;
            s += p;
        }
#pragma unroll
        for (int jt = 0; jt < 2; ++jt) {
            float p = __expf(sc2[jt][reg] - mx2[reg]);
            sc2[jt][reg] = p;
            s2 += p;
        }
        sm[reg] = s; sm2[reg] = s2;
    }
#pragma unroll
    for (int off = 1; off <= 8; off <<= 1)
#pragma unroll
        for (int reg = 0; reg < 4; ++reg) {
            sm[reg]  += __shfl_xor(sm[reg],  off);
            sm2[reg] += __shfl_xor(sm2[reg], off);
        }

#pragma unroll
    for (int reg = 0; reg < 4; ++reg) {
        float f1 = gl[reg] / sm[reg];
        float f2 = g2[reg] / sm2[reg];
        int rowoff = (rbase + reg) * PSTR;
#pragma unroll
        for (int jt = 0; jt < 8; ++jt) {
            __hip_bfloat16 hb = (__hip_bfloat16)(sc[jt][reg] * f1);
            Pls[rowoff + jt * 16 + l16] = *(unsigned short*)&hb;
        }
#pragma unroll
        for (int jt = 0; jt < 2; ++jt) {
            __hip_bfloat16 hb = (__hip_bfloat16)(sc2[jt][reg] * f2);
            Pls[rowoff + 128 + jt * 16 + l16] = *(unsigned short*)&hb;
        }
    }
    asm volatile("s_waitcnt lgkmcnt(0)" ::: "memory");  // wave-private P round-trip

    f32x4 o[4];
#pragma unroll
    for (int nt = 0; nt < 4; ++nt) o[nt] = (f32x4){0.f, 0.f, 0.f, 0.f};
#pragma unroll
    for (int kt = 0; kt < 5; ++kt) {
        short8 a = *(const short8*)&Pls[(w * 16 + l16) * PSTR + kt * 32 + quad * 8];
#pragma unroll
        for (int nt = 0; nt < 4; ++nt) {
            int dd = nt * 16 + l16;
            short8 b = *(const short8*)&Vts[dd * PSTR + kt * 32 + quad * 8];
            o[nt] = __builtin_amdgcn_mfma_f32_16x16x32_bf16(a, b, o[nt], 0, 0, 0);
        }
    }

#pragma unroll
    for (int nt = 0; nt < 4; ++nt) {
#pragma unroll
        for (int reg = 0; reg < 4; ++reg) {
            int row = t0 + rbase + reg;
            int col = h * 64 + nt * 16 + l16;
            Aout[(size_t)row * DM + col] = (__hip_bfloat16)(o[nt][reg]);
        }
    }
}

extern "C" void kernel_launch(void* const* d_in, const int* in_sizes, int n_in,
                              void* d_out, int out_size, void* d_ws, size_t ws_size,
                              hipStream_t stream)
{
    const float* x  = (const float*)d_in[0];
    const float* Wq = (const float*)d_in[1];
    const float* bq = (const float*)d_in[2];
    const float* Wk = (const float*)d_in[3];
    const float* bk = (const float*)d_in[4];
    const float* Wv = (const float*)d_in[5];
    const float* bv = (const float*)d_in[6];
    const float* Wo = (const float*)d_in[7];
    const float* bo = (const float*)d_in[8];
    const float* Wg = (const float*)d_in[9];
    const float* bg = (const float*)d_in[10];
    float* out = (float*)d_out;

    char* ws = (char*)d_ws;
    const size_t MB = 1024 * 1024;
    __hip_bfloat16* xb  = (__hip_bfloat16*)(ws + 0 * MB);   // 8 MB
    __hip_bfloat16* Qb  = (__hip_bfloat16*)(ws + 8 * MB);   // 8 MB  } contiguous
    __hip_bfloat16* Kb  = (__hip_bfloat16*)(ws + 16 * MB);  // 8 MB  } Ocat for
    __hip_bfloat16* Vb  = (__hip_bfloat16*)(ws + 24 * MB);  // 8 MB  } gemm192
    __hip_bfloat16* Ab  = (__hip_bfloat16*)(ws + 32 * MB);  // 8 MB
    __hip_bfloat16* Wqb = (__hip_bfloat16*)(ws + 40 * MB);  // 2 MB  } contiguous
    __hip_bfloat16* Wkb = (__hip_bfloat16*)(ws + 42 * MB);  // 2 MB  } Bcat for
    __hip_bfloat16* Wvb = (__hip_bfloat16*)(ws + 44 * MB);  // 2 MB  } gemm192
    __hip_bfloat16* Wob = (__hip_bfloat16*)(ws + 46 * MB);  // 2 MB
    __hip_bfloat16* CKb = (__hip_bfloat16*)(ws + 48 * MB);            // 256 KB
    __hip_bfloat16* CVb = (__hip_bfloat16*)(ws + 48 * MB + 256*1024); // 256 KB
    float* Gf           = (float*)(ws + 48 * MB + 512 * 1024);        // 256 KB
    __hip_bfloat16* Wgb = (__hip_bfloat16*)(ws + 48 * MB + 768*1024); // 32 KB

    cast_all<<<dim3(8208), 256, 0, stream>>>(x, Wq, Wk, Wv, Wo, Wg,
                                             xb, Wqb, Wkb, Wvb, Wob, Wgb);

    // Fused QKV GEMM, 256x192 tiles over concatenated B/O: grid (16,16)
    // = 256 blocks = full machine, XCD-swizzled.
    gemm192<__hip_bfloat16><<<dim3(16, 16), 512, 0, stream>>>(
        xb, Wqb, bq, bk, bv, Qb);
    // Merged chunk-means + gate GEMM (one dispatch, independent halves).
    aux_kernel<<<dim3(320), 256, 0, stream>>>(Kb, Vb, xb, Wgb, bg, CKb, CVb, Gf);
    attn_mfma<<<dim3(64, 16), 256, 0, stream>>>(Qb, Kb, Vb, CKb, CVb, Gf, Ab);
    // Output GEMM: 128x64 tiles, grid (32, 16) = 512 blocks, XCD-swizzled.
    gemm_n64<float><<<dim3(32, 16), 256, 0, stream>>>(Ab, Wob, bo, out);
}